// Round 9
// baseline (626.219 us; speedup 1.0000x reference)
//
#include <hip/hip_runtime.h>
#include <hip/hip_bf16.h>

// Problem constants
#define NB 32
#define NT 1024
#define IH 180
#define IW 330
#define KSZ 37
#define XBINS 181
#define H1 90
#define W1 165
#define H2 45
#define W2 82
#define PIX2 (H2*W2)          // 3690
#define KTOT PIX2
#define KPAD 3712
#define CH1 32
#define CH2 64
#define CH3 128
#define NSTRIP 6
#define NKC 8                 // einsum K-chunks (512 each over KPAD)

// FC split-K config
#define NKF 256               // K-chunks for fc (16384/64)
#define KCF 64

// heat_rowcombine band config
#define BXR 12                // output rows per band (15 bands cover 180)
#define YHW 165               // half of IW
#define GROWS_MAX 54          // max staged G rows

// Per-batch f32-slot counts
#define EL_HEAT (IH*IW)           // 59,400
#define EL_REGB 237600            // out1 bf16 [H1*W1][32] -> pp1 bf16 [PIX2][128] -> px_part f32 -> fc partials
#define EL_REGC (CH2*PIX2/2)      // 118,080 : out2 bf16 ch-last [pixel][64]
#define EL_REGD (CH3*KPAD/2)      // 237,568 : G f32 -> fbuf bf16 -> pp2 bf16 [c][KPAD] -> wT f32
#define EL_REGE (CH3*KPAD/2)      // 237,568 : fx bf16 [c][KPAD]
#define EL_PX   (CH3*CH3)         // 16,384
#define EL_PER_BATCH (EL_HEAT + EL_REGB + EL_REGC + EL_REGD + EL_REGE + EL_PX) // 906,600

// folded-weight sizes (bf16 shorts)
#define WSH_A1 (9*128*64)
#define WSH_A2 (9*128*128)
#define WSH_C2 (9*64*32)
#define WSH_TOT (2*WSH_A1 + 2*WSH_A2 + WSH_C2)

typedef __attribute__((ext_vector_type(8))) short short8;
typedef __attribute__((ext_vector_type(4))) float floatx4;

__device__ __forceinline__ short f2bf(float v) {
    __hip_bfloat16 h = __float2bfloat16(v);
    return *reinterpret_cast<short*>(&h);
}
__device__ __forceinline__ float b2f(short s) {
    __hip_bfloat16 h = *reinterpret_cast<__hip_bfloat16*>(&s);
    return __bfloat162float(h);
}

// ---------------------------------------------------------------------------
__global__ __launch_bounds__(256) void mm_init(unsigned* __restrict__ m_bits,
                                               unsigned* __restrict__ pmm_bits) {
    int i = threadIdx.x;
    if (i < 64) {
        m_bits[i] = 0u;
        pmm_bits[2 * i]     = 0x7F800000u;   // +inf
        pmm_bits[2 * i + 1] = 0u;
    }
}

// ---------------------------------------------------------------------------
// S1: separable scatter — column profiles into G[xp][Y]
// ---------------------------------------------------------------------------
__global__ __launch_bounds__(256) void heat_scatter_cols(const float* __restrict__ x_t,
                                                         float* __restrict__ G,
                                                         int b0) {
    const int strip = blockIdx.x;
    const int lb = blockIdx.y;
    const int b = b0 + lb;
    const int c0 = strip * 64;
    const int cw = min(64, IW - c0);
    __shared__ float g[XBINS * 64];
    __shared__ float k1n[64];
    __shared__ float2 pts[NT];
    const int tid = threadIdx.x;

    if (tid < 64) {
        float v = 0.0f;
        if (tid < KSZ) {
            float ax = (float)tid - 18.0f;
            v = expf(-ax * ax / 18.0f);
        }
        k1n[tid] = v;
    }
    for (int i = tid; i < XBINS * 64; i += 256) g[i] = 0.0f;
    {
        const float2* xb = (const float2*)x_t + (size_t)b * NT;
        for (int i = tid; i < NT; i += 256) pts[i] = xb[i];
    }
    __syncthreads();
    if (tid == 0) {
        float s = 0.0f;
        for (int i = 0; i < KSZ; i++) s += k1n[i];
        float inv = 1.0f / s;
        for (int i = 0; i < KSZ; i++) k1n[i] *= inv;
    }
    __syncthreads();

    const int wave = tid >> 6;
    const int lane = tid & 63;
    const float kc = k1n[lane];

    for (int p = wave; p < NT; p += 4) {
        float x = pts[p].x, y = pts[p].y;
        if (isnan(x) || isnan(y)) continue;
        int xp = IH - (int)((x - 30.0f) * 180.0f);
        xp = min(max(xp, 0), 180);
        int yp = (int)((y - 120.0f) * 165.0f);
        int ys = min(max(yp - 18, 0), IW - 36);
        int ye = min(max(yp + 18, 0), IW);
        int nc = ye - ys;
        int col = ys + lane;
        if (lane < nc && col >= c0 && col < c0 + cw)
            atomicAdd(&g[xp * 64 + col - c0], kc);
    }
    __syncthreads();
    for (int i = tid; i < XBINS * cw; i += 256) {
        int row = i / cw, col = i % cw;
        G[((size_t)lb * XBINS + row) * IW + c0 + col] = g[row * 64 + col];
    }
}

// ---------------------------------------------------------------------------
// S2: row-combine + fused per-batch max (band-tiled, LDS-staged G)
// ---------------------------------------------------------------------------
__global__ __launch_bounds__(256) void heat_rowcombine(const float* __restrict__ G,
                                                       float* __restrict__ heat,
                                                       unsigned* __restrict__ m_bits) {
    const int band = blockIdx.x;        // 0..14
    const int lb = blockIdx.y;
    const int half = blockIdx.z;        // 0..1
    const int X0 = band * BXR;
    const int c0 = half * YHW;
    const int tid = threadIdx.x;

    __shared__ float k1n[64];
    __shared__ float gs[GROWS_MAX * YHW];   // 35,640 B
    __shared__ float red[256];

    if (tid < 64) {
        float v = 0.0f;
        if (tid < KSZ) {
            float ax = (float)tid - 18.0f;
            v = expf(-ax * ax / 18.0f);
        }
        k1n[tid] = v;
    }

    const int rlo = max(0, X0 - 17);
    const int rhi = (X0 + BXR - 1 >= IH - 36) ? 180 : (X0 + BXR - 1 + 18);
    const int nrows = rhi - rlo + 1;        // <= 54
    const float* Gb = G + (size_t)lb * XBINS * IW;
    for (int i = tid; i < nrows * YHW; i += 256) {
        int r = i / YHW, y = i % YHW;
        gs[i] = Gb[(size_t)(rlo + r) * IW + c0 + y];
    }
    __syncthreads();
    if (tid == 0) {
        float s = 0.0f;
        for (int i = 0; i < KSZ; i++) s += k1n[i];
        float inv = 1.0f / s;
        for (int i = 0; i < KSZ; i++) k1n[i] *= inv;
    }
    __syncthreads();

    float lmax = 0.0f;
    for (int p = tid; p < BXR * YHW; p += 256) {
        const int xr = p / YHW;
        const int yy = p % YHW;
        const int X = X0 + xr;
        const int Y = c0 + yy;
        const int lo = max(0, X - 17);
        const int hi = (X >= IH - 36) ? 180 : X + 18;
        float s = 0.0f;
        for (int xp = lo; xp <= hi; ++xp) {
            int xs = min(max(xp - 18, 0), IH - 36);
            s += k1n[X - xs] * gs[(xp - rlo) * YHW + yy];
        }
        heat[(size_t)lb * EL_HEAT + (size_t)X * IW + Y] = s;
        lmax = fmaxf(lmax, s);
    }
    red[tid] = lmax;
    __syncthreads();
    for (int st = 128; st > 0; st >>= 1) {
        if (tid < st) red[tid] = fmaxf(red[tid], red[tid + st]);
        __syncthreads();
    }
    if (tid == 0) atomicMax(&m_bits[lb], __float_as_uint(red[0]));
}

// ---------------------------------------------------------------------------
// K3: conv1(1->32) + BN + relu + pool (fuse folded); out bf16 ch-last [pix][32]
// ---------------------------------------------------------------------------
__global__ __launch_bounds__(256) void conv1_pool(const float* __restrict__ heat,
                                                  const float* __restrict__ image,
                                                  const float* __restrict__ m,
                                                  const float* __restrict__ w,
                                                  const float* __restrict__ cb,
                                                  const float* __restrict__ g,
                                                  const float* __restrict__ bb,
                                                  short* __restrict__ out1,
                                                  int b0, int gb) {
    __shared__ float ws_[CH1 * 9];
    __shared__ float bs_[CH1];
    const int tid = threadIdx.x;
    for (int i = tid; i < CH1 * 9; i += 256) {
        int oc = i / 9;
        ws_[i] = w[i] * g[oc];
    }
    if (tid < CH1) bs_[tid] = cb[tid] * g[tid] + bb[tid];
    __syncthreads();

    int t = blockIdx.x * 256 + tid;
    if (t >= gb * H1 * W1) return;
    int lb = t / (H1 * W1);
    int r = t % (H1 * W1);
    int py = r / W1, px = r % W1;
    const float s = 0.7f / (m[lb] + 1e-10f);
    const float* hb = heat + (size_t)lb * EL_HEAT;
    const float* ib = image + (size_t)(b0 + lb) * EL_HEAT;

    float v[4][4];
    int y0 = 2 * py - 1, x0 = 2 * px - 1;
#pragma unroll
    for (int i = 0; i < 4; i++) {
#pragma unroll
        for (int j = 0; j < 4; j++) {
            int y = y0 + i, x = x0 + j;
            float val = 0.0f;
            if (y >= 0 && y < IH && x >= 0 && x < IW) {
                size_t idx = (size_t)y * IW + x;
                val = s * hb[idx] + 0.3f * ib[idx];
            }
            v[i][j] = val;
        }
    }
    short8 pk[4];
#pragma unroll
    for (int oc = 0; oc < CH1; oc++) {
        float a00 = 0, a01 = 0, a10 = 0, a11 = 0;
        const float* wp = &ws_[oc * 9];
#pragma unroll
        for (int ky = 0; ky < 3; ky++) {
#pragma unroll
            for (int kx = 0; kx < 3; kx++) {
                float wv = wp[ky * 3 + kx];
                a00 += wv * v[ky][kx];
                a01 += wv * v[ky][kx + 1];
                a10 += wv * v[ky + 1][kx];
                a11 += wv * v[ky + 1][kx + 1];
            }
        }
        float bias = bs_[oc];
        a00 = fmaxf(a00 + bias, 0.0f);
        a01 = fmaxf(a01 + bias, 0.0f);
        a10 = fmaxf(a10 + bias, 0.0f);
        a11 = fmaxf(a11 + bias, 0.0f);
        pk[oc >> 3][oc & 7] = f2bf(fmaxf(fmaxf(a00, a01), fmaxf(a10, a11)));
    }
    short8* op = reinterpret_cast<short8*>(&out1[((size_t)lb * H1 * W1 + r) * CH1]);
#pragma unroll
    for (int vv = 0; vv < 4; vv++) op[vv] = pk[vv];
}

// ---------------------------------------------------------------------------
// weight fold/transpose: wT[tap][oc][ic] = bf16(w[oc][ic][tap]*g[oc])
// ---------------------------------------------------------------------------
__global__ __launch_bounds__(256) void wfold_k(const float* __restrict__ w,
                                               const float* __restrict__ g,
                                               const float* __restrict__ cb,
                                               const float* __restrict__ bb,
                                               short* __restrict__ wT,
                                               float* __restrict__ bfold,
                                               int OC, int IC) {
    int i = blockIdx.x * 256 + threadIdx.x;
    int n = 9 * OC * IC;
    if (i >= n) return;
    int tap = i / (OC * IC);
    int r = i % (OC * IC);
    int oc = r / IC;
    int ic = r % IC;
    wT[i] = f2bf(w[((size_t)oc * IC + ic) * 9 + tap] * g[oc]);
    if (tap == 0 && ic == 0) bfold[oc] = cb[oc] * g[oc] + bb[oc];
}

// ---------------------------------------------------------------------------
// K4: conv2(32->64) + BN + relu + 2x2 pool via bf16 MFMA.
// ---------------------------------------------------------------------------
__global__ __launch_bounds__(256) void conv2_mfma(const short* __restrict__ in,
                                                  const short* __restrict__ wT,
                                                  const float* __restrict__ bfold,
                                                  short* __restrict__ out) {
    const int xt = blockIdx.x;   // 0..5 : 32 pre-pool cols
    const int yt = blockIdx.y;   // 0..11: 8 pre-pool rows
    const int lb = blockIdx.z;
    const int x0 = xt * 32, y0 = yt * 8;
    const int tid = threadIdx.x;
    const int wave = tid >> 6, lane = tid & 63;
    const int mm = lane & 15, q = lane >> 4;
    constexpr int AP = 40;
    constexpr int CP = 72;                      // C-stage stride (16B-aligned rows)
    __shared__ __align__(16) short smem[10 * 34 * AP];   // 27,200 B (>= 64*CP=9,216)

    floatx4 acc[2][2][4];
#pragma unroll
    for (int a = 0; a < 2; ++a)
#pragma unroll
        for (int bq = 0; bq < 2; ++bq)
#pragma unroll
            for (int j = 0; j < 4; ++j) acc[a][bq][j] = (floatx4){0.f, 0.f, 0.f, 0.f};

    const short* inb = in + (size_t)lb * (H1 * W1) * CH1;
    for (int e = tid; e < 10 * 34 * 4; e += 256) {
        int dy = e / (34 * 4);
        int r = e % (34 * 4);
        int tx = r / 4;
        int i8 = r % 4;
        int yin = y0 + dy - 1, xin = x0 + tx - 1;
        short8 hv = {0, 0, 0, 0, 0, 0, 0, 0};
        if (yin >= 0 && yin < H1 && xin >= 0 && xin < W1)
            hv = *reinterpret_cast<const short8*>(&inb[((size_t)(yin * W1 + xin)) * CH1 + i8 * 8]);
        *reinterpret_cast<short8*>(&smem[(dy * 34 + tx) * AP + i8 * 8]) = hv;
    }
    __syncthreads();

#pragma unroll
    for (int tap = 0; tap < 9; ++tap) {
        const int dy = tap / 3, dx = tap % 3;
        short8 bf[4];
#pragma unroll
        for (int j = 0; j < 4; ++j)
            bf[j] = *reinterpret_cast<const short8*>(&wT[((size_t)tap * 64 + j * 16 + mm) * 32 + q * 8]);
#pragma unroll
        for (int row = 0; row < 2; ++row) {
#pragma unroll
            for (int xh = 0; xh < 2; ++xh) {
                short8 af = *reinterpret_cast<const short8*>(
                    &smem[((2 * wave + row + dy) * 34 + xh * 16 + dx + mm) * AP + q * 8]);
#pragma unroll
                for (int j = 0; j < 4; ++j)
                    acc[row][xh][j] = __builtin_amdgcn_mfma_f32_16x16x32_bf16(af, bf[j], acc[row][xh][j], 0, 0, 0);
            }
        }
    }
    __syncthreads();

    // stage pooled C into LDS: [local pooled pixel 0..63][CP]
    short* cst = smem;
#pragma unroll
    for (int xh = 0; xh < 2; ++xh) {
#pragma unroll
        for (int j = 0; j < 4; ++j) {
            const float bias = bfold[j * 16 + mm];
#pragma unroll
            for (int rp = 0; rp < 2; ++rp) {
                int pxl = xh * 8 + q * 2 + rp;            // 0..15
                float v = fmaxf(fmaxf(acc[0][xh][j][2 * rp], acc[0][xh][j][2 * rp + 1]),
                                fmaxf(acc[1][xh][j][2 * rp], acc[1][xh][j][2 * rp + 1]));
                v = fmaxf(v + bias, 0.0f);
                cst[(wave * 16 + pxl) * CP + j * 16 + mm] = f2bf(v);
            }
        }
    }
    __syncthreads();

    // coalesced copy-out: 64 px x 8 short8
    short* ob = out + (size_t)lb * PIX2 * CH2;
    for (int e = tid; e < 512; e += 256) {
        int pl = e >> 3, c8 = e & 7;
        int py = yt * 4 + (pl >> 4);
        int pxg = xt * 16 + (pl & 15);
        if (py < H2 && pxg < W2)
            *reinterpret_cast<short8*>(&ob[((size_t)py * W2 + pxg) * CH2 + c8 * 8]) =
                *reinterpret_cast<const short8*>(&cst[pl * CP + c8 * 8]);
    }
}

// ---------------------------------------------------------------------------
// K5-K8: 3x3 conv via bf16 MFMA; bf16 ch-last input; 32x4 tile.
// Round-9: KC=64 (AP=72) — one staging+barrier pair per 64 ic instead of
// two. Inner order `for ks: for tap` reproduces the KC=32 accumulation
// sequence exactly -> bit-identical results. Per-tap schedule unchanged.
// OM: 0 = bf16 ch-last out, 2 = bf16 ch-first [oc][KPAD].
// DUAL: grid.y = 24; sel = blockIdx.y/12 picks {wA,bA,oA} vs {wB,bB,oB}.
// ---------------------------------------------------------------------------
template <int IC, bool SIG, int OM, bool DUAL>
__global__ __launch_bounds__(256) void conv3x3_mfma(const short* __restrict__ in,
                                                    const short* __restrict__ wA,
                                                    const short* __restrict__ wB,
                                                    const float* __restrict__ bA,
                                                    const float* __restrict__ bB,
                                                    short* __restrict__ oA,
                                                    short* __restrict__ oB) {
    const int xt = blockIdx.x;                          // 0..2 (32 cols)
    const int yt = DUAL ? (blockIdx.y % 12) : blockIdx.y;   // 0..11 (4 rows)
    const int sel = DUAL ? (blockIdx.y / 12) : 0;
    const int lb = blockIdx.z;
    const int x0 = xt * 32, y0 = yt * 4;
    const int tid = threadIdx.x;
    const int wave = tid >> 6, lane = tid & 63;
    const int mm = lane & 15, q = lane >> 4;

    const short* wT = (DUAL && sel) ? wB : wA;
    const float* bfold = (DUAL && sel) ? bB : bA;
    short* outp = (DUAL && sel) ? oB : oA;

    constexpr int KC = 64;
    constexpr int NCH = IC / KC;       // 1 (IC=64) or 2 (IC=128)
    constexpr int AP = 72;             // KC + 8 pad
    constexpr int CP0 = 136;   // [pixel][128] stage stride (16B-aligned, 2-way banks)
    constexpr int CP2 = 132;   // [oc][pixel] stage stride (4B-aligned, distinct banks)
    // max(tileA 6*34*72=14,688, OM0 128*136=17,408, OM2 128*132=16,896) shorts
    __shared__ __align__(16) short smem[17408];

    floatx4 acc[16];
#pragma unroll
    for (int i = 0; i < 16; ++i) acc[i] = (floatx4){0.f, 0.f, 0.f, 0.f};

    const short* inb = in + (size_t)lb * PIX2 * IC;

    for (int c = 0; c < NCH; ++c) {
        const int ic0 = c * KC;
        for (int e = tid; e < 6 * 34 * (KC / 8); e += 256) {
            int dy = e / (34 * (KC / 8));
            int r  = e % (34 * (KC / 8));
            int tx = r / (KC / 8);
            int i8 = r % (KC / 8);
            int yin = y0 + dy - 1, xin = x0 + tx - 1;
            short8 hv = {0, 0, 0, 0, 0, 0, 0, 0};
            if (yin >= 0 && yin < H2 && xin >= 0 && xin < W2)
                hv = *reinterpret_cast<const short8*>(
                    &inb[((size_t)(yin * W2 + xin)) * IC + ic0 + i8 * 8]);
            *reinterpret_cast<short8*>(&smem[(dy * 34 + tx) * AP + i8 * 8]) = hv;
        }
        __syncthreads();

        const int oc0 = wave * 32 + mm;
#pragma unroll
        for (int ks = 0; ks < 2; ++ks) {
            const int ko = ks * 32;
#pragma unroll
            for (int tap = 0; tap < 9; ++tap) {
                const int dy = tap / 3, dx = tap % 3;
                short8 b0 = *reinterpret_cast<const short8*>(
                    &wT[((size_t)tap * 128 + oc0) * IC + ic0 + ko + q * 8]);
                short8 b1 = *reinterpret_cast<const short8*>(
                    &wT[((size_t)tap * 128 + oc0 + 16) * IC + ic0 + ko + q * 8]);
#pragma unroll
                for (int t = 0; t < 8; ++t) {
                    const int tr = t >> 1, tc = t & 1;
                    short8 af = *reinterpret_cast<const short8*>(
                        &smem[((tr + dy) * 34 + tc * 16 + dx + mm) * AP + ko + q * 8]);
                    acc[t * 2]     = __builtin_amdgcn_mfma_f32_16x16x32_bf16(af, b0, acc[t * 2], 0, 0, 0);
                    acc[t * 2 + 1] = __builtin_amdgcn_mfma_f32_16x16x32_bf16(af, b1, acc[t * 2 + 1], 0, 0, 0);
                }
            }
        }
        __syncthreads();
    }

    // stage C into LDS
    const int oc0 = wave * 32 + mm;
    const float bias0 = bfold[oc0];
    const float bias1 = bfold[oc0 + 16];
    short* cst = smem;
#pragma unroll
    for (int t = 0; t < 8; ++t) {
        const int tr = t >> 1, tc = t & 1;
#pragma unroll
        for (int r = 0; r < 4; ++r) {
            int pl = tr * 32 + tc * 16 + q * 4 + r;       // 0..127
            float z0 = acc[t * 2][r] + bias0;
            float z1 = acc[t * 2 + 1][r] + bias1;
            if (SIG) {
                z0 = 1.0f / (1.0f + expf(-z0));
                z1 = 1.0f / (1.0f + expf(-z1));
            } else {
                z0 = fmaxf(z0, 0.0f);
                z1 = fmaxf(z1, 0.0f);
            }
            if (OM == 0) {
                cst[pl * CP0 + oc0] = f2bf(z0);
                cst[pl * CP0 + oc0 + 16] = f2bf(z1);
            } else {
                cst[oc0 * CP2 + pl] = f2bf(z0);
                cst[(oc0 + 16) * CP2 + pl] = f2bf(z1);
            }
        }
    }
    __syncthreads();

    if (OM == 0) {
        short* ob = outp + (size_t)lb * PIX2 * 128;
        for (int e = tid; e < 2048; e += 256) {
            int pl = e >> 4, c8 = e & 15;
            int yy = y0 + (pl >> 5), xx = x0 + (pl & 31);
            if (yy < H2 && xx < W2)
                *reinterpret_cast<short8*>(&ob[((size_t)yy * W2 + xx) * 128 + c8 * 8]) =
                    *reinterpret_cast<const short8*>(&cst[pl * CP0 + c8 * 8]);
        }
    } else {
        short* ob = outp + (size_t)lb * 128 * KPAD;
        for (int e = tid; e < 8192; e += 256) {
            int oc = e >> 6;                   // 0..127
            int r2 = e & 63;
            int yy4 = r2 >> 4;                 // 0..3
            int x2 = (r2 & 15) * 2;            // 0..30
            int yy = y0 + yy4, xx = x0 + x2;
            if (yy < H2 && xx < W2) {
                int pl = yy4 * 32 + x2;
                if (xx + 1 < W2) {
                    *reinterpret_cast<int*>(&ob[(size_t)oc * KPAD + yy * W2 + xx]) =
                        *reinterpret_cast<const int*>(&cst[oc * CP2 + pl]);
                } else {
                    ob[(size_t)oc * KPAD + yy * W2 + xx] = cst[oc * CP2 + pl];
                }
            }
        }
    }
}

// ---------------------------------------------------------------------------
// K9: per-batch min/max of pp2 (bf16 ch-first [c][KPAD], valid hw < PIX2).
// Vectorized short8 loads; 8 channels per block; one atomic pair per block.
// ---------------------------------------------------------------------------
__global__ __launch_bounds__(256) void pminmax(const short* __restrict__ p,
                                               unsigned* __restrict__ pmm_bits) {
    const int cg = blockIdx.x;             // 0..15 (8 channels each)
    const int lb = blockIdx.y;
    const short* pb = p + (size_t)lb * 128 * KPAD + (size_t)cg * 8 * KPAD;
    float mn = INFINITY, mx = 0.0f;
#pragma unroll
    for (int c = 0; c < 8; ++c) {
        const short* pc = pb + (size_t)c * KPAD;
        for (int i8 = threadIdx.x; i8 < PIX2 / 8; i8 += 256) {   // 461 vectors
            short8 v = *reinterpret_cast<const short8*>(&pc[i8 * 8]);
#pragma unroll
            for (int j = 0; j < 8; ++j) {
                float f = b2f(v[j]);
                mn = fminf(mn, f);
                mx = fmaxf(mx, f);
            }
        }
        if (threadIdx.x < PIX2 - (PIX2 / 8) * 8) {               // tail: 2 elems
            float f = b2f(pc[(PIX2 / 8) * 8 + threadIdx.x]);
            mn = fminf(mn, f);
            mx = fmaxf(mx, f);
        }
    }
    __shared__ float rmn[256], rmx[256];
    rmn[threadIdx.x] = mn; rmx[threadIdx.x] = mx;
    __syncthreads();
    for (int s = 128; s > 0; s >>= 1) {
        if (threadIdx.x < s) {
            rmn[threadIdx.x] = fminf(rmn[threadIdx.x], rmn[threadIdx.x + s]);
            rmx[threadIdx.x] = fmaxf(rmx[threadIdx.x], rmx[threadIdx.x + s]);
        }
        __syncthreads();
    }
    if (threadIdx.x == 0) {
        atomicMin(&pmm_bits[lb * 2],     __float_as_uint(rmn[0]));
        atomicMax(&pmm_bits[lb * 2 + 1], __float_as_uint(rmx[0]));
    }
}

// ---------------------------------------------------------------------------
// K11a: K-split einsum via bf16 MFMA, pmap fused into A-staging.
// ---------------------------------------------------------------------------
__global__ __launch_bounds__(256) void einsum_part(const short* __restrict__ pp2,
                                                   const short* __restrict__ fxb,
                                                   const float* __restrict__ mm_,
                                                   float* __restrict__ px_part) {
    const int kc = blockIdx.x;   // 0..NKC-1
    const int lb = blockIdx.y;
    const int gb = gridDim.y;
    const int tid = threadIdx.x;
    const int wave = tid >> 6, lane = tid & 63;
    const int mm = lane & 15, q = lane >> 4;
    constexpr int AP = 72;
    __shared__ __align__(16) short As[128 * AP];
    __shared__ __align__(16) short Bs[128 * AP];

    const float mn = mm_[lb * 2];
    const float denom = fmaxf(mm_[lb * 2 + 1] - mn, 1e-4f);
    const float rden = 1.0f / denom;

    floatx4 acc[2][8];
#pragma unroll
    for (int a = 0; a < 2; ++a)
#pragma unroll
        for (int n = 0; n < 8; ++n) acc[a][n] = (floatx4){0.f, 0.f, 0.f, 0.f};

    const short* Ab = pp2 + (size_t)lb * 128 * KPAD;
    const short* Bb = fxb + (size_t)lb * 128 * KPAD;

    for (int it = 0; it < 8; ++it) {
        const int kk = kc * 512 + it * 64;
        if (kk >= KTOT) break;
        for (int e = tid; e < 2048; e += 256) {
            const bool isA = (e < 1024);
            const int e2 = isA ? e : e - 1024;
            const int row = e2 >> 3, i8 = e2 & 7;
            const int k = kk + i8 * 8;
            const short* src = (isA ? Ab : Bb) + (size_t)row * KPAD + k;
            short8 v = {0, 0, 0, 0, 0, 0, 0, 0};
            if (k + 8 <= KTOT) {
                v = *reinterpret_cast<const short8*>(src);
            } else {
#pragma unroll
                for (int j = 0; j < 8; ++j) v[j] = (k + j < KTOT) ? src[j] : (short)0;
            }
            if (isA) {
#pragma unroll
                for (int j = 0; j < 8; ++j) {
                    if (k + j < KTOT) {
                        float f = (b2f(v[j]) - mn) * rden;
                        v[j] = f2bf(1.0f / (1.0f + expf(-10.0f * (f - 0.5f))));
                    } else v[j] = 0;
                }
                *reinterpret_cast<short8*>(&As[row * AP + i8 * 8]) = v;
            } else {
                *reinterpret_cast<short8*>(&Bs[row * AP + i8 * 8]) = v;
            }
        }
        __syncthreads();
#pragma unroll
        for (int ks = 0; ks < 2; ++ks) {
            short8 af0 = *reinterpret_cast<const short8*>(&As[((2 * wave) * 16 + mm) * AP + ks * 32 + q * 8]);
            short8 af1 = *reinterpret_cast<const short8*>(&As[((2 * wave + 1) * 16 + mm) * AP + ks * 32 + q * 8]);
#pragma unroll
            for (int n = 0; n < 8; ++n) {
                short8 bf = *reinterpret_cast<const short8*>(&Bs[(n * 16 + mm) * AP + ks * 32 + q * 8]);
                acc[0][n] = __builtin_amdgcn_mfma_f32_16x16x32_bf16(af0, bf, acc[0][n], 0, 0, 0);
                acc[1][n] = __builtin_amdgcn_mfma_f32_16x16x32_bf16(af1, bf, acc[1][n], 0, 0, 0);
            }
        }
        __syncthreads();
    }

    float* base = px_part + ((size_t)kc * gb + lb) * EL_PX;
#pragma unroll
    for (int a = 0; a < 2; ++a) {
        const int gm0 = (2 * wave + a) * 16 + q * 4;
#pragma unroll
        for (int n = 0; n < 8; ++n) {
            const int gn = n * 16 + mm;
#pragma unroll
            for (int r = 0; r < 4; ++r)
                base[(size_t)(gm0 + r) * 128 + gn] = acc[a][n][r];
        }
    }
}

// ---------------------------------------------------------------------------
// K11b: reduce the NKC partials -> px (applies 1/3690)
// ---------------------------------------------------------------------------
__global__ __launch_bounds__(256) void px_reduce(const float* __restrict__ part,
                                                 float* __restrict__ px,
                                                 int gb) {
    int i = blockIdx.x * 256 + threadIdx.x;
    if (i >= gb * EL_PX) return;
    int lb = i / EL_PX;
    int r = i % EL_PX;
    float s = 0.0f;
#pragma unroll
    for (int kc = 0; kc < NKC; ++kc)
        s += part[((size_t)kc * gb + lb) * EL_PX + r];
    px[i] = s * (1.0f / (float)KTOT);
}

// ---------------------------------------------------------------------------
// K12: FC as split-K f32 GEMM. fc_w read exactly once.
// ---------------------------------------------------------------------------
__global__ __launch_bounds__(256) void fc_wt(const float* __restrict__ w,
                                             float* __restrict__ wT) {
    __shared__ float t[32][33];
    const int bk = blockIdx.x * 32;   // k tile (0..16383)
    const int bo = blockIdx.y * 32;   // o tile (0..255)
    const int tx = threadIdx.x & 31;
    const int ty = threadIdx.x >> 5;  // 0..7
#pragma unroll
    for (int r = 0; r < 4; ++r) {
        int o = bo + ty + r * 8;
        t[ty + r * 8][tx] = w[(size_t)o * EL_PX + bk + tx];
    }
    __syncthreads();
#pragma unroll
    for (int r = 0; r < 4; ++r) {
        int k = bk + ty + r * 8;
        wT[(size_t)k * 256 + bo + tx] = t[tx][ty + r * 8];
    }
}

__global__ __launch_bounds__(256) void fc_part(const float* __restrict__ px,
                                               const float* __restrict__ wT,
                                               float* __restrict__ part) {
    const int kc = blockIdx.x;          // 0..NKF-1
    const int o = threadIdx.x;          // 0..255
    const int k0 = kc * KCF;
    float acc[32];
#pragma unroll
    for (int lb = 0; lb < 32; ++lb) acc[lb] = 0.0f;

    for (int k8 = 0; k8 < KCF; k8 += 8) {
        float wv[8];
#pragma unroll
        for (int j = 0; j < 8; ++j)
            wv[j] = wT[(size_t)(k0 + k8 + j) * 256 + o];
#pragma unroll
        for (int lb = 0; lb < 32; ++lb) {
            const float* pc = px + (size_t)lb * EL_PX + k0 + k8;
            float4 p0 = *reinterpret_cast<const float4*>(pc);
            float4 p1 = *reinterpret_cast<const float4*>(pc + 4);
            acc[lb] += wv[0] * p0.x + wv[1] * p0.y + wv[2] * p0.z + wv[3] * p0.w
                     + wv[4] * p1.x + wv[5] * p1.y + wv[6] * p1.z + wv[7] * p1.w;
        }
    }
    float* pb = part + (size_t)kc * (32 * 256);
#pragma unroll
    for (int lb = 0; lb < 32; ++lb)
        pb[lb * 256 + o] = acc[lb];
}

__global__ __launch_bounds__(256) void fc_out(const float* __restrict__ part,
                                              const float* __restrict__ fcb,
                                              float* __restrict__ out) {
    const int i = blockIdx.x * 256 + threadIdx.x;   // 0..8191
    float s = 0.0f;
    for (int c = 0; c < NKF; ++c)
        s += part[(size_t)c * 8192 + i];
    out[i] = s + fcb[i & 255];
}

// ---------------------------------------------------------------------------
// K12 (fallback for GB<32): FC -> f32 out
// ---------------------------------------------------------------------------
__global__ __launch_bounds__(256) void fc_k(const float* __restrict__ px,
                                            const float* __restrict__ w,
                                            const float* __restrict__ bias,
                                            float* __restrict__ out,
                                            int b0) {
    const int gw = blockIdx.x * 4 + (threadIdx.x >> 6);
    const int lane = threadIdx.x & 63;
    const int lb = gw >> 8;
    const int o = gw & 255;
    const float* xb = px + (size_t)lb * EL_PX;
    const float* wr = w + (size_t)o * EL_PX;
    float s = 0.0f;
    for (int k = lane; k < EL_PX; k += 64) s += xb[k] * wr[k];
#pragma unroll
    for (int off = 32; off > 0; off >>= 1) s += __shfl_down(s, off);
    if (lane == 0) out[(size_t)(b0 + lb) * 256 + o] = s + bias[o];
}

// ---------------------------------------------------------------------------
extern "C" void kernel_launch(void* const* d_in, const int* in_sizes, int n_in,
                              void* d_out, int out_size, void* d_ws, size_t ws_size,
                              hipStream_t stream) {
    const float* x_t   = (const float*)d_in[0];
    const float* image = (const float*)d_in[1];
    const float* c1_w  = (const float*)d_in[2];
    const float* c1_b  = (const float*)d_in[3];
    const float* bn1_g = (const float*)d_in[4];
    const float* bn1_b = (const float*)d_in[5];
    const float* c2_w  = (const float*)d_in[6];
    const float* c2_b  = (const float*)d_in[7];
    const float* bn2_g = (const float*)d_in[8];
    const float* bn2_b = (const float*)d_in[9];
    const float* a1_w  = (const float*)d_in[10];
    const float* a1_b  = (const float*)d_in[11];
    const float* abn1_g= (const float*)d_in[12];
    const float* abn1_b= (const float*)d_in[13];
    const float* a2_w  = (const float*)d_in[14];
    const float* a2_b  = (const float*)d_in[15];
    const float* abn2_g= (const float*)d_in[16];
    const float* abn2_b= (const float*)d_in[17];
    const float* p1_w  = (const float*)d_in[18];
    const float* p1_b  = (const float*)d_in[19];
    const float* pbn1_g= (const float*)d_in[20];
    const float* pbn1_b= (const float*)d_in[21];
    const float* p2_w  = (const float*)d_in[22];
    const float* p2_b  = (const float*)d_in[23];
    const float* pbn2_g= (const float*)d_in[24];
    const float* pbn2_b= (const float*)d_in[25];
    const float* fc_w  = (const float*)d_in[26];
    const float* fc_b  = (const float*)d_in[27];
    float* outp = (float*)d_out;

    // Fixed region: folded bf16 weights + biases
    float* ws = (float*)d_ws;
    short* wTa1 = (short*)ws;
    short* wTa2 = wTa1 + WSH_A1;
    short* wTp1 = wTa2 + WSH_A2;
    short* wTp2 = wTp1 + WSH_A1;
    short* wTc2 = wTp2 + WSH_A2;
    float* bfa1 = ws + WSH_TOT / 2;
    float* bfa2 = bfa1 + 128;
    float* bfp1 = bfa2 + 128;
    float* bfp2 = bfp1 + 128;
    float* bfc2 = bfp2 + 128;
    float* dyn  = bfc2 + 128;
    const size_t fixed_floats = WSH_TOT / 2 + 1024;

    int GB = 32;
    while (GB > 1) {
        size_t need = ((size_t)GB * EL_PER_BATCH + fixed_floats + 256) * sizeof(float);
        if (need <= ws_size) break;
        GB >>= 1;
    }
    const int ngroups = NB / GB;

    float* heat = dyn;                                 // GB*EL_HEAT
    float* m    = heat + (size_t)GB * EL_HEAT;         // 64
    float* regB = m + 64;                              // GB*EL_REGB
    float* regC = regB + (size_t)GB * EL_REGB;         // GB*EL_REGC
    float* regD = regC + (size_t)GB * EL_REGC;         // GB*EL_REGD
    float* regE = regD + (size_t)GB * EL_REGD;         // GB*EL_REGE
    float* pmm  = regE + (size_t)GB * EL_REGE;         // 128
    float* px   = pmm + 128;                           // GB*EL_PX

    float* G      = regD;            // [lb][181][330] f32 (dead after rowcombine)
    short* out1b  = (short*)regB;    // bf16 ch-last [H1*W1][32]
    short* out2b  = (short*)regC;    // bf16 ch-last [pixel][64]
    short* fbuf   = (short*)regD;    // bf16 ch-last [pixel][128] (a1 out)
    short* fxbf   = (short*)regE;    // bf16 ch-first [c][KPAD]
    short* pp1    = (short*)regB;    // bf16 ch-last (out1 dead)
    short* pp2    = (short*)regD;    // bf16 ch-first [c][KPAD] (fbuf dead)
    float* pxpart = regB;            // f32, NKC*GB*EL_PX (pp1 dead after p2 conv)
    // FC-phase aliases (valid once einsum_part/px_reduce are done):
    float* fcwT   = regD;            // f32 wT[16384][256] (pp2 dead)
    float* fcpart = regB;            // f32 NKF*8192 (pxpart dead after px_reduce)

    wfold_k<<<(9 * 128 * CH2 + 255) / 256, 256, 0, stream>>>(a1_w, abn1_g, a1_b, abn1_b, wTa1, bfa1, 128, CH2);
    wfold_k<<<(9 * 128 * CH3 + 255) / 256, 256, 0, stream>>>(a2_w, abn2_g, a2_b, abn2_b, wTa2, bfa2, 128, CH3);
    wfold_k<<<(9 * 128 * CH2 + 255) / 256, 256, 0, stream>>>(p1_w, pbn1_g, p1_b, pbn1_b, wTp1, bfp1, 128, CH2);
    wfold_k<<<(9 * 128 * CH3 + 255) / 256, 256, 0, stream>>>(p2_w, pbn2_g, p2_b, pbn2_b, wTp2, bfp2, 128, CH3);
    wfold_k<<<(9 * 64 * 32 + 255) / 256, 256, 0, stream>>>(c2_w, bn2_g, c2_b, bn2_b, wTc2, bfc2, 64, 32);

    for (int gidx = 0; gidx < ngroups; ++gidx) {
        const int b0 = gidx * GB;
        mm_init<<<1, 256, 0, stream>>>((unsigned*)m, (unsigned*)pmm);
        heat_scatter_cols<<<dim3(NSTRIP, GB), 256, 0, stream>>>(x_t, G, b0);
        heat_rowcombine<<<dim3(IH / BXR, GB, 2), 256, 0, stream>>>(G, heat, (unsigned*)m);
        conv1_pool<<<(GB * H1 * W1 + 255) / 256, 256, 0, stream>>>(
            heat, image, m, c1_w, c1_b, bn1_g, bn1_b, out1b, b0, GB);
        conv2_mfma<<<dim3(6, 12, GB), 256, 0, stream>>>(out1b, wTc2, bfc2, out2b);
        // merged a1+p1 (shared input, disjoint outputs; per-block body = round-3)
        conv3x3_mfma<CH2, false, 0, true><<<dim3(3, 24, GB), 256, 0, stream>>>(
            out2b, wTa1, wTp1, bfa1, bfp1, fbuf, pp1);
        conv3x3_mfma<CH3, true,  2, false><<<dim3(3, 12, GB), 256, 0, stream>>>(
            fbuf, wTa2, wTa2, bfa2, bfa2, fxbf, fxbf);
        conv3x3_mfma<CH3, false, 2, false><<<dim3(3, 12, GB), 256, 0, stream>>>(
            pp1, wTp2, wTp2, bfp2, bfp2, pp2, pp2);
        pminmax<<<dim3(16, GB), 256, 0, stream>>>(pp2, (unsigned*)pmm);
        einsum_part<<<dim3(NKC, GB), 256, 0, stream>>>(pp2, fxbf, pmm, pxpart);
        px_reduce<<<(GB * EL_PX + 255) / 256, 256, 0, stream>>>(pxpart, px, GB);
        if (GB == 32) {
            fc_wt<<<dim3(EL_PX / 32, 256 / 32), 256, 0, stream>>>(fc_w, fcwT);
            fc_part<<<NKF, 256, 0, stream>>>(px, fcwT, fcpart);
            fc_out<<<8192 / 256, 256, 0, stream>>>(fcpart, fc_b, outp);
        } else {
            fc_k<<<GB * 64, 256, 0, stream>>>(px, fc_w, fc_b, outp, b0);
        }
    }
}

// Round 10
// 612.087 us; speedup vs baseline: 1.0231x; 1.0231x over previous
//
#include <hip/hip_runtime.h>
#include <hip/hip_bf16.h>

// Problem constants
#define NB 32
#define NT 1024
#define IH 180
#define IW 330
#define KSZ 37
#define XBINS 181
#define H1 90
#define W1 165
#define H2 45
#define W2 82
#define PIX2 (H2*W2)          // 3690
#define KTOT PIX2
#define KPAD 3712
#define CH1 32
#define CH2 64
#define CH3 128
#define NSTRIP 6
#define NKC 8                 // einsum K-chunks (512 each over KPAD)

// FC split-K config
#define NKF 256               // K-chunks for fc (16384/64)
#define KCF 64

// heat_rowcombine band config
#define BXR 12                // output rows per band (15 bands cover 180)
#define YHW 165               // half of IW
#define GROWS_MAX 54          // max staged G rows

// Per-batch f32-slot counts
#define EL_HEAT (IH*IW)           // 59,400
#define EL_REGB 237600            // out1 bf16 [H1*W1][32] -> pp1 bf16 [PIX2][128] -> px_part f32 -> fc partials
#define EL_REGC (CH2*PIX2/2)      // 118,080 : out2 bf16 ch-last [pixel][64]
#define EL_REGD (CH3*KPAD/2)      // 237,568 : G f32 -> fbuf bf16 -> pp2 bf16 [c][KPAD] -> wT f32
#define EL_REGE (CH3*KPAD/2)      // 237,568 : fx bf16 [c][KPAD]
#define EL_PX   (CH3*CH3)         // 16,384
#define EL_PER_BATCH (EL_HEAT + EL_REGB + EL_REGC + EL_REGD + EL_REGE + EL_PX) // 906,600

// folded-weight sizes (bf16 shorts)
#define WSH_A1 (9*128*64)
#define WSH_A2 (9*128*128)
#define WSH_C2 (9*64*32)
#define WSH_TOT (2*WSH_A1 + 2*WSH_A2 + WSH_C2)

typedef __attribute__((ext_vector_type(8))) short short8;
typedef __attribute__((ext_vector_type(4))) float floatx4;

__device__ __forceinline__ short f2bf(float v) {
    __hip_bfloat16 h = __float2bfloat16(v);
    return *reinterpret_cast<short*>(&h);
}
__device__ __forceinline__ float b2f(short s) {
    __hip_bfloat16 h = *reinterpret_cast<__hip_bfloat16*>(&s);
    return __bfloat162float(h);
}

// ---------------------------------------------------------------------------
__global__ __launch_bounds__(256) void mm_init(unsigned* __restrict__ m_bits,
                                               unsigned* __restrict__ pmm_bits) {
    int i = threadIdx.x;
    if (i < 64) {
        m_bits[i] = 0u;
        pmm_bits[2 * i]     = 0x7F800000u;   // +inf
        pmm_bits[2 * i + 1] = 0u;
    }
}

// ---------------------------------------------------------------------------
// S1: separable scatter — column profiles into G[xp][Y]
// ---------------------------------------------------------------------------
__global__ __launch_bounds__(256) void heat_scatter_cols(const float* __restrict__ x_t,
                                                         float* __restrict__ G,
                                                         int b0) {
    const int strip = blockIdx.x;
    const int lb = blockIdx.y;
    const int b = b0 + lb;
    const int c0 = strip * 64;
    const int cw = min(64, IW - c0);
    __shared__ float g[XBINS * 64];
    __shared__ float k1n[64];
    __shared__ float2 pts[NT];
    const int tid = threadIdx.x;

    if (tid < 64) {
        float v = 0.0f;
        if (tid < KSZ) {
            float ax = (float)tid - 18.0f;
            v = expf(-ax * ax / 18.0f);
        }
        k1n[tid] = v;
    }
    for (int i = tid; i < XBINS * 64; i += 256) g[i] = 0.0f;
    {
        const float2* xb = (const float2*)x_t + (size_t)b * NT;
        for (int i = tid; i < NT; i += 256) pts[i] = xb[i];
    }
    __syncthreads();
    if (tid == 0) {
        float s = 0.0f;
        for (int i = 0; i < KSZ; i++) s += k1n[i];
        float inv = 1.0f / s;
        for (int i = 0; i < KSZ; i++) k1n[i] *= inv;
    }
    __syncthreads();

    const int wave = tid >> 6;
    const int lane = tid & 63;
    const float kc = k1n[lane];

    for (int p = wave; p < NT; p += 4) {
        float x = pts[p].x, y = pts[p].y;
        if (isnan(x) || isnan(y)) continue;
        int xp = IH - (int)((x - 30.0f) * 180.0f);
        xp = min(max(xp, 0), 180);
        int yp = (int)((y - 120.0f) * 165.0f);
        int ys = min(max(yp - 18, 0), IW - 36);
        int ye = min(max(yp + 18, 0), IW);
        int nc = ye - ys;
        int col = ys + lane;
        if (lane < nc && col >= c0 && col < c0 + cw)
            atomicAdd(&g[xp * 64 + col - c0], kc);
    }
    __syncthreads();
    for (int i = tid; i < XBINS * cw; i += 256) {
        int row = i / cw, col = i % cw;
        G[((size_t)lb * XBINS + row) * IW + c0 + col] = g[row * 64 + col];
    }
}

// ---------------------------------------------------------------------------
// S2: row-combine + fused per-batch max (band-tiled, LDS-staged G)
// ---------------------------------------------------------------------------
__global__ __launch_bounds__(256) void heat_rowcombine(const float* __restrict__ G,
                                                       float* __restrict__ heat,
                                                       unsigned* __restrict__ m_bits) {
    const int band = blockIdx.x;        // 0..14
    const int lb = blockIdx.y;
    const int half = blockIdx.z;        // 0..1
    const int X0 = band * BXR;
    const int c0 = half * YHW;
    const int tid = threadIdx.x;

    __shared__ float k1n[64];
    __shared__ float gs[GROWS_MAX * YHW];   // 35,640 B
    __shared__ float red[256];

    if (tid < 64) {
        float v = 0.0f;
        if (tid < KSZ) {
            float ax = (float)tid - 18.0f;
            v = expf(-ax * ax / 18.0f);
        }
        k1n[tid] = v;
    }

    const int rlo = max(0, X0 - 17);
    const int rhi = (X0 + BXR - 1 >= IH - 36) ? 180 : (X0 + BXR - 1 + 18);
    const int nrows = rhi - rlo + 1;        // <= 54
    const float* Gb = G + (size_t)lb * XBINS * IW;
    for (int i = tid; i < nrows * YHW; i += 256) {
        int r = i / YHW, y = i % YHW;
        gs[i] = Gb[(size_t)(rlo + r) * IW + c0 + y];
    }
    __syncthreads();
    if (tid == 0) {
        float s = 0.0f;
        for (int i = 0; i < KSZ; i++) s += k1n[i];
        float inv = 1.0f / s;
        for (int i = 0; i < KSZ; i++) k1n[i] *= inv;
    }
    __syncthreads();

    float lmax = 0.0f;
    for (int p = tid; p < BXR * YHW; p += 256) {
        const int xr = p / YHW;
        const int yy = p % YHW;
        const int X = X0 + xr;
        const int Y = c0 + yy;
        const int lo = max(0, X - 17);
        const int hi = (X >= IH - 36) ? 180 : X + 18;
        float s = 0.0f;
        for (int xp = lo; xp <= hi; ++xp) {
            int xs = min(max(xp - 18, 0), IH - 36);
            s += k1n[X - xs] * gs[(xp - rlo) * YHW + yy];
        }
        heat[(size_t)lb * EL_HEAT + (size_t)X * IW + Y] = s;
        lmax = fmaxf(lmax, s);
    }
    red[tid] = lmax;
    __syncthreads();
    for (int st = 128; st > 0; st >>= 1) {
        if (tid < st) red[tid] = fmaxf(red[tid], red[tid + st]);
        __syncthreads();
    }
    if (tid == 0) atomicMax(&m_bits[lb], __float_as_uint(red[0]));
}

// ---------------------------------------------------------------------------
// K3: conv1(1->32) + BN + relu + pool (fuse folded); out bf16 ch-last [pix][32]
// ---------------------------------------------------------------------------
__global__ __launch_bounds__(256) void conv1_pool(const float* __restrict__ heat,
                                                  const float* __restrict__ image,
                                                  const float* __restrict__ m,
                                                  const float* __restrict__ w,
                                                  const float* __restrict__ cb,
                                                  const float* __restrict__ g,
                                                  const float* __restrict__ bb,
                                                  short* __restrict__ out1,
                                                  int b0, int gb) {
    __shared__ float ws_[CH1 * 9];
    __shared__ float bs_[CH1];
    const int tid = threadIdx.x;
    for (int i = tid; i < CH1 * 9; i += 256) {
        int oc = i / 9;
        ws_[i] = w[i] * g[oc];
    }
    if (tid < CH1) bs_[tid] = cb[tid] * g[tid] + bb[tid];
    __syncthreads();

    int t = blockIdx.x * 256 + tid;
    if (t >= gb * H1 * W1) return;
    int lb = t / (H1 * W1);
    int r = t % (H1 * W1);
    int py = r / W1, px = r % W1;
    const float s = 0.7f / (m[lb] + 1e-10f);
    const float* hb = heat + (size_t)lb * EL_HEAT;
    const float* ib = image + (size_t)(b0 + lb) * EL_HEAT;

    float v[4][4];
    int y0 = 2 * py - 1, x0 = 2 * px - 1;
#pragma unroll
    for (int i = 0; i < 4; i++) {
#pragma unroll
        for (int j = 0; j < 4; j++) {
            int y = y0 + i, x = x0 + j;
            float val = 0.0f;
            if (y >= 0 && y < IH && x >= 0 && x < IW) {
                size_t idx = (size_t)y * IW + x;
                val = s * hb[idx] + 0.3f * ib[idx];
            }
            v[i][j] = val;
        }
    }
    short8 pk[4];
#pragma unroll
    for (int oc = 0; oc < CH1; oc++) {
        float a00 = 0, a01 = 0, a10 = 0, a11 = 0;
        const float* wp = &ws_[oc * 9];
#pragma unroll
        for (int ky = 0; ky < 3; ky++) {
#pragma unroll
            for (int kx = 0; kx < 3; kx++) {
                float wv = wp[ky * 3 + kx];
                a00 += wv * v[ky][kx];
                a01 += wv * v[ky][kx + 1];
                a10 += wv * v[ky + 1][kx];
                a11 += wv * v[ky + 1][kx + 1];
            }
        }
        float bias = bs_[oc];
        a00 = fmaxf(a00 + bias, 0.0f);
        a01 = fmaxf(a01 + bias, 0.0f);
        a10 = fmaxf(a10 + bias, 0.0f);
        a11 = fmaxf(a11 + bias, 0.0f);
        pk[oc >> 3][oc & 7] = f2bf(fmaxf(fmaxf(a00, a01), fmaxf(a10, a11)));
    }
    short8* op = reinterpret_cast<short8*>(&out1[((size_t)lb * H1 * W1 + r) * CH1]);
#pragma unroll
    for (int vv = 0; vv < 4; vv++) op[vv] = pk[vv];
}

// ---------------------------------------------------------------------------
// weight fold/transpose: wT[tap][oc][ic] = bf16(w[oc][ic][tap]*g[oc])
// ---------------------------------------------------------------------------
__global__ __launch_bounds__(256) void wfold_k(const float* __restrict__ w,
                                               const float* __restrict__ g,
                                               const float* __restrict__ cb,
                                               const float* __restrict__ bb,
                                               short* __restrict__ wT,
                                               float* __restrict__ bfold,
                                               int OC, int IC) {
    int i = blockIdx.x * 256 + threadIdx.x;
    int n = 9 * OC * IC;
    if (i >= n) return;
    int tap = i / (OC * IC);
    int r = i % (OC * IC);
    int oc = r / IC;
    int ic = r % IC;
    wT[i] = f2bf(w[((size_t)oc * IC + ic) * 9 + tap] * g[oc]);
    if (tap == 0 && ic == 0) bfold[oc] = cb[oc] * g[oc] + bb[oc];
}

// ---------------------------------------------------------------------------
// K4: conv2(32->64) + BN + relu + 2x2 pool via bf16 MFMA.
// ---------------------------------------------------------------------------
__global__ __launch_bounds__(256) void conv2_mfma(const short* __restrict__ in,
                                                  const short* __restrict__ wT,
                                                  const float* __restrict__ bfold,
                                                  short* __restrict__ out) {
    const int xt = blockIdx.x;   // 0..5 : 32 pre-pool cols
    const int yt = blockIdx.y;   // 0..11: 8 pre-pool rows
    const int lb = blockIdx.z;
    const int x0 = xt * 32, y0 = yt * 8;
    const int tid = threadIdx.x;
    const int wave = tid >> 6, lane = tid & 63;
    const int mm = lane & 15, q = lane >> 4;
    constexpr int AP = 40;
    constexpr int CP = 72;                      // C-stage stride (16B-aligned rows)
    __shared__ __align__(16) short smem[10 * 34 * AP];   // 27,200 B (>= 64*CP=9,216)

    floatx4 acc[2][2][4];
#pragma unroll
    for (int a = 0; a < 2; ++a)
#pragma unroll
        for (int bq = 0; bq < 2; ++bq)
#pragma unroll
            for (int j = 0; j < 4; ++j) acc[a][bq][j] = (floatx4){0.f, 0.f, 0.f, 0.f};

    const short* inb = in + (size_t)lb * (H1 * W1) * CH1;
    for (int e = tid; e < 10 * 34 * 4; e += 256) {
        int dy = e / (34 * 4);
        int r = e % (34 * 4);
        int tx = r / 4;
        int i8 = r % 4;
        int yin = y0 + dy - 1, xin = x0 + tx - 1;
        short8 hv = {0, 0, 0, 0, 0, 0, 0, 0};
        if (yin >= 0 && yin < H1 && xin >= 0 && xin < W1)
            hv = *reinterpret_cast<const short8*>(&inb[((size_t)(yin * W1 + xin)) * CH1 + i8 * 8]);
        *reinterpret_cast<short8*>(&smem[(dy * 34 + tx) * AP + i8 * 8]) = hv;
    }
    __syncthreads();

#pragma unroll
    for (int tap = 0; tap < 9; ++tap) {
        const int dy = tap / 3, dx = tap % 3;
        short8 bf[4];
#pragma unroll
        for (int j = 0; j < 4; ++j)
            bf[j] = *reinterpret_cast<const short8*>(&wT[((size_t)tap * 64 + j * 16 + mm) * 32 + q * 8]);
#pragma unroll
        for (int row = 0; row < 2; ++row) {
#pragma unroll
            for (int xh = 0; xh < 2; ++xh) {
                short8 af = *reinterpret_cast<const short8*>(
                    &smem[((2 * wave + row + dy) * 34 + xh * 16 + dx + mm) * AP + q * 8]);
#pragma unroll
                for (int j = 0; j < 4; ++j)
                    acc[row][xh][j] = __builtin_amdgcn_mfma_f32_16x16x32_bf16(af, bf[j], acc[row][xh][j], 0, 0, 0);
            }
        }
    }
    __syncthreads();

    // stage pooled C into LDS: [local pooled pixel 0..63][CP]
    short* cst = smem;
#pragma unroll
    for (int xh = 0; xh < 2; ++xh) {
#pragma unroll
        for (int j = 0; j < 4; ++j) {
            const float bias = bfold[j * 16 + mm];
#pragma unroll
            for (int rp = 0; rp < 2; ++rp) {
                int pxl = xh * 8 + q * 2 + rp;            // 0..15
                float v = fmaxf(fmaxf(acc[0][xh][j][2 * rp], acc[0][xh][j][2 * rp + 1]),
                                fmaxf(acc[1][xh][j][2 * rp], acc[1][xh][j][2 * rp + 1]));
                v = fmaxf(v + bias, 0.0f);
                cst[(wave * 16 + pxl) * CP + j * 16 + mm] = f2bf(v);
            }
        }
    }
    __syncthreads();

    // coalesced copy-out: 64 px x 8 short8
    short* ob = out + (size_t)lb * PIX2 * CH2;
    for (int e = tid; e < 512; e += 256) {
        int pl = e >> 3, c8 = e & 7;
        int py = yt * 4 + (pl >> 4);
        int pxg = xt * 16 + (pl & 15);
        if (py < H2 && pxg < W2)
            *reinterpret_cast<short8*>(&ob[((size_t)py * W2 + pxg) * CH2 + c8 * 8]) =
                *reinterpret_cast<const short8*>(&cst[pl * CP + c8 * 8]);
    }
}

// ---------------------------------------------------------------------------
// K5-K8: 3x3 conv via bf16 MFMA; bf16 ch-last input; 32x4 tile.
// (exact round-3 structure — known good; KC=32; frozen)
// OM: 0 = bf16 ch-last out, 2 = bf16 ch-first [oc][KPAD].
// DUAL: grid.y = 24; sel = blockIdx.y/12 picks {wA,bA,oA} vs {wB,bB,oB}.
// ---------------------------------------------------------------------------
template <int IC, bool SIG, int OM, bool DUAL>
__global__ __launch_bounds__(256) void conv3x3_mfma(const short* __restrict__ in,
                                                    const short* __restrict__ wA,
                                                    const short* __restrict__ wB,
                                                    const float* __restrict__ bA,
                                                    const float* __restrict__ bB,
                                                    short* __restrict__ oA,
                                                    short* __restrict__ oB) {
    const int xt = blockIdx.x;                          // 0..2 (32 cols)
    const int yt = DUAL ? (blockIdx.y % 12) : blockIdx.y;   // 0..11 (4 rows)
    const int sel = DUAL ? (blockIdx.y / 12) : 0;
    const int lb = blockIdx.z;
    const int x0 = xt * 32, y0 = yt * 4;
    const int tid = threadIdx.x;
    const int wave = tid >> 6, lane = tid & 63;
    const int mm = lane & 15, q = lane >> 4;

    const short* wT = (DUAL && sel) ? wB : wA;
    const float* bfold = (DUAL && sel) ? bB : bA;
    short* outp = (DUAL && sel) ? oB : oA;

    constexpr int KC = 32;
    constexpr int NCH = IC / KC;
    constexpr int AP = 40;
    constexpr int CP0 = 136;   // [pixel][128] stage stride (16B-aligned, 2-way banks)
    constexpr int CP2 = 132;   // [oc][pixel] stage stride (4B-aligned, distinct banks)
    // max(tileA 8160, OM0 128*136=17408, OM2 128*132=16896) shorts
    __shared__ __align__(16) short smem[17408];

    floatx4 acc[16];
#pragma unroll
    for (int i = 0; i < 16; ++i) acc[i] = (floatx4){0.f, 0.f, 0.f, 0.f};

    const short* inb = in + (size_t)lb * PIX2 * IC;

    for (int c = 0; c < NCH; ++c) {
        const int ic0 = c * KC;
        for (int e = tid; e < 6 * 34 * (KC / 8); e += 256) {
            int dy = e / (34 * (KC / 8));
            int r  = e % (34 * (KC / 8));
            int tx = r / (KC / 8);
            int i8 = r % (KC / 8);
            int yin = y0 + dy - 1, xin = x0 + tx - 1;
            short8 hv = {0, 0, 0, 0, 0, 0, 0, 0};
            if (yin >= 0 && yin < H2 && xin >= 0 && xin < W2)
                hv = *reinterpret_cast<const short8*>(
                    &inb[((size_t)(yin * W2 + xin)) * IC + ic0 + i8 * 8]);
            *reinterpret_cast<short8*>(&smem[(dy * 34 + tx) * AP + i8 * 8]) = hv;
        }
        __syncthreads();

        const int oc0 = wave * 32 + mm;
#pragma unroll
        for (int tap = 0; tap < 9; ++tap) {
            const int dy = tap / 3, dx = tap % 3;
            short8 b0 = *reinterpret_cast<const short8*>(
                &wT[((size_t)tap * 128 + oc0) * IC + ic0 + q * 8]);
            short8 b1 = *reinterpret_cast<const short8*>(
                &wT[((size_t)tap * 128 + oc0 + 16) * IC + ic0 + q * 8]);
#pragma unroll
            for (int t = 0; t < 8; ++t) {
                const int tr = t >> 1, tc = t & 1;
                short8 af = *reinterpret_cast<const short8*>(
                    &smem[((tr + dy) * 34 + tc * 16 + dx + mm) * AP + q * 8]);
                acc[t * 2]     = __builtin_amdgcn_mfma_f32_16x16x32_bf16(af, b0, acc[t * 2], 0, 0, 0);
                acc[t * 2 + 1] = __builtin_amdgcn_mfma_f32_16x16x32_bf16(af, b1, acc[t * 2 + 1], 0, 0, 0);
            }
        }
        __syncthreads();
    }

    // stage C into LDS
    const int oc0 = wave * 32 + mm;
    const float bias0 = bfold[oc0];
    const float bias1 = bfold[oc0 + 16];
    short* cst = smem;
#pragma unroll
    for (int t = 0; t < 8; ++t) {
        const int tr = t >> 1, tc = t & 1;
#pragma unroll
        for (int r = 0; r < 4; ++r) {
            int pl = tr * 32 + tc * 16 + q * 4 + r;       // 0..127
            float z0 = acc[t * 2][r] + bias0;
            float z1 = acc[t * 2 + 1][r] + bias1;
            if (SIG) {
                z0 = 1.0f / (1.0f + expf(-z0));
                z1 = 1.0f / (1.0f + expf(-z1));
            } else {
                z0 = fmaxf(z0, 0.0f);
                z1 = fmaxf(z1, 0.0f);
            }
            if (OM == 0) {
                cst[pl * CP0 + oc0] = f2bf(z0);
                cst[pl * CP0 + oc0 + 16] = f2bf(z1);
            } else {
                cst[oc0 * CP2 + pl] = f2bf(z0);
                cst[(oc0 + 16) * CP2 + pl] = f2bf(z1);
            }
        }
    }
    __syncthreads();

    if (OM == 0) {
        short* ob = outp + (size_t)lb * PIX2 * 128;
        for (int e = tid; e < 2048; e += 256) {
            int pl = e >> 4, c8 = e & 15;
            int yy = y0 + (pl >> 5), xx = x0 + (pl & 31);
            if (yy < H2 && xx < W2)
                *reinterpret_cast<short8*>(&ob[((size_t)yy * W2 + xx) * 128 + c8 * 8]) =
                    *reinterpret_cast<const short8*>(&cst[pl * CP0 + c8 * 8]);
        }
    } else {
        short* ob = outp + (size_t)lb * 128 * KPAD;
        for (int e = tid; e < 8192; e += 256) {
            int oc = e >> 6;                   // 0..127
            int r2 = e & 63;
            int yy4 = r2 >> 4;                 // 0..3
            int x2 = (r2 & 15) * 2;            // 0..30
            int yy = y0 + yy4, xx = x0 + x2;
            if (yy < H2 && xx < W2) {
                int pl = yy4 * 32 + x2;
                if (xx + 1 < W2) {
                    *reinterpret_cast<int*>(&ob[(size_t)oc * KPAD + yy * W2 + xx]) =
                        *reinterpret_cast<const int*>(&cst[oc * CP2 + pl]);
                } else {
                    ob[(size_t)oc * KPAD + yy * W2 + xx] = cst[oc * CP2 + pl];
                }
            }
        }
    }
}

// ---------------------------------------------------------------------------
// K9: per-batch min/max of pp2 (bf16 ch-first [c][KPAD], valid hw < PIX2).
// Vectorized short8 loads; 8 channels per block; one atomic pair per block.
// ---------------------------------------------------------------------------
__global__ __launch_bounds__(256) void pminmax(const short* __restrict__ p,
                                               unsigned* __restrict__ pmm_bits) {
    const int cg = blockIdx.x;             // 0..15 (8 channels each)
    const int lb = blockIdx.y;
    const short* pb = p + (size_t)lb * 128 * KPAD + (size_t)cg * 8 * KPAD;
    float mn = INFINITY, mx = 0.0f;
#pragma unroll
    for (int c = 0; c < 8; ++c) {
        const short* pc = pb + (size_t)c * KPAD;
        for (int i8 = threadIdx.x; i8 < PIX2 / 8; i8 += 256) {   // 461 vectors
            short8 v = *reinterpret_cast<const short8*>(&pc[i8 * 8]);
#pragma unroll
            for (int j = 0; j < 8; ++j) {
                float f = b2f(v[j]);
                mn = fminf(mn, f);
                mx = fmaxf(mx, f);
            }
        }
        if (threadIdx.x < PIX2 - (PIX2 / 8) * 8) {               // tail: 2 elems
            float f = b2f(pc[(PIX2 / 8) * 8 + threadIdx.x]);
            mn = fminf(mn, f);
            mx = fmaxf(mx, f);
        }
    }
    __shared__ float rmn[256], rmx[256];
    rmn[threadIdx.x] = mn; rmx[threadIdx.x] = mx;
    __syncthreads();
    for (int s = 128; s > 0; s >>= 1) {
        if (threadIdx.x < s) {
            rmn[threadIdx.x] = fminf(rmn[threadIdx.x], rmn[threadIdx.x + s]);
            rmx[threadIdx.x] = fmaxf(rmx[threadIdx.x], rmx[threadIdx.x + s]);
        }
        __syncthreads();
    }
    if (threadIdx.x == 0) {
        atomicMin(&pmm_bits[lb * 2],     __float_as_uint(rmn[0]));
        atomicMax(&pmm_bits[lb * 2 + 1], __float_as_uint(rmx[0]));
    }
}

// ---------------------------------------------------------------------------
// K11a: K-split einsum via bf16 MFMA, pmap fused into A-staging.
// ---------------------------------------------------------------------------
__global__ __launch_bounds__(256) void einsum_part(const short* __restrict__ pp2,
                                                   const short* __restrict__ fxb,
                                                   const float* __restrict__ mm_,
                                                   float* __restrict__ px_part) {
    const int kc = blockIdx.x;   // 0..NKC-1
    const int lb = blockIdx.y;
    const int gb = gridDim.y;
    const int tid = threadIdx.x;
    const int wave = tid >> 6, lane = tid & 63;
    const int mm = lane & 15, q = lane >> 4;
    constexpr int AP = 72;
    __shared__ __align__(16) short As[128 * AP];
    __shared__ __align__(16) short Bs[128 * AP];

    const float mn = mm_[lb * 2];
    const float denom = fmaxf(mm_[lb * 2 + 1] - mn, 1e-4f);
    const float rden = 1.0f / denom;

    floatx4 acc[2][8];
#pragma unroll
    for (int a = 0; a < 2; ++a)
#pragma unroll
        for (int n = 0; n < 8; ++n) acc[a][n] = (floatx4){0.f, 0.f, 0.f, 0.f};

    const short* Ab = pp2 + (size_t)lb * 128 * KPAD;
    const short* Bb = fxb + (size_t)lb * 128 * KPAD;

    for (int it = 0; it < 8; ++it) {
        const int kk = kc * 512 + it * 64;
        if (kk >= KTOT) break;
        for (int e = tid; e < 2048; e += 256) {
            const bool isA = (e < 1024);
            const int e2 = isA ? e : e - 1024;
            const int row = e2 >> 3, i8 = e2 & 7;
            const int k = kk + i8 * 8;
            const short* src = (isA ? Ab : Bb) + (size_t)row * KPAD + k;
            short8 v = {0, 0, 0, 0, 0, 0, 0, 0};
            if (k + 8 <= KTOT) {
                v = *reinterpret_cast<const short8*>(src);
            } else {
#pragma unroll
                for (int j = 0; j < 8; ++j) v[j] = (k + j < KTOT) ? src[j] : (short)0;
            }
            if (isA) {
#pragma unroll
                for (int j = 0; j < 8; ++j) {
                    if (k + j < KTOT) {
                        float f = (b2f(v[j]) - mn) * rden;
                        v[j] = f2bf(1.0f / (1.0f + expf(-10.0f * (f - 0.5f))));
                    } else v[j] = 0;
                }
                *reinterpret_cast<short8*>(&As[row * AP + i8 * 8]) = v;
            } else {
                *reinterpret_cast<short8*>(&Bs[row * AP + i8 * 8]) = v;
            }
        }
        __syncthreads();
#pragma unroll
        for (int ks = 0; ks < 2; ++ks) {
            short8 af0 = *reinterpret_cast<const short8*>(&As[((2 * wave) * 16 + mm) * AP + ks * 32 + q * 8]);
            short8 af1 = *reinterpret_cast<const short8*>(&As[((2 * wave + 1) * 16 + mm) * AP + ks * 32 + q * 8]);
#pragma unroll
            for (int n = 0; n < 8; ++n) {
                short8 bf = *reinterpret_cast<const short8*>(&Bs[(n * 16 + mm) * AP + ks * 32 + q * 8]);
                acc[0][n] = __builtin_amdgcn_mfma_f32_16x16x32_bf16(af0, bf, acc[0][n], 0, 0, 0);
                acc[1][n] = __builtin_amdgcn_mfma_f32_16x16x32_bf16(af1, bf, acc[1][n], 0, 0, 0);
            }
        }
        __syncthreads();
    }

    float* base = px_part + ((size_t)kc * gb + lb) * EL_PX;
#pragma unroll
    for (int a = 0; a < 2; ++a) {
        const int gm0 = (2 * wave + a) * 16 + q * 4;
#pragma unroll
        for (int n = 0; n < 8; ++n) {
            const int gn = n * 16 + mm;
#pragma unroll
            for (int r = 0; r < 4; ++r)
                base[(size_t)(gm0 + r) * 128 + gn] = acc[a][n][r];
        }
    }
}

// ---------------------------------------------------------------------------
// K11b: reduce the NKC partials -> px (applies 1/3690)
// ---------------------------------------------------------------------------
__global__ __launch_bounds__(256) void px_reduce(const float* __restrict__ part,
                                                 float* __restrict__ px,
                                                 int gb) {
    int i = blockIdx.x * 256 + threadIdx.x;
    if (i >= gb * EL_PX) return;
    int lb = i / EL_PX;
    int r = i % EL_PX;
    float s = 0.0f;
#pragma unroll
    for (int kc = 0; kc < NKC; ++kc)
        s += part[((size_t)kc * gb + lb) * EL_PX + r];
    px[i] = s * (1.0f / (float)KTOT);
}

// ---------------------------------------------------------------------------
// K12: FC as split-K f32 GEMM. fc_w read exactly once.
// ---------------------------------------------------------------------------
__global__ __launch_bounds__(256) void fc_wt(const float* __restrict__ w,
                                             float* __restrict__ wT) {
    __shared__ float t[32][33];
    const int bk = blockIdx.x * 32;   // k tile (0..16383)
    const int bo = blockIdx.y * 32;   // o tile (0..255)
    const int tx = threadIdx.x & 31;
    const int ty = threadIdx.x >> 5;  // 0..7
#pragma unroll
    for (int r = 0; r < 4; ++r) {
        int o = bo + ty + r * 8;
        t[ty + r * 8][tx] = w[(size_t)o * EL_PX + bk + tx];
    }
    __syncthreads();
#pragma unroll
    for (int r = 0; r < 4; ++r) {
        int k = bk + ty + r * 8;
        wT[(size_t)k * 256 + bo + tx] = t[tx][ty + r * 8];
    }
}

__global__ __launch_bounds__(256) void fc_part(const float* __restrict__ px,
                                               const float* __restrict__ wT,
                                               float* __restrict__ part) {
    const int kc = blockIdx.x;          // 0..NKF-1
    const int o = threadIdx.x;          // 0..255
    const int k0 = kc * KCF;
    float acc[32];
#pragma unroll
    for (int lb = 0; lb < 32; ++lb) acc[lb] = 0.0f;

    for (int k8 = 0; k8 < KCF; k8 += 8) {
        float wv[8];
#pragma unroll
        for (int j = 0; j < 8; ++j)
            wv[j] = wT[(size_t)(k0 + k8 + j) * 256 + o];
#pragma unroll
        for (int lb = 0; lb < 32; ++lb) {
            const float* pc = px + (size_t)lb * EL_PX + k0 + k8;
            float4 p0 = *reinterpret_cast<const float4*>(pc);
            float4 p1 = *reinterpret_cast<const float4*>(pc + 4);
            acc[lb] += wv[0] * p0.x + wv[1] * p0.y + wv[2] * p0.z + wv[3] * p0.w
                     + wv[4] * p1.x + wv[5] * p1.y + wv[6] * p1.z + wv[7] * p1.w;
        }
    }
    float* pb = part + (size_t)kc * (32 * 256);
#pragma unroll
    for (int lb = 0; lb < 32; ++lb)
        pb[lb * 256 + o] = acc[lb];
}

__global__ __launch_bounds__(256) void fc_out(const float* __restrict__ part,
                                              const float* __restrict__ fcb,
                                              float* __restrict__ out) {
    const int i = blockIdx.x * 256 + threadIdx.x;   // 0..8191
    float s = 0.0f;
    for (int c = 0; c < NKF; ++c)
        s += part[(size_t)c * 8192 + i];
    out[i] = s + fcb[i & 255];
}

// ---------------------------------------------------------------------------
// K12 (fallback for GB<32): FC -> f32 out
// ---------------------------------------------------------------------------
__global__ __launch_bounds__(256) void fc_k(const float* __restrict__ px,
                                            const float* __restrict__ w,
                                            const float* __restrict__ bias,
                                            float* __restrict__ out,
                                            int b0) {
    const int gw = blockIdx.x * 4 + (threadIdx.x >> 6);
    const int lane = threadIdx.x & 63;
    const int lb = gw >> 8;
    const int o = gw & 255;
    const float* xb = px + (size_t)lb * EL_PX;
    const float* wr = w + (size_t)o * EL_PX;
    float s = 0.0f;
    for (int k = lane; k < EL_PX; k += 64) s += xb[k] * wr[k];
#pragma unroll
    for (int off = 32; off > 0; off >>= 1) s += __shfl_down(s, off);
    if (lane == 0) out[(size_t)(b0 + lb) * 256 + o] = s + bias[o];
}

// ---------------------------------------------------------------------------
extern "C" void kernel_launch(void* const* d_in, const int* in_sizes, int n_in,
                              void* d_out, int out_size, void* d_ws, size_t ws_size,
                              hipStream_t stream) {
    const float* x_t   = (const float*)d_in[0];
    const float* image = (const float*)d_in[1];
    const float* c1_w  = (const float*)d_in[2];
    const float* c1_b  = (const float*)d_in[3];
    const float* bn1_g = (const float*)d_in[4];
    const float* bn1_b = (const float*)d_in[5];
    const float* c2_w  = (const float*)d_in[6];
    const float* c2_b  = (const float*)d_in[7];
    const float* bn2_g = (const float*)d_in[8];
    const float* bn2_b = (const float*)d_in[9];
    const float* a1_w  = (const float*)d_in[10];
    const float* a1_b  = (const float*)d_in[11];
    const float* abn1_g= (const float*)d_in[12];
    const float* abn1_b= (const float*)d_in[13];
    const float* a2_w  = (const float*)d_in[14];
    const float* a2_b  = (const float*)d_in[15];
    const float* abn2_g= (const float*)d_in[16];
    const float* abn2_b= (const float*)d_in[17];
    const float* p1_w  = (const float*)d_in[18];
    const float* p1_b  = (const float*)d_in[19];
    const float* pbn1_g= (const float*)d_in[20];
    const float* pbn1_b= (const float*)d_in[21];
    const float* p2_w  = (const float*)d_in[22];
    const float* p2_b  = (const float*)d_in[23];
    const float* pbn2_g= (const float*)d_in[24];
    const float* pbn2_b= (const float*)d_in[25];
    const float* fc_w  = (const float*)d_in[26];
    const float* fc_b  = (const float*)d_in[27];
    float* outp = (float*)d_out;

    // Fixed region: folded bf16 weights + biases
    float* ws = (float*)d_ws;
    short* wTa1 = (short*)ws;
    short* wTa2 = wTa1 + WSH_A1;
    short* wTp1 = wTa2 + WSH_A2;
    short* wTp2 = wTp1 + WSH_A1;
    short* wTc2 = wTp2 + WSH_A2;
    float* bfa1 = ws + WSH_TOT / 2;
    float* bfa2 = bfa1 + 128;
    float* bfp1 = bfa2 + 128;
    float* bfp2 = bfp1 + 128;
    float* bfc2 = bfp2 + 128;
    float* dyn  = bfc2 + 128;
    const size_t fixed_floats = WSH_TOT / 2 + 1024;

    int GB = 32;
    while (GB > 1) {
        size_t need = ((size_t)GB * EL_PER_BATCH + fixed_floats + 256) * sizeof(float);
        if (need <= ws_size) break;
        GB >>= 1;
    }
    const int ngroups = NB / GB;

    float* heat = dyn;                                 // GB*EL_HEAT
    float* m    = heat + (size_t)GB * EL_HEAT;         // 64
    float* regB = m + 64;                              // GB*EL_REGB
    float* regC = regB + (size_t)GB * EL_REGB;         // GB*EL_REGC
    float* regD = regC + (size_t)GB * EL_REGC;         // GB*EL_REGD
    float* regE = regD + (size_t)GB * EL_REGD;         // GB*EL_REGE
    float* pmm  = regE + (size_t)GB * EL_REGE;         // 128
    float* px   = pmm + 128;                           // GB*EL_PX

    float* G      = regD;            // [lb][181][330] f32 (dead after rowcombine)
    short* out1b  = (short*)regB;    // bf16 ch-last [H1*W1][32]
    short* out2b  = (short*)regC;    // bf16 ch-last [pixel][64]
    short* fbuf   = (short*)regD;    // bf16 ch-last [pixel][128] (a1 out)
    short* fxbf   = (short*)regE;    // bf16 ch-first [c][KPAD]
    short* pp1    = (short*)regB;    // bf16 ch-last (out1 dead)
    short* pp2    = (short*)regD;    // bf16 ch-first [c][KPAD] (fbuf dead)
    float* pxpart = regB;            // f32, NKC*GB*EL_PX (pp1 dead after p2 conv)
    // FC-phase aliases (valid once einsum_part/px_reduce are done):
    float* fcwT   = regD;            // f32 wT[16384][256] (pp2 dead)
    float* fcpart = regB;            // f32 NKF*8192 (pxpart dead after px_reduce)

    wfold_k<<<(9 * 128 * CH2 + 255) / 256, 256, 0, stream>>>(a1_w, abn1_g, a1_b, abn1_b, wTa1, bfa1, 128, CH2);
    wfold_k<<<(9 * 128 * CH3 + 255) / 256, 256, 0, stream>>>(a2_w, abn2_g, a2_b, abn2_b, wTa2, bfa2, 128, CH3);
    wfold_k<<<(9 * 128 * CH2 + 255) / 256, 256, 0, stream>>>(p1_w, pbn1_g, p1_b, pbn1_b, wTp1, bfp1, 128, CH2);
    wfold_k<<<(9 * 128 * CH3 + 255) / 256, 256, 0, stream>>>(p2_w, pbn2_g, p2_b, pbn2_b, wTp2, bfp2, 128, CH3);
    wfold_k<<<(9 * 64 * 32 + 255) / 256, 256, 0, stream>>>(c2_w, bn2_g, c2_b, bn2_b, wTc2, bfc2, 64, 32);

    for (int gidx = 0; gidx < ngroups; ++gidx) {
        const int b0 = gidx * GB;
        mm_init<<<1, 256, 0, stream>>>((unsigned*)m, (unsigned*)pmm);
        heat_scatter_cols<<<dim3(NSTRIP, GB), 256, 0, stream>>>(x_t, G, b0);
        heat_rowcombine<<<dim3(IH / BXR, GB, 2), 256, 0, stream>>>(G, heat, (unsigned*)m);
        conv1_pool<<<(GB * H1 * W1 + 255) / 256, 256, 0, stream>>>(
            heat, image, m, c1_w, c1_b, bn1_g, bn1_b, out1b, b0, GB);
        conv2_mfma<<<dim3(6, 12, GB), 256, 0, stream>>>(out1b, wTc2, bfc2, out2b);
        // merged a1+p1 (shared input, disjoint outputs; per-block body = round-3)
        conv3x3_mfma<CH2, false, 0, true><<<dim3(3, 24, GB), 256, 0, stream>>>(
            out2b, wTa1, wTp1, bfa1, bfp1, fbuf, pp1);
        conv3x3_mfma<CH3, true,  2, false><<<dim3(3, 12, GB), 256, 0, stream>>>(
            fbuf, wTa2, wTa2, bfa2, bfa2, fxbf, fxbf);
        conv3x3_mfma<CH3, false, 2, false><<<dim3(3, 12, GB), 256, 0, stream>>>(
            pp1, wTp2, wTp2, bfp2, bfp2, pp2, pp2);
        pminmax<<<dim3(16, GB), 256, 0, stream>>>(pp2, (unsigned*)pmm);
        einsum_part<<<dim3(NKC, GB), 256, 0, stream>>>(pp2, fxbf, pmm, pxpart);
        px_reduce<<<(GB * EL_PX + 255) / 256, 256, 0, stream>>>(pxpart, px, GB);
        if (GB == 32) {
            fc_wt<<<dim3(EL_PX / 32, 256 / 32), 256, 0, stream>>>(fc_w, fcwT);
            fc_part<<<NKF, 256, 0, stream>>>(px, fcwT, fcpart);
            fc_out<<<8192 / 256, 256, 0, stream>>>(fcpart, fc_b, outp);
        } else {
            fc_k<<<GB * 64, 256, 0, stream>>>(px, fc_w, fc_b, outp, b0);
        }
    }
}

// Round 11
// 589.284 us; speedup vs baseline: 1.0627x; 1.0387x over previous
//
#include <hip/hip_runtime.h>
#include <hip/hip_bf16.h>

// Problem constants
#define NB 32
#define NT 1024
#define IH 180
#define IW 330
#define KSZ 37
#define XBINS 181
#define H1 90
#define W1 165
#define H2 45
#define W2 82
#define PIX2 (H2*W2)          // 3690
#define KTOT PIX2
#define KPAD 3712
#define CH1 32
#define CH2 64
#define CH3 128
#define NSTRIP 6
#define NKC 20                // einsum K-chunks (192 each over KPAD; 640 blocks = 2.5/CU)
#define ITC 3                 // 64-k steps per chunk

// FC split-K config
#define NKF 256               // K-chunks for fc (16384/64)
#define KCF 64

// heat_rowcombine band config
#define BXR 12                // output rows per band (15 bands cover 180)
#define YHW 165               // half of IW
#define GROWS_MAX 54          // max staged G rows

// Per-batch f32-slot counts
#define EL_HEAT (IH*IW)           // 59,400
#define EL_REGB 237600            // out1 bf16 [H1*W1][32] -> pp1 bf16 [PIX2][128] -> px_part f32 -> fc partials
#define EL_REGC (CH2*PIX2/2)      // 118,080 : out2 bf16 ch-last [pixel][64]
#define EL_REGD (CH3*KPAD/2)      // 237,568 : G f32 -> fbuf bf16 -> pp2 bf16 [c][KPAD] -> wT f32
#define EL_REGE (CH3*KPAD/2)      // 237,568 : fx bf16 [c][KPAD]
#define EL_PX   (CH3*CH3)         // 16,384
#define EL_PER_BATCH (EL_HEAT + EL_REGB + EL_REGC + EL_REGD + EL_REGE + EL_PX) // 906,600
// pxpart (NKC*GB*EL_PX = 10.49M floats) spans regB+regC (11.38M) — both dead by einsum time.

// folded-weight sizes (bf16 shorts)
#define WSH_A1 (9*128*64)
#define WSH_A2 (9*128*128)
#define WSH_C2 (9*64*32)
#define WSH_TOT (2*WSH_A1 + 2*WSH_A2 + WSH_C2)

typedef __attribute__((ext_vector_type(8))) short short8;
typedef __attribute__((ext_vector_type(4))) float floatx4;

__device__ __forceinline__ short f2bf(float v) {
    __hip_bfloat16 h = __float2bfloat16(v);
    return *reinterpret_cast<short*>(&h);
}
__device__ __forceinline__ float b2f(short s) {
    __hip_bfloat16 h = *reinterpret_cast<__hip_bfloat16*>(&s);
    return __bfloat162float(h);
}

// ---------------------------------------------------------------------------
__global__ __launch_bounds__(256) void mm_init(unsigned* __restrict__ m_bits,
                                               unsigned* __restrict__ pmm_bits) {
    int i = threadIdx.x;
    if (i < 64) {
        m_bits[i] = 0u;
        pmm_bits[2 * i]     = 0x7F800000u;   // +inf
        pmm_bits[2 * i + 1] = 0u;
    }
}

// ---------------------------------------------------------------------------
// S1: separable scatter — column profiles into G[xp][Y]
// ---------------------------------------------------------------------------
__global__ __launch_bounds__(256) void heat_scatter_cols(const float* __restrict__ x_t,
                                                         float* __restrict__ G,
                                                         int b0) {
    const int strip = blockIdx.x;
    const int lb = blockIdx.y;
    const int b = b0 + lb;
    const int c0 = strip * 64;
    const int cw = min(64, IW - c0);
    __shared__ float g[XBINS * 64];
    __shared__ float k1n[64];
    __shared__ float2 pts[NT];
    const int tid = threadIdx.x;

    if (tid < 64) {
        float v = 0.0f;
        if (tid < KSZ) {
            float ax = (float)tid - 18.0f;
            v = expf(-ax * ax / 18.0f);
        }
        k1n[tid] = v;
    }
    for (int i = tid; i < XBINS * 64; i += 256) g[i] = 0.0f;
    {
        const float2* xb = (const float2*)x_t + (size_t)b * NT;
        for (int i = tid; i < NT; i += 256) pts[i] = xb[i];
    }
    __syncthreads();
    if (tid == 0) {
        float s = 0.0f;
        for (int i = 0; i < KSZ; i++) s += k1n[i];
        float inv = 1.0f / s;
        for (int i = 0; i < KSZ; i++) k1n[i] *= inv;
    }
    __syncthreads();

    const int wave = tid >> 6;
    const int lane = tid & 63;
    const float kc = k1n[lane];

    for (int p = wave; p < NT; p += 4) {
        float x = pts[p].x, y = pts[p].y;
        if (isnan(x) || isnan(y)) continue;
        int xp = IH - (int)((x - 30.0f) * 180.0f);
        xp = min(max(xp, 0), 180);
        int yp = (int)((y - 120.0f) * 165.0f);
        int ys = min(max(yp - 18, 0), IW - 36);
        int ye = min(max(yp + 18, 0), IW);
        int nc = ye - ys;
        int col = ys + lane;
        if (lane < nc && col >= c0 && col < c0 + cw)
            atomicAdd(&g[xp * 64 + col - c0], kc);
    }
    __syncthreads();
    for (int i = tid; i < XBINS * cw; i += 256) {
        int row = i / cw, col = i % cw;
        G[((size_t)lb * XBINS + row) * IW + c0 + col] = g[row * 64 + col];
    }
}

// ---------------------------------------------------------------------------
// S2: row-combine + fused per-batch max (band-tiled, LDS-staged G)
// ---------------------------------------------------------------------------
__global__ __launch_bounds__(256) void heat_rowcombine(const float* __restrict__ G,
                                                       float* __restrict__ heat,
                                                       unsigned* __restrict__ m_bits) {
    const int band = blockIdx.x;        // 0..14
    const int lb = blockIdx.y;
    const int half = blockIdx.z;        // 0..1
    const int X0 = band * BXR;
    const int c0 = half * YHW;
    const int tid = threadIdx.x;

    __shared__ float k1n[64];
    __shared__ float gs[GROWS_MAX * YHW];   // 35,640 B
    __shared__ float red[256];

    if (tid < 64) {
        float v = 0.0f;
        if (tid < KSZ) {
            float ax = (float)tid - 18.0f;
            v = expf(-ax * ax / 18.0f);
        }
        k1n[tid] = v;
    }

    const int rlo = max(0, X0 - 17);
    const int rhi = (X0 + BXR - 1 >= IH - 36) ? 180 : (X0 + BXR - 1 + 18);
    const int nrows = rhi - rlo + 1;        // <= 54
    const float* Gb = G + (size_t)lb * XBINS * IW;
    for (int i = tid; i < nrows * YHW; i += 256) {
        int r = i / YHW, y = i % YHW;
        gs[i] = Gb[(size_t)(rlo + r) * IW + c0 + y];
    }
    __syncthreads();
    if (tid == 0) {
        float s = 0.0f;
        for (int i = 0; i < KSZ; i++) s += k1n[i];
        float inv = 1.0f / s;
        for (int i = 0; i < KSZ; i++) k1n[i] *= inv;
    }
    __syncthreads();

    float lmax = 0.0f;
    for (int p = tid; p < BXR * YHW; p += 256) {
        const int xr = p / YHW;
        const int yy = p % YHW;
        const int X = X0 + xr;
        const int Y = c0 + yy;
        const int lo = max(0, X - 17);
        const int hi = (X >= IH - 36) ? 180 : X + 18;
        float s = 0.0f;
        for (int xp = lo; xp <= hi; ++xp) {
            int xs = min(max(xp - 18, 0), IH - 36);
            s += k1n[X - xs] * gs[(xp - rlo) * YHW + yy];
        }
        heat[(size_t)lb * EL_HEAT + (size_t)X * IW + Y] = s;
        lmax = fmaxf(lmax, s);
    }
    red[tid] = lmax;
    __syncthreads();
    for (int st = 128; st > 0; st >>= 1) {
        if (tid < st) red[tid] = fmaxf(red[tid], red[tid + st]);
        __syncthreads();
    }
    if (tid == 0) atomicMax(&m_bits[lb], __float_as_uint(red[0]));
}

// ---------------------------------------------------------------------------
// K3: conv1(1->32) + BN + relu + pool (fuse folded); out bf16 ch-last [pix][32]
// ---------------------------------------------------------------------------
__global__ __launch_bounds__(256) void conv1_pool(const float* __restrict__ heat,
                                                  const float* __restrict__ image,
                                                  const float* __restrict__ m,
                                                  const float* __restrict__ w,
                                                  const float* __restrict__ cb,
                                                  const float* __restrict__ g,
                                                  const float* __restrict__ bb,
                                                  short* __restrict__ out1,
                                                  int b0, int gb) {
    __shared__ float ws_[CH1 * 9];
    __shared__ float bs_[CH1];
    const int tid = threadIdx.x;
    for (int i = tid; i < CH1 * 9; i += 256) {
        int oc = i / 9;
        ws_[i] = w[i] * g[oc];
    }
    if (tid < CH1) bs_[tid] = cb[tid] * g[tid] + bb[tid];
    __syncthreads();

    int t = blockIdx.x * 256 + tid;
    if (t >= gb * H1 * W1) return;
    int lb = t / (H1 * W1);
    int r = t % (H1 * W1);
    int py = r / W1, px = r % W1;
    const float s = 0.7f / (m[lb] + 1e-10f);
    const float* hb = heat + (size_t)lb * EL_HEAT;
    const float* ib = image + (size_t)(b0 + lb) * EL_HEAT;

    float v[4][4];
    int y0 = 2 * py - 1, x0 = 2 * px - 1;
#pragma unroll
    for (int i = 0; i < 4; i++) {
#pragma unroll
        for (int j = 0; j < 4; j++) {
            int y = y0 + i, x = x0 + j;
            float val = 0.0f;
            if (y >= 0 && y < IH && x >= 0 && x < IW) {
                size_t idx = (size_t)y * IW + x;
                val = s * hb[idx] + 0.3f * ib[idx];
            }
            v[i][j] = val;
        }
    }
    short8 pk[4];
#pragma unroll
    for (int oc = 0; oc < CH1; oc++) {
        float a00 = 0, a01 = 0, a10 = 0, a11 = 0;
        const float* wp = &ws_[oc * 9];
#pragma unroll
        for (int ky = 0; ky < 3; ky++) {
#pragma unroll
            for (int kx = 0; kx < 3; kx++) {
                float wv = wp[ky * 3 + kx];
                a00 += wv * v[ky][kx];
                a01 += wv * v[ky][kx + 1];
                a10 += wv * v[ky + 1][kx];
                a11 += wv * v[ky + 1][kx + 1];
            }
        }
        float bias = bs_[oc];
        a00 = fmaxf(a00 + bias, 0.0f);
        a01 = fmaxf(a01 + bias, 0.0f);
        a10 = fmaxf(a10 + bias, 0.0f);
        a11 = fmaxf(a11 + bias, 0.0f);
        pk[oc >> 3][oc & 7] = f2bf(fmaxf(fmaxf(a00, a01), fmaxf(a10, a11)));
    }
    short8* op = reinterpret_cast<short8*>(&out1[((size_t)lb * H1 * W1 + r) * CH1]);
#pragma unroll
    for (int vv = 0; vv < 4; vv++) op[vv] = pk[vv];
}

// ---------------------------------------------------------------------------
// weight fold/transpose: wT[tap][oc][ic] = bf16(w[oc][ic][tap]*g[oc])
// ---------------------------------------------------------------------------
__global__ __launch_bounds__(256) void wfold_k(const float* __restrict__ w,
                                               const float* __restrict__ g,
                                               const float* __restrict__ cb,
                                               const float* __restrict__ bb,
                                               short* __restrict__ wT,
                                               float* __restrict__ bfold,
                                               int OC, int IC) {
    int i = blockIdx.x * 256 + threadIdx.x;
    int n = 9 * OC * IC;
    if (i >= n) return;
    int tap = i / (OC * IC);
    int r = i % (OC * IC);
    int oc = r / IC;
    int ic = r % IC;
    wT[i] = f2bf(w[((size_t)oc * IC + ic) * 9 + tap] * g[oc]);
    if (tap == 0 && ic == 0) bfold[oc] = cb[oc] * g[oc] + bb[oc];
}

// ---------------------------------------------------------------------------
// K4: conv2(32->64) + BN + relu + 2x2 pool via bf16 MFMA.
// ---------------------------------------------------------------------------
__global__ __launch_bounds__(256) void conv2_mfma(const short* __restrict__ in,
                                                  const short* __restrict__ wT,
                                                  const float* __restrict__ bfold,
                                                  short* __restrict__ out) {
    const int xt = blockIdx.x;   // 0..5 : 32 pre-pool cols
    const int yt = blockIdx.y;   // 0..11: 8 pre-pool rows
    const int lb = blockIdx.z;
    const int x0 = xt * 32, y0 = yt * 8;
    const int tid = threadIdx.x;
    const int wave = tid >> 6, lane = tid & 63;
    const int mm = lane & 15, q = lane >> 4;
    constexpr int AP = 40;
    constexpr int CP = 72;                      // C-stage stride (16B-aligned rows)
    __shared__ __align__(16) short smem[10 * 34 * AP];   // 27,200 B (>= 64*CP=9,216)

    floatx4 acc[2][2][4];
#pragma unroll
    for (int a = 0; a < 2; ++a)
#pragma unroll
        for (int bq = 0; bq < 2; ++bq)
#pragma unroll
            for (int j = 0; j < 4; ++j) acc[a][bq][j] = (floatx4){0.f, 0.f, 0.f, 0.f};

    const short* inb = in + (size_t)lb * (H1 * W1) * CH1;
    for (int e = tid; e < 10 * 34 * 4; e += 256) {
        int dy = e / (34 * 4);
        int r = e % (34 * 4);
        int tx = r / 4;
        int i8 = r % 4;
        int yin = y0 + dy - 1, xin = x0 + tx - 1;
        short8 hv = {0, 0, 0, 0, 0, 0, 0, 0};
        if (yin >= 0 && yin < H1 && xin >= 0 && xin < W1)
            hv = *reinterpret_cast<const short8*>(&inb[((size_t)(yin * W1 + xin)) * CH1 + i8 * 8]);
        *reinterpret_cast<short8*>(&smem[(dy * 34 + tx) * AP + i8 * 8]) = hv;
    }
    __syncthreads();

#pragma unroll
    for (int tap = 0; tap < 9; ++tap) {
        const int dy = tap / 3, dx = tap % 3;
        short8 bf[4];
#pragma unroll
        for (int j = 0; j < 4; ++j)
            bf[j] = *reinterpret_cast<const short8*>(&wT[((size_t)tap * 64 + j * 16 + mm) * 32 + q * 8]);
#pragma unroll
        for (int row = 0; row < 2; ++row) {
#pragma unroll
            for (int xh = 0; xh < 2; ++xh) {
                short8 af = *reinterpret_cast<const short8*>(
                    &smem[((2 * wave + row + dy) * 34 + xh * 16 + dx + mm) * AP + q * 8]);
#pragma unroll
                for (int j = 0; j < 4; ++j)
                    acc[row][xh][j] = __builtin_amdgcn_mfma_f32_16x16x32_bf16(af, bf[j], acc[row][xh][j], 0, 0, 0);
            }
        }
    }
    __syncthreads();

    // stage pooled C into LDS: [local pooled pixel 0..63][CP]
    short* cst = smem;
#pragma unroll
    for (int xh = 0; xh < 2; ++xh) {
#pragma unroll
        for (int j = 0; j < 4; ++j) {
            const float bias = bfold[j * 16 + mm];
#pragma unroll
            for (int rp = 0; rp < 2; ++rp) {
                int pxl = xh * 8 + q * 2 + rp;            // 0..15
                float v = fmaxf(fmaxf(acc[0][xh][j][2 * rp], acc[0][xh][j][2 * rp + 1]),
                                fmaxf(acc[1][xh][j][2 * rp], acc[1][xh][j][2 * rp + 1]));
                v = fmaxf(v + bias, 0.0f);
                cst[(wave * 16 + pxl) * CP + j * 16 + mm] = f2bf(v);
            }
        }
    }
    __syncthreads();

    // coalesced copy-out: 64 px x 8 short8
    short* ob = out + (size_t)lb * PIX2 * CH2;
    for (int e = tid; e < 512; e += 256) {
        int pl = e >> 3, c8 = e & 7;
        int py = yt * 4 + (pl >> 4);
        int pxg = xt * 16 + (pl & 15);
        if (py < H2 && pxg < W2)
            *reinterpret_cast<short8*>(&ob[((size_t)py * W2 + pxg) * CH2 + c8 * 8]) =
                *reinterpret_cast<const short8*>(&cst[pl * CP + c8 * 8]);
    }
}

// ---------------------------------------------------------------------------
// K5-K8: 3x3 conv via bf16 MFMA; bf16 ch-last input; 32x4 tile.
// (exact round-3 structure — known good; KC=32; frozen)
// OM: 0 = bf16 ch-last out, 2 = bf16 ch-first [oc][KPAD].
// DUAL: grid.y = 24; sel = blockIdx.y/12 picks {wA,bA,oA} vs {wB,bB,oB}.
// ---------------------------------------------------------------------------
template <int IC, bool SIG, int OM, bool DUAL>
__global__ __launch_bounds__(256) void conv3x3_mfma(const short* __restrict__ in,
                                                    const short* __restrict__ wA,
                                                    const short* __restrict__ wB,
                                                    const float* __restrict__ bA,
                                                    const float* __restrict__ bB,
                                                    short* __restrict__ oA,
                                                    short* __restrict__ oB) {
    const int xt = blockIdx.x;                          // 0..2 (32 cols)
    const int yt = DUAL ? (blockIdx.y % 12) : blockIdx.y;   // 0..11 (4 rows)
    const int sel = DUAL ? (blockIdx.y / 12) : 0;
    const int lb = blockIdx.z;
    const int x0 = xt * 32, y0 = yt * 4;
    const int tid = threadIdx.x;
    const int wave = tid >> 6, lane = tid & 63;
    const int mm = lane & 15, q = lane >> 4;

    const short* wT = (DUAL && sel) ? wB : wA;
    const float* bfold = (DUAL && sel) ? bB : bA;
    short* outp = (DUAL && sel) ? oB : oA;

    constexpr int KC = 32;
    constexpr int NCH = IC / KC;
    constexpr int AP = 40;
    constexpr int CP0 = 136;   // [pixel][128] stage stride (16B-aligned, 2-way banks)
    constexpr int CP2 = 132;   // [oc][pixel] stage stride (4B-aligned, distinct banks)
    // max(tileA 8160, OM0 128*136=17408, OM2 128*132=16896) shorts
    __shared__ __align__(16) short smem[17408];

    floatx4 acc[16];
#pragma unroll
    for (int i = 0; i < 16; ++i) acc[i] = (floatx4){0.f, 0.f, 0.f, 0.f};

    const short* inb = in + (size_t)lb * PIX2 * IC;

    for (int c = 0; c < NCH; ++c) {
        const int ic0 = c * KC;
        for (int e = tid; e < 6 * 34 * (KC / 8); e += 256) {
            int dy = e / (34 * (KC / 8));
            int r  = e % (34 * (KC / 8));
            int tx = r / (KC / 8);
            int i8 = r % (KC / 8);
            int yin = y0 + dy - 1, xin = x0 + tx - 1;
            short8 hv = {0, 0, 0, 0, 0, 0, 0, 0};
            if (yin >= 0 && yin < H2 && xin >= 0 && xin < W2)
                hv = *reinterpret_cast<const short8*>(
                    &inb[((size_t)(yin * W2 + xin)) * IC + ic0 + i8 * 8]);
            *reinterpret_cast<short8*>(&smem[(dy * 34 + tx) * AP + i8 * 8]) = hv;
        }
        __syncthreads();

        const int oc0 = wave * 32 + mm;
#pragma unroll
        for (int tap = 0; tap < 9; ++tap) {
            const int dy = tap / 3, dx = tap % 3;
            short8 b0 = *reinterpret_cast<const short8*>(
                &wT[((size_t)tap * 128 + oc0) * IC + ic0 + q * 8]);
            short8 b1 = *reinterpret_cast<const short8*>(
                &wT[((size_t)tap * 128 + oc0 + 16) * IC + ic0 + q * 8]);
#pragma unroll
            for (int t = 0; t < 8; ++t) {
                const int tr = t >> 1, tc = t & 1;
                short8 af = *reinterpret_cast<const short8*>(
                    &smem[((tr + dy) * 34 + tc * 16 + dx + mm) * AP + q * 8]);
                acc[t * 2]     = __builtin_amdgcn_mfma_f32_16x16x32_bf16(af, b0, acc[t * 2], 0, 0, 0);
                acc[t * 2 + 1] = __builtin_amdgcn_mfma_f32_16x16x32_bf16(af, b1, acc[t * 2 + 1], 0, 0, 0);
            }
        }
        __syncthreads();
    }

    // stage C into LDS
    const int oc0 = wave * 32 + mm;
    const float bias0 = bfold[oc0];
    const float bias1 = bfold[oc0 + 16];
    short* cst = smem;
#pragma unroll
    for (int t = 0; t < 8; ++t) {
        const int tr = t >> 1, tc = t & 1;
#pragma unroll
        for (int r = 0; r < 4; ++r) {
            int pl = tr * 32 + tc * 16 + q * 4 + r;       // 0..127
            float z0 = acc[t * 2][r] + bias0;
            float z1 = acc[t * 2 + 1][r] + bias1;
            if (SIG) {
                z0 = 1.0f / (1.0f + expf(-z0));
                z1 = 1.0f / (1.0f + expf(-z1));
            } else {
                z0 = fmaxf(z0, 0.0f);
                z1 = fmaxf(z1, 0.0f);
            }
            if (OM == 0) {
                cst[pl * CP0 + oc0] = f2bf(z0);
                cst[pl * CP0 + oc0 + 16] = f2bf(z1);
            } else {
                cst[oc0 * CP2 + pl] = f2bf(z0);
                cst[(oc0 + 16) * CP2 + pl] = f2bf(z1);
            }
        }
    }
    __syncthreads();

    if (OM == 0) {
        short* ob = outp + (size_t)lb * PIX2 * 128;
        for (int e = tid; e < 2048; e += 256) {
            int pl = e >> 4, c8 = e & 15;
            int yy = y0 + (pl >> 5), xx = x0 + (pl & 31);
            if (yy < H2 && xx < W2)
                *reinterpret_cast<short8*>(&ob[((size_t)yy * W2 + xx) * 128 + c8 * 8]) =
                    *reinterpret_cast<const short8*>(&cst[pl * CP0 + c8 * 8]);
        }
    } else {
        short* ob = outp + (size_t)lb * 128 * KPAD;
        for (int e = tid; e < 8192; e += 256) {
            int oc = e >> 6;                   // 0..127
            int r2 = e & 63;
            int yy4 = r2 >> 4;                 // 0..3
            int x2 = (r2 & 15) * 2;            // 0..30
            int yy = y0 + yy4, xx = x0 + x2;
            if (yy < H2 && xx < W2) {
                int pl = yy4 * 32 + x2;
                if (xx + 1 < W2) {
                    *reinterpret_cast<int*>(&ob[(size_t)oc * KPAD + yy * W2 + xx]) =
                        *reinterpret_cast<const int*>(&cst[oc * CP2 + pl]);
                } else {
                    ob[(size_t)oc * KPAD + yy * W2 + xx] = cst[oc * CP2 + pl];
                }
            }
        }
    }
}

// ---------------------------------------------------------------------------
// K9: per-batch min/max of pp2 (bf16 ch-first [c][KPAD], valid hw < PIX2).
// Vectorized short8 loads; 8 channels per block; one atomic pair per block.
// ---------------------------------------------------------------------------
__global__ __launch_bounds__(256) void pminmax(const short* __restrict__ p,
                                               unsigned* __restrict__ pmm_bits) {
    const int cg = blockIdx.x;             // 0..15 (8 channels each)
    const int lb = blockIdx.y;
    const short* pb = p + (size_t)lb * 128 * KPAD + (size_t)cg * 8 * KPAD;
    float mn = INFINITY, mx = 0.0f;
#pragma unroll
    for (int c = 0; c < 8; ++c) {
        const short* pc = pb + (size_t)c * KPAD;
        for (int i8 = threadIdx.x; i8 < PIX2 / 8; i8 += 256) {   // 461 vectors
            short8 v = *reinterpret_cast<const short8*>(&pc[i8 * 8]);
#pragma unroll
            for (int j = 0; j < 8; ++j) {
                float f = b2f(v[j]);
                mn = fminf(mn, f);
                mx = fmaxf(mx, f);
            }
        }
        if (threadIdx.x < PIX2 - (PIX2 / 8) * 8) {               // tail: 2 elems
            float f = b2f(pc[(PIX2 / 8) * 8 + threadIdx.x]);
            mn = fminf(mn, f);
            mx = fmaxf(mx, f);
        }
    }
    __shared__ float rmn[256], rmx[256];
    rmn[threadIdx.x] = mn; rmx[threadIdx.x] = mx;
    __syncthreads();
    for (int s = 128; s > 0; s >>= 1) {
        if (threadIdx.x < s) {
            rmn[threadIdx.x] = fminf(rmn[threadIdx.x], rmn[threadIdx.x + s]);
            rmx[threadIdx.x] = fmaxf(rmx[threadIdx.x], rmx[threadIdx.x + s]);
        }
        __syncthreads();
    }
    if (threadIdx.x == 0) {
        atomicMin(&pmm_bits[lb * 2],     __float_as_uint(rmn[0]));
        atomicMax(&pmm_bits[lb * 2 + 1], __float_as_uint(rmx[0]));
    }
}

// ---------------------------------------------------------------------------
// K11a: K-split einsum via bf16 MFMA, pmap fused into A-staging.
// NKC=20 chunks of 192 k (3x64) -> 640 blocks = 2.5/CU (was 1/CU at NKC=8).
// Per-block inner body unchanged; each A/B element still read exactly once.
// ---------------------------------------------------------------------------
__global__ __launch_bounds__(256) void einsum_part(const short* __restrict__ pp2,
                                                   const short* __restrict__ fxb,
                                                   const float* __restrict__ mm_,
                                                   float* __restrict__ px_part) {
    const int kc = blockIdx.x;   // 0..NKC-1
    const int lb = blockIdx.y;
    const int gb = gridDim.y;
    const int tid = threadIdx.x;
    const int wave = tid >> 6, lane = tid & 63;
    const int mm = lane & 15, q = lane >> 4;
    constexpr int AP = 72;
    __shared__ __align__(16) short As[128 * AP];
    __shared__ __align__(16) short Bs[128 * AP];

    const float mn = mm_[lb * 2];
    const float denom = fmaxf(mm_[lb * 2 + 1] - mn, 1e-4f);
    const float rden = 1.0f / denom;

    floatx4 acc[2][8];
#pragma unroll
    for (int a = 0; a < 2; ++a)
#pragma unroll
        for (int n = 0; n < 8; ++n) acc[a][n] = (floatx4){0.f, 0.f, 0.f, 0.f};

    const short* Ab = pp2 + (size_t)lb * 128 * KPAD;
    const short* Bb = fxb + (size_t)lb * 128 * KPAD;

    for (int it = 0; it < ITC; ++it) {
        const int kk = kc * (ITC * 64) + it * 64;
        if (kk >= KTOT) break;
        for (int e = tid; e < 2048; e += 256) {
            const bool isA = (e < 1024);
            const int e2 = isA ? e : e - 1024;
            const int row = e2 >> 3, i8 = e2 & 7;
            const int k = kk + i8 * 8;
            const short* src = (isA ? Ab : Bb) + (size_t)row * KPAD + k;
            short8 v = {0, 0, 0, 0, 0, 0, 0, 0};
            if (k + 8 <= KTOT) {
                v = *reinterpret_cast<const short8*>(src);
            } else {
#pragma unroll
                for (int j = 0; j < 8; ++j) v[j] = (k + j < KTOT) ? src[j] : (short)0;
            }
            if (isA) {
#pragma unroll
                for (int j = 0; j < 8; ++j) {
                    if (k + j < KTOT) {
                        float f = (b2f(v[j]) - mn) * rden;
                        v[j] = f2bf(1.0f / (1.0f + expf(-10.0f * (f - 0.5f))));
                    } else v[j] = 0;
                }
                *reinterpret_cast<short8*>(&As[row * AP + i8 * 8]) = v;
            } else {
                *reinterpret_cast<short8*>(&Bs[row * AP + i8 * 8]) = v;
            }
        }
        __syncthreads();
#pragma unroll
        for (int ks = 0; ks < 2; ++ks) {
            short8 af0 = *reinterpret_cast<const short8*>(&As[((2 * wave) * 16 + mm) * AP + ks * 32 + q * 8]);
            short8 af1 = *reinterpret_cast<const short8*>(&As[((2 * wave + 1) * 16 + mm) * AP + ks * 32 + q * 8]);
#pragma unroll
            for (int n = 0; n < 8; ++n) {
                short8 bf = *reinterpret_cast<const short8*>(&Bs[(n * 16 + mm) * AP + ks * 32 + q * 8]);
                acc[0][n] = __builtin_amdgcn_mfma_f32_16x16x32_bf16(af0, bf, acc[0][n], 0, 0, 0);
                acc[1][n] = __builtin_amdgcn_mfma_f32_16x16x32_bf16(af1, bf, acc[1][n], 0, 0, 0);
            }
        }
        __syncthreads();
    }

    float* base = px_part + ((size_t)kc * gb + lb) * EL_PX;
#pragma unroll
    for (int a = 0; a < 2; ++a) {
        const int gm0 = (2 * wave + a) * 16 + q * 4;
#pragma unroll
        for (int n = 0; n < 8; ++n) {
            const int gn = n * 16 + mm;
#pragma unroll
            for (int r = 0; r < 4; ++r)
                base[(size_t)(gm0 + r) * 128 + gn] = acc[a][n][r];
        }
    }
}

// ---------------------------------------------------------------------------
// K11b: reduce the NKC partials -> px (applies 1/3690)
// ---------------------------------------------------------------------------
__global__ __launch_bounds__(256) void px_reduce(const float* __restrict__ part,
                                                 float* __restrict__ px,
                                                 int gb) {
    int i = blockIdx.x * 256 + threadIdx.x;
    if (i >= gb * EL_PX) return;
    int lb = i / EL_PX;
    int r = i % EL_PX;
    float s = 0.0f;
#pragma unroll
    for (int kc = 0; kc < NKC; ++kc)
        s += part[((size_t)kc * gb + lb) * EL_PX + r];
    px[i] = s * (1.0f / (float)KTOT);
}

// ---------------------------------------------------------------------------
// K12: FC as split-K f32 GEMM. fc_w read exactly once.
// ---------------------------------------------------------------------------
__global__ __launch_bounds__(256) void fc_wt(const float* __restrict__ w,
                                             float* __restrict__ wT) {
    __shared__ float t[32][33];
    const int bk = blockIdx.x * 32;   // k tile (0..16383)
    const int bo = blockIdx.y * 32;   // o tile (0..255)
    const int tx = threadIdx.x & 31;
    const int ty = threadIdx.x >> 5;  // 0..7
#pragma unroll
    for (int r = 0; r < 4; ++r) {
        int o = bo + ty + r * 8;
        t[ty + r * 8][tx] = w[(size_t)o * EL_PX + bk + tx];
    }
    __syncthreads();
#pragma unroll
    for (int r = 0; r < 4; ++r) {
        int k = bk + ty + r * 8;
        wT[(size_t)k * 256 + bo + tx] = t[tx][ty + r * 8];
    }
}

__global__ __launch_bounds__(256) void fc_part(const float* __restrict__ px,
                                               const float* __restrict__ wT,
                                               float* __restrict__ part) {
    const int kc = blockIdx.x;          // 0..NKF-1
    const int o = threadIdx.x;          // 0..255
    const int k0 = kc * KCF;
    float acc[32];
#pragma unroll
    for (int lb = 0; lb < 32; ++lb) acc[lb] = 0.0f;

    for (int k8 = 0; k8 < KCF; k8 += 8) {
        float wv[8];
#pragma unroll
        for (int j = 0; j < 8; ++j)
            wv[j] = wT[(size_t)(k0 + k8 + j) * 256 + o];
#pragma unroll
        for (int lb = 0; lb < 32; ++lb) {
            const float* pc = px + (size_t)lb * EL_PX + k0 + k8;
            float4 p0 = *reinterpret_cast<const float4*>(pc);
            float4 p1 = *reinterpret_cast<const float4*>(pc + 4);
            acc[lb] += wv[0] * p0.x + wv[1] * p0.y + wv[2] * p0.z + wv[3] * p0.w
                     + wv[4] * p1.x + wv[5] * p1.y + wv[6] * p1.z + wv[7] * p1.w;
        }
    }
    float* pb = part + (size_t)kc * (32 * 256);
#pragma unroll
    for (int lb = 0; lb < 32; ++lb)
        pb[lb * 256 + o] = acc[lb];
}

__global__ __launch_bounds__(256) void fc_out(const float* __restrict__ part,
                                              const float* __restrict__ fcb,
                                              float* __restrict__ out) {
    const int i = blockIdx.x * 256 + threadIdx.x;   // 0..8191
    float s = 0.0f;
    for (int c = 0; c < NKF; ++c)
        s += part[(size_t)c * 8192 + i];
    out[i] = s + fcb[i & 255];
}

// ---------------------------------------------------------------------------
// K12 (fallback for GB<32): FC -> f32 out
// ---------------------------------------------------------------------------
__global__ __launch_bounds__(256) void fc_k(const float* __restrict__ px,
                                            const float* __restrict__ w,
                                            const float* __restrict__ bias,
                                            float* __restrict__ out,
                                            int b0) {
    const int gw = blockIdx.x * 4 + (threadIdx.x >> 6);
    const int lane = threadIdx.x & 63;
    const int lb = gw >> 8;
    const int o = gw & 255;
    const float* xb = px + (size_t)lb * EL_PX;
    const float* wr = w + (size_t)o * EL_PX;
    float s = 0.0f;
    for (int k = lane; k < EL_PX; k += 64) s += xb[k] * wr[k];
#pragma unroll
    for (int off = 32; off > 0; off >>= 1) s += __shfl_down(s, off);
    if (lane == 0) out[(size_t)(b0 + lb) * 256 + o] = s + bias[o];
}

// ---------------------------------------------------------------------------
extern "C" void kernel_launch(void* const* d_in, const int* in_sizes, int n_in,
                              void* d_out, int out_size, void* d_ws, size_t ws_size,
                              hipStream_t stream) {
    const float* x_t   = (const float*)d_in[0];
    const float* image = (const float*)d_in[1];
    const float* c1_w  = (const float*)d_in[2];
    const float* c1_b  = (const float*)d_in[3];
    const float* bn1_g = (const float*)d_in[4];
    const float* bn1_b = (const float*)d_in[5];
    const float* c2_w  = (const float*)d_in[6];
    const float* c2_b  = (const float*)d_in[7];
    const float* bn2_g = (const float*)d_in[8];
    const float* bn2_b = (const float*)d_in[9];
    const float* a1_w  = (const float*)d_in[10];
    const float* a1_b  = (const float*)d_in[11];
    const float* abn1_g= (const float*)d_in[12];
    const float* abn1_b= (const float*)d_in[13];
    const float* a2_w  = (const float*)d_in[14];
    const float* a2_b  = (const float*)d_in[15];
    const float* abn2_g= (const float*)d_in[16];
    const float* abn2_b= (const float*)d_in[17];
    const float* p1_w  = (const float*)d_in[18];
    const float* p1_b  = (const float*)d_in[19];
    const float* pbn1_g= (const float*)d_in[20];
    const float* pbn1_b= (const float*)d_in[21];
    const float* p2_w  = (const float*)d_in[22];
    const float* p2_b  = (const float*)d_in[23];
    const float* pbn2_g= (const float*)d_in[24];
    const float* pbn2_b= (const float*)d_in[25];
    const float* fc_w  = (const float*)d_in[26];
    const float* fc_b  = (const float*)d_in[27];
    float* outp = (float*)d_out;

    // Fixed region: folded bf16 weights + biases
    float* ws = (float*)d_ws;
    short* wTa1 = (short*)ws;
    short* wTa2 = wTa1 + WSH_A1;
    short* wTp1 = wTa2 + WSH_A2;
    short* wTp2 = wTp1 + WSH_A1;
    short* wTc2 = wTp2 + WSH_A2;
    float* bfa1 = ws + WSH_TOT / 2;
    float* bfa2 = bfa1 + 128;
    float* bfp1 = bfa2 + 128;
    float* bfp2 = bfp1 + 128;
    float* bfc2 = bfp2 + 128;
    float* dyn  = bfc2 + 128;
    const size_t fixed_floats = WSH_TOT / 2 + 1024;

    int GB = 32;
    while (GB > 1) {
        size_t need = ((size_t)GB * EL_PER_BATCH + fixed_floats + 256) * sizeof(float);
        if (need <= ws_size) break;
        GB >>= 1;
    }
    const int ngroups = NB / GB;

    float* heat = dyn;                                 // GB*EL_HEAT
    float* m    = heat + (size_t)GB * EL_HEAT;         // 64
    float* regB = m + 64;                              // GB*EL_REGB
    float* regC = regB + (size_t)GB * EL_REGB;         // GB*EL_REGC
    float* regD = regC + (size_t)GB * EL_REGC;         // GB*EL_REGD
    float* regE = regD + (size_t)GB * EL_REGD;         // GB*EL_REGE
    float* pmm  = regE + (size_t)GB * EL_REGE;         // 128
    float* px   = pmm + 128;                           // GB*EL_PX

    float* G      = regD;            // [lb][181][330] f32 (dead after rowcombine)
    short* out1b  = (short*)regB;    // bf16 ch-last [H1*W1][32]
    short* out2b  = (short*)regC;    // bf16 ch-last [pixel][64]
    short* fbuf   = (short*)regD;    // bf16 ch-last [pixel][128] (a1 out)
    short* fxbf   = (short*)regE;    // bf16 ch-first [c][KPAD]
    short* pp1    = (short*)regB;    // bf16 ch-last (out1 dead)
    short* pp2    = (short*)regD;    // bf16 ch-first [c][KPAD] (fbuf dead)
    float* pxpart = regB;            // f32, NKC*GB*EL_PX = 10.49M, spans regB+regC (both dead)
    // FC-phase aliases (valid once einsum_part/px_reduce are done):
    float* fcwT   = regD;            // f32 wT[16384][256] (pp2 dead)
    float* fcpart = regB;            // f32 NKF*8192 (pxpart dead after px_reduce)

    wfold_k<<<(9 * 128 * CH2 + 255) / 256, 256, 0, stream>>>(a1_w, abn1_g, a1_b, abn1_b, wTa1, bfa1, 128, CH2);
    wfold_k<<<(9 * 128 * CH3 + 255) / 256, 256, 0, stream>>>(a2_w, abn2_g, a2_b, abn2_b, wTa2, bfa2, 128, CH3);
    wfold_k<<<(9 * 128 * CH2 + 255) / 256, 256, 0, stream>>>(p1_w, pbn1_g, p1_b, pbn1_b, wTp1, bfp1, 128, CH2);
    wfold_k<<<(9 * 128 * CH3 + 255) / 256, 256, 0, stream>>>(p2_w, pbn2_g, p2_b, pbn2_b, wTp2, bfp2, 128, CH3);
    wfold_k<<<(9 * 64 * 32 + 255) / 256, 256, 0, stream>>>(c2_w, bn2_g, c2_b, bn2_b, wTc2, bfc2, 64, 32);

    for (int gidx = 0; gidx < ngroups; ++gidx) {
        const int b0 = gidx * GB;
        mm_init<<<1, 256, 0, stream>>>((unsigned*)m, (unsigned*)pmm);
        heat_scatter_cols<<<dim3(NSTRIP, GB), 256, 0, stream>>>(x_t, G, b0);
        heat_rowcombine<<<dim3(IH / BXR, GB, 2), 256, 0, stream>>>(G, heat, (unsigned*)m);
        conv1_pool<<<(GB * H1 * W1 + 255) / 256, 256, 0, stream>>>(
            heat, image, m, c1_w, c1_b, bn1_g, bn1_b, out1b, b0, GB);
        conv2_mfma<<<dim3(6, 12, GB), 256, 0, stream>>>(out1b, wTc2, bfc2, out2b);
        // merged a1+p1 (shared input, disjoint outputs; per-block body = round-3)
        conv3x3_mfma<CH2, false, 0, true><<<dim3(3, 24, GB), 256, 0, stream>>>(
            out2b, wTa1, wTp1, bfa1, bfp1, fbuf, pp1);
        conv3x3_mfma<CH3, true,  2, false><<<dim3(3, 12, GB), 256, 0, stream>>>(
            fbuf, wTa2, wTa2, bfa2, bfa2, fxbf, fxbf);
        conv3x3_mfma<CH3, false, 2, false><<<dim3(3, 12, GB), 256, 0, stream>>>(
            pp1, wTp2, wTp2, bfp2, bfp2, pp2, pp2);
        pminmax<<<dim3(16, GB), 256, 0, stream>>>(pp2, (unsigned*)pmm);
        einsum_part<<<dim3(NKC, GB), 256, 0, stream>>>(pp2, fxbf, pmm, pxpart);
        px_reduce<<<(GB * EL_PX + 255) / 256, 256, 0, stream>>>(pxpart, px, GB);
        if (GB == 32) {
            fc_wt<<<dim3(EL_PX / 32, 256 / 32), 256, 0, stream>>>(fc_w, fcwT);
            fc_part<<<NKF, 256, 0, stream>>>(px, fcwT, fcpart);
            fc_out<<<8192 / 256, 256, 0, stream>>>(fcpart, fc_b, outp);
        } else {
            fc_k<<<GB * 64, 256, 0, stream>>>(px, fc_w, fc_b, outp, b0);
        }
    }
}

// Round 12
// 572.966 us; speedup vs baseline: 1.0929x; 1.0285x over previous
//
#include <hip/hip_runtime.h>
#include <hip/hip_bf16.h>

// Problem constants
#define NB 32
#define NT 1024
#define IH 180
#define IW 330
#define KSZ 37
#define XBINS 181
#define H1 90
#define W1 165
#define H2 45
#define W2 82
#define PIX2 (H2*W2)          // 3690
#define KTOT PIX2
#define KPAD 3712
#define CH1 32
#define CH2 64
#define CH3 128
#define NSTRIP 6
#define NKC 20                // einsum K-chunks (192 each over KPAD; 640 blocks = 2.5/CU)
#define ITC 3                 // 64-k steps per chunk

// FC split-K config
#define NKF 256               // K-chunks for fc (16384/64)
#define KCF 64

// heat_rowcombine band config
#define BXR 12                // output rows per band (15 bands cover 180)
#define YHW 165               // half of IW
#define GROWS_MAX 54          // max staged G rows

// Per-batch f32-slot counts
#define EL_HEAT (IH*IW)           // 59,400
#define EL_REGB 237600            // out1 bf16 [H1*W1][32] -> pp1 bf16 [PIX2][128] -> px_part f32 -> fc partials
#define EL_REGC (CH2*PIX2/2)      // 118,080 : out2 bf16 ch-last [pixel][64]
#define EL_REGD (CH3*KPAD/2)      // 237,568 : G f32 -> fbuf bf16 -> (pp2) -> wT f32
#define EL_REGE (CH3*KPAD/2)      // 237,568 : fx bf16 [c][KPAD]
#define EL_PX   (CH3*CH3)         // 16,384
#define EL_PER_BATCH (EL_HEAT + EL_REGB + EL_REGC + EL_REGD + EL_REGE + EL_PX) // 906,600
// pxpart (NKC*GB*EL_PX = 10.49M floats) spans regB+regC (11.38M) — both dead by einsum time.
// Optional regF (GB*EL_REGD) holds pp2 so a2+p2 can merge (pp2 no longer aliases fbuf).

// folded-weight sizes (bf16 shorts)
#define WSH_A1 (9*128*64)
#define WSH_A2 (9*128*128)
#define WSH_C2 (9*64*32)
#define WSH_TOT (2*WSH_A1 + 2*WSH_A2 + WSH_C2)

typedef __attribute__((ext_vector_type(8))) short short8;
typedef __attribute__((ext_vector_type(4))) float floatx4;

__device__ __forceinline__ short f2bf(float v) {
    __hip_bfloat16 h = __float2bfloat16(v);
    return *reinterpret_cast<short*>(&h);
}
__device__ __forceinline__ float b2f(short s) {
    __hip_bfloat16 h = *reinterpret_cast<__hip_bfloat16*>(&s);
    return __bfloat162float(h);
}

// ---------------------------------------------------------------------------
__global__ __launch_bounds__(256) void mm_init(unsigned* __restrict__ m_bits,
                                               unsigned* __restrict__ pmm_bits) {
    int i = threadIdx.x;
    if (i < 64) {
        m_bits[i] = 0u;
        pmm_bits[2 * i]     = 0x7F800000u;   // +inf
        pmm_bits[2 * i + 1] = 0u;
    }
}

// ---------------------------------------------------------------------------
// S1: separable scatter — column profiles into G[xp][Y]
// ---------------------------------------------------------------------------
__global__ __launch_bounds__(256) void heat_scatter_cols(const float* __restrict__ x_t,
                                                         float* __restrict__ G,
                                                         int b0) {
    const int strip = blockIdx.x;
    const int lb = blockIdx.y;
    const int b = b0 + lb;
    const int c0 = strip * 64;
    const int cw = min(64, IW - c0);
    __shared__ float g[XBINS * 64];
    __shared__ float k1n[64];
    __shared__ float2 pts[NT];
    const int tid = threadIdx.x;

    if (tid < 64) {
        float v = 0.0f;
        if (tid < KSZ) {
            float ax = (float)tid - 18.0f;
            v = expf(-ax * ax / 18.0f);
        }
        k1n[tid] = v;
    }
    for (int i = tid; i < XBINS * 64; i += 256) g[i] = 0.0f;
    {
        const float2* xb = (const float2*)x_t + (size_t)b * NT;
        for (int i = tid; i < NT; i += 256) pts[i] = xb[i];
    }
    __syncthreads();
    if (tid == 0) {
        float s = 0.0f;
        for (int i = 0; i < KSZ; i++) s += k1n[i];
        float inv = 1.0f / s;
        for (int i = 0; i < KSZ; i++) k1n[i] *= inv;
    }
    __syncthreads();

    const int wave = tid >> 6;
    const int lane = tid & 63;
    const float kc = k1n[lane];

    for (int p = wave; p < NT; p += 4) {
        float x = pts[p].x, y = pts[p].y;
        if (isnan(x) || isnan(y)) continue;
        int xp = IH - (int)((x - 30.0f) * 180.0f);
        xp = min(max(xp, 0), 180);
        int yp = (int)((y - 120.0f) * 165.0f);
        int ys = min(max(yp - 18, 0), IW - 36);
        int ye = min(max(yp + 18, 0), IW);
        int nc = ye - ys;
        int col = ys + lane;
        if (lane < nc && col >= c0 && col < c0 + cw)
            atomicAdd(&g[xp * 64 + col - c0], kc);
    }
    __syncthreads();
    for (int i = tid; i < XBINS * cw; i += 256) {
        int row = i / cw, col = i % cw;
        G[((size_t)lb * XBINS + row) * IW + c0 + col] = g[row * 64 + col];
    }
}

// ---------------------------------------------------------------------------
// S2: row-combine + fused per-batch max (band-tiled, LDS-staged G)
// ---------------------------------------------------------------------------
__global__ __launch_bounds__(256) void heat_rowcombine(const float* __restrict__ G,
                                                       float* __restrict__ heat,
                                                       unsigned* __restrict__ m_bits) {
    const int band = blockIdx.x;        // 0..14
    const int lb = blockIdx.y;
    const int half = blockIdx.z;        // 0..1
    const int X0 = band * BXR;
    const int c0 = half * YHW;
    const int tid = threadIdx.x;

    __shared__ float k1n[64];
    __shared__ float gs[GROWS_MAX * YHW];   // 35,640 B
    __shared__ float red[256];

    if (tid < 64) {
        float v = 0.0f;
        if (tid < KSZ) {
            float ax = (float)tid - 18.0f;
            v = expf(-ax * ax / 18.0f);
        }
        k1n[tid] = v;
    }

    const int rlo = max(0, X0 - 17);
    const int rhi = (X0 + BXR - 1 >= IH - 36) ? 180 : (X0 + BXR - 1 + 18);
    const int nrows = rhi - rlo + 1;        // <= 54
    const float* Gb = G + (size_t)lb * XBINS * IW;
    for (int i = tid; i < nrows * YHW; i += 256) {
        int r = i / YHW, y = i % YHW;
        gs[i] = Gb[(size_t)(rlo + r) * IW + c0 + y];
    }
    __syncthreads();
    if (tid == 0) {
        float s = 0.0f;
        for (int i = 0; i < KSZ; i++) s += k1n[i];
        float inv = 1.0f / s;
        for (int i = 0; i < KSZ; i++) k1n[i] *= inv;
    }
    __syncthreads();

    float lmax = 0.0f;
    for (int p = tid; p < BXR * YHW; p += 256) {
        const int xr = p / YHW;
        const int yy = p % YHW;
        const int X = X0 + xr;
        const int Y = c0 + yy;
        const int lo = max(0, X - 17);
        const int hi = (X >= IH - 36) ? 180 : X + 18;
        float s = 0.0f;
        for (int xp = lo; xp <= hi; ++xp) {
            int xs = min(max(xp - 18, 0), IH - 36);
            s += k1n[X - xs] * gs[(xp - rlo) * YHW + yy];
        }
        heat[(size_t)lb * EL_HEAT + (size_t)X * IW + Y] = s;
        lmax = fmaxf(lmax, s);
    }
    red[tid] = lmax;
    __syncthreads();
    for (int st = 128; st > 0; st >>= 1) {
        if (tid < st) red[tid] = fmaxf(red[tid], red[tid + st]);
        __syncthreads();
    }
    if (tid == 0) atomicMax(&m_bits[lb], __float_as_uint(red[0]));
}

// ---------------------------------------------------------------------------
// K3: conv1(1->32) + BN + relu + pool (fuse folded); out bf16 ch-last [pix][32]
// ---------------------------------------------------------------------------
__global__ __launch_bounds__(256) void conv1_pool(const float* __restrict__ heat,
                                                  const float* __restrict__ image,
                                                  const float* __restrict__ m,
                                                  const float* __restrict__ w,
                                                  const float* __restrict__ cb,
                                                  const float* __restrict__ g,
                                                  const float* __restrict__ bb,
                                                  short* __restrict__ out1,
                                                  int b0, int gb) {
    __shared__ float ws_[CH1 * 9];
    __shared__ float bs_[CH1];
    const int tid = threadIdx.x;
    for (int i = tid; i < CH1 * 9; i += 256) {
        int oc = i / 9;
        ws_[i] = w[i] * g[oc];
    }
    if (tid < CH1) bs_[tid] = cb[tid] * g[tid] + bb[tid];
    __syncthreads();

    int t = blockIdx.x * 256 + tid;
    if (t >= gb * H1 * W1) return;
    int lb = t / (H1 * W1);
    int r = t % (H1 * W1);
    int py = r / W1, px = r % W1;
    const float s = 0.7f / (m[lb] + 1e-10f);
    const float* hb = heat + (size_t)lb * EL_HEAT;
    const float* ib = image + (size_t)(b0 + lb) * EL_HEAT;

    float v[4][4];
    int y0 = 2 * py - 1, x0 = 2 * px - 1;
#pragma unroll
    for (int i = 0; i < 4; i++) {
#pragma unroll
        for (int j = 0; j < 4; j++) {
            int y = y0 + i, x = x0 + j;
            float val = 0.0f;
            if (y >= 0 && y < IH && x >= 0 && x < IW) {
                size_t idx = (size_t)y * IW + x;
                val = s * hb[idx] + 0.3f * ib[idx];
            }
            v[i][j] = val;
        }
    }
    short8 pk[4];
#pragma unroll
    for (int oc = 0; oc < CH1; oc++) {
        float a00 = 0, a01 = 0, a10 = 0, a11 = 0;
        const float* wp = &ws_[oc * 9];
#pragma unroll
        for (int ky = 0; ky < 3; ky++) {
#pragma unroll
            for (int kx = 0; kx < 3; kx++) {
                float wv = wp[ky * 3 + kx];
                a00 += wv * v[ky][kx];
                a01 += wv * v[ky][kx + 1];
                a10 += wv * v[ky + 1][kx];
                a11 += wv * v[ky + 1][kx + 1];
            }
        }
        float bias = bs_[oc];
        a00 = fmaxf(a00 + bias, 0.0f);
        a01 = fmaxf(a01 + bias, 0.0f);
        a10 = fmaxf(a10 + bias, 0.0f);
        a11 = fmaxf(a11 + bias, 0.0f);
        pk[oc >> 3][oc & 7] = f2bf(fmaxf(fmaxf(a00, a01), fmaxf(a10, a11)));
    }
    short8* op = reinterpret_cast<short8*>(&out1[((size_t)lb * H1 * W1 + r) * CH1]);
#pragma unroll
    for (int vv = 0; vv < 4; vv++) op[vv] = pk[vv];
}

// ---------------------------------------------------------------------------
// weight fold/transpose: wT[tap][oc][ic] = bf16(w[oc][ic][tap]*g[oc])
// ---------------------------------------------------------------------------
__global__ __launch_bounds__(256) void wfold_k(const float* __restrict__ w,
                                               const float* __restrict__ g,
                                               const float* __restrict__ cb,
                                               const float* __restrict__ bb,
                                               short* __restrict__ wT,
                                               float* __restrict__ bfold,
                                               int OC, int IC) {
    int i = blockIdx.x * 256 + threadIdx.x;
    int n = 9 * OC * IC;
    if (i >= n) return;
    int tap = i / (OC * IC);
    int r = i % (OC * IC);
    int oc = r / IC;
    int ic = r % IC;
    wT[i] = f2bf(w[((size_t)oc * IC + ic) * 9 + tap] * g[oc]);
    if (tap == 0 && ic == 0) bfold[oc] = cb[oc] * g[oc] + bb[oc];
}

// ---------------------------------------------------------------------------
// K4: conv2(32->64) + BN + relu + 2x2 pool via bf16 MFMA.
// ---------------------------------------------------------------------------
__global__ __launch_bounds__(256) void conv2_mfma(const short* __restrict__ in,
                                                  const short* __restrict__ wT,
                                                  const float* __restrict__ bfold,
                                                  short* __restrict__ out) {
    const int xt = blockIdx.x;   // 0..5 : 32 pre-pool cols
    const int yt = blockIdx.y;   // 0..11: 8 pre-pool rows
    const int lb = blockIdx.z;
    const int x0 = xt * 32, y0 = yt * 8;
    const int tid = threadIdx.x;
    const int wave = tid >> 6, lane = tid & 63;
    const int mm = lane & 15, q = lane >> 4;
    constexpr int AP = 40;
    constexpr int CP = 72;                      // C-stage stride (16B-aligned rows)
    __shared__ __align__(16) short smem[10 * 34 * AP];   // 27,200 B (>= 64*CP=9,216)

    floatx4 acc[2][2][4];
#pragma unroll
    for (int a = 0; a < 2; ++a)
#pragma unroll
        for (int bq = 0; bq < 2; ++bq)
#pragma unroll
            for (int j = 0; j < 4; ++j) acc[a][bq][j] = (floatx4){0.f, 0.f, 0.f, 0.f};

    const short* inb = in + (size_t)lb * (H1 * W1) * CH1;
    for (int e = tid; e < 10 * 34 * 4; e += 256) {
        int dy = e / (34 * 4);
        int r = e % (34 * 4);
        int tx = r / 4;
        int i8 = r % 4;
        int yin = y0 + dy - 1, xin = x0 + tx - 1;
        short8 hv = {0, 0, 0, 0, 0, 0, 0, 0};
        if (yin >= 0 && yin < H1 && xin >= 0 && xin < W1)
            hv = *reinterpret_cast<const short8*>(&inb[((size_t)(yin * W1 + xin)) * CH1 + i8 * 8]);
        *reinterpret_cast<short8*>(&smem[(dy * 34 + tx) * AP + i8 * 8]) = hv;
    }
    __syncthreads();

#pragma unroll
    for (int tap = 0; tap < 9; ++tap) {
        const int dy = tap / 3, dx = tap % 3;
        short8 bf[4];
#pragma unroll
        for (int j = 0; j < 4; ++j)
            bf[j] = *reinterpret_cast<const short8*>(&wT[((size_t)tap * 64 + j * 16 + mm) * 32 + q * 8]);
#pragma unroll
        for (int row = 0; row < 2; ++row) {
#pragma unroll
            for (int xh = 0; xh < 2; ++xh) {
                short8 af = *reinterpret_cast<const short8*>(
                    &smem[((2 * wave + row + dy) * 34 + xh * 16 + dx + mm) * AP + q * 8]);
#pragma unroll
                for (int j = 0; j < 4; ++j)
                    acc[row][xh][j] = __builtin_amdgcn_mfma_f32_16x16x32_bf16(af, bf[j], acc[row][xh][j], 0, 0, 0);
            }
        }
    }
    __syncthreads();

    // stage pooled C into LDS: [local pooled pixel 0..63][CP]
    short* cst = smem;
#pragma unroll
    for (int xh = 0; xh < 2; ++xh) {
#pragma unroll
        for (int j = 0; j < 4; ++j) {
            const float bias = bfold[j * 16 + mm];
#pragma unroll
            for (int rp = 0; rp < 2; ++rp) {
                int pxl = xh * 8 + q * 2 + rp;            // 0..15
                float v = fmaxf(fmaxf(acc[0][xh][j][2 * rp], acc[0][xh][j][2 * rp + 1]),
                                fmaxf(acc[1][xh][j][2 * rp], acc[1][xh][j][2 * rp + 1]));
                v = fmaxf(v + bias, 0.0f);
                cst[(wave * 16 + pxl) * CP + j * 16 + mm] = f2bf(v);
            }
        }
    }
    __syncthreads();

    // coalesced copy-out: 64 px x 8 short8
    short* ob = out + (size_t)lb * PIX2 * CH2;
    for (int e = tid; e < 512; e += 256) {
        int pl = e >> 3, c8 = e & 7;
        int py = yt * 4 + (pl >> 4);
        int pxg = xt * 16 + (pl & 15);
        if (py < H2 && pxg < W2)
            *reinterpret_cast<short8*>(&ob[((size_t)py * W2 + pxg) * CH2 + c8 * 8]) =
                *reinterpret_cast<const short8*>(&cst[pl * CP + c8 * 8]);
    }
}

// ---------------------------------------------------------------------------
// K5-K8: 3x3 conv via bf16 MFMA; bf16 ch-last input; 32x4 tile.
// (exact round-3 per-block structure — KC=32; frozen)
// OM: 0 = bf16 ch-last out, 2 = bf16 ch-first [oc][KPAD].
// DUAL: grid.y = 24; sel = blockIdx.y/12 picks {iA,wA,bA,oA} vs {iB,wB,bB,oB}.
// SIGMODE: 0 = relu both; 1 = sigmoid; 2 = sel0 sigmoid / sel1 relu (a2+p2).
// a1p1 instantiation (SIGMODE=0) folds to the identical round-11 codegen.
// ---------------------------------------------------------------------------
template <int IC, int OM, int SIGMODE, bool DUAL>
__global__ __launch_bounds__(256) void conv3x3_mfma(const short* __restrict__ iA,
                                                    const short* __restrict__ iB,
                                                    const short* __restrict__ wA,
                                                    const short* __restrict__ wB,
                                                    const float* __restrict__ bA,
                                                    const float* __restrict__ bB,
                                                    short* __restrict__ oA,
                                                    short* __restrict__ oB) {
    const int xt = blockIdx.x;                          // 0..2 (32 cols)
    const int yt = DUAL ? (blockIdx.y % 12) : blockIdx.y;   // 0..11 (4 rows)
    const int sel = DUAL ? (blockIdx.y / 12) : 0;
    const int lb = blockIdx.z;
    const int x0 = xt * 32, y0 = yt * 4;
    const int tid = threadIdx.x;
    const int wave = tid >> 6, lane = tid & 63;
    const int mm = lane & 15, q = lane >> 4;

    const short* in = (DUAL && sel) ? iB : iA;
    const short* wT = (DUAL && sel) ? wB : wA;
    const float* bfold = (DUAL && sel) ? bB : bA;
    short* outp = (DUAL && sel) ? oB : oA;
    const bool sig = (SIGMODE == 1) || (SIGMODE == 2 && sel == 0);

    constexpr int KC = 32;
    constexpr int NCH = IC / KC;
    constexpr int AP = 40;
    constexpr int CP0 = 136;   // [pixel][128] stage stride (16B-aligned, 2-way banks)
    constexpr int CP2 = 132;   // [oc][pixel] stage stride (4B-aligned, distinct banks)
    // max(tileA 8160, OM0 128*136=17408, OM2 128*132=16896) shorts
    __shared__ __align__(16) short smem[17408];

    floatx4 acc[16];
#pragma unroll
    for (int i = 0; i < 16; ++i) acc[i] = (floatx4){0.f, 0.f, 0.f, 0.f};

    const short* inb = in + (size_t)lb * PIX2 * IC;

    for (int c = 0; c < NCH; ++c) {
        const int ic0 = c * KC;
        for (int e = tid; e < 6 * 34 * (KC / 8); e += 256) {
            int dy = e / (34 * (KC / 8));
            int r  = e % (34 * (KC / 8));
            int tx = r / (KC / 8);
            int i8 = r % (KC / 8);
            int yin = y0 + dy - 1, xin = x0 + tx - 1;
            short8 hv = {0, 0, 0, 0, 0, 0, 0, 0};
            if (yin >= 0 && yin < H2 && xin >= 0 && xin < W2)
                hv = *reinterpret_cast<const short8*>(
                    &inb[((size_t)(yin * W2 + xin)) * IC + ic0 + i8 * 8]);
            *reinterpret_cast<short8*>(&smem[(dy * 34 + tx) * AP + i8 * 8]) = hv;
        }
        __syncthreads();

        const int oc0 = wave * 32 + mm;
#pragma unroll
        for (int tap = 0; tap < 9; ++tap) {
            const int dy = tap / 3, dx = tap % 3;
            short8 b0 = *reinterpret_cast<const short8*>(
                &wT[((size_t)tap * 128 + oc0) * IC + ic0 + q * 8]);
            short8 b1 = *reinterpret_cast<const short8*>(
                &wT[((size_t)tap * 128 + oc0 + 16) * IC + ic0 + q * 8]);
#pragma unroll
            for (int t = 0; t < 8; ++t) {
                const int tr = t >> 1, tc = t & 1;
                short8 af = *reinterpret_cast<const short8*>(
                    &smem[((tr + dy) * 34 + tc * 16 + dx + mm) * AP + q * 8]);
                acc[t * 2]     = __builtin_amdgcn_mfma_f32_16x16x32_bf16(af, b0, acc[t * 2], 0, 0, 0);
                acc[t * 2 + 1] = __builtin_amdgcn_mfma_f32_16x16x32_bf16(af, b1, acc[t * 2 + 1], 0, 0, 0);
            }
        }
        __syncthreads();
    }

    // stage C into LDS
    const int oc0 = wave * 32 + mm;
    const float bias0 = bfold[oc0];
    const float bias1 = bfold[oc0 + 16];
    short* cst = smem;
#pragma unroll
    for (int t = 0; t < 8; ++t) {
        const int tr = t >> 1, tc = t & 1;
#pragma unroll
        for (int r = 0; r < 4; ++r) {
            int pl = tr * 32 + tc * 16 + q * 4 + r;       // 0..127
            float z0 = acc[t * 2][r] + bias0;
            float z1 = acc[t * 2 + 1][r] + bias1;
            if (sig) {
                z0 = 1.0f / (1.0f + expf(-z0));
                z1 = 1.0f / (1.0f + expf(-z1));
            } else {
                z0 = fmaxf(z0, 0.0f);
                z1 = fmaxf(z1, 0.0f);
            }
            if (OM == 0) {
                cst[pl * CP0 + oc0] = f2bf(z0);
                cst[pl * CP0 + oc0 + 16] = f2bf(z1);
            } else {
                cst[oc0 * CP2 + pl] = f2bf(z0);
                cst[(oc0 + 16) * CP2 + pl] = f2bf(z1);
            }
        }
    }
    __syncthreads();

    if (OM == 0) {
        short* ob = outp + (size_t)lb * PIX2 * 128;
        for (int e = tid; e < 2048; e += 256) {
            int pl = e >> 4, c8 = e & 15;
            int yy = y0 + (pl >> 5), xx = x0 + (pl & 31);
            if (yy < H2 && xx < W2)
                *reinterpret_cast<short8*>(&ob[((size_t)yy * W2 + xx) * 128 + c8 * 8]) =
                    *reinterpret_cast<const short8*>(&cst[pl * CP0 + c8 * 8]);
        }
    } else {
        short* ob = outp + (size_t)lb * 128 * KPAD;
        for (int e = tid; e < 8192; e += 256) {
            int oc = e >> 6;                   // 0..127
            int r2 = e & 63;
            int yy4 = r2 >> 4;                 // 0..3
            int x2 = (r2 & 15) * 2;            // 0..30
            int yy = y0 + yy4, xx = x0 + x2;
            if (yy < H2 && xx < W2) {
                int pl = yy4 * 32 + x2;
                if (xx + 1 < W2) {
                    *reinterpret_cast<int*>(&ob[(size_t)oc * KPAD + yy * W2 + xx]) =
                        *reinterpret_cast<const int*>(&cst[oc * CP2 + pl]);
                } else {
                    ob[(size_t)oc * KPAD + yy * W2 + xx] = cst[oc * CP2 + pl];
                }
            }
        }
    }
}

// ---------------------------------------------------------------------------
// K9: per-batch min/max of pp2 (bf16 ch-first [c][KPAD], valid hw < PIX2).
// Vectorized short8 loads; 8 channels per block; one atomic pair per block.
// ---------------------------------------------------------------------------
__global__ __launch_bounds__(256) void pminmax(const short* __restrict__ p,
                                               unsigned* __restrict__ pmm_bits) {
    const int cg = blockIdx.x;             // 0..15 (8 channels each)
    const int lb = blockIdx.y;
    const short* pb = p + (size_t)lb * 128 * KPAD + (size_t)cg * 8 * KPAD;
    float mn = INFINITY, mx = 0.0f;
#pragma unroll
    for (int c = 0; c < 8; ++c) {
        const short* pc = pb + (size_t)c * KPAD;
        for (int i8 = threadIdx.x; i8 < PIX2 / 8; i8 += 256) {   // 461 vectors
            short8 v = *reinterpret_cast<const short8*>(&pc[i8 * 8]);
#pragma unroll
            for (int j = 0; j < 8; ++j) {
                float f = b2f(v[j]);
                mn = fminf(mn, f);
                mx = fmaxf(mx, f);
            }
        }
        if (threadIdx.x < PIX2 - (PIX2 / 8) * 8) {               // tail: 2 elems
            float f = b2f(pc[(PIX2 / 8) * 8 + threadIdx.x]);
            mn = fminf(mn, f);
            mx = fmaxf(mx, f);
        }
    }
    __shared__ float rmn[256], rmx[256];
    rmn[threadIdx.x] = mn; rmx[threadIdx.x] = mx;
    __syncthreads();
    for (int s = 128; s > 0; s >>= 1) {
        if (threadIdx.x < s) {
            rmn[threadIdx.x] = fminf(rmn[threadIdx.x], rmn[threadIdx.x + s]);
            rmx[threadIdx.x] = fmaxf(rmx[threadIdx.x], rmx[threadIdx.x + s]);
        }
        __syncthreads();
    }
    if (threadIdx.x == 0) {
        atomicMin(&pmm_bits[lb * 2],     __float_as_uint(rmn[0]));
        atomicMax(&pmm_bits[lb * 2 + 1], __float_as_uint(rmx[0]));
    }
}

// ---------------------------------------------------------------------------
// K11a: K-split einsum via bf16 MFMA, pmap fused into A-staging.
// NKC=20 chunks of 192 k (3x64) -> 640 blocks = 2.5/CU.
// ---------------------------------------------------------------------------
__global__ __launch_bounds__(256) void einsum_part(const short* __restrict__ pp2,
                                                   const short* __restrict__ fxb,
                                                   const float* __restrict__ mm_,
                                                   float* __restrict__ px_part) {
    const int kc = blockIdx.x;   // 0..NKC-1
    const int lb = blockIdx.y;
    const int gb = gridDim.y;
    const int tid = threadIdx.x;
    const int wave = tid >> 6, lane = tid & 63;
    const int mm = lane & 15, q = lane >> 4;
    constexpr int AP = 72;
    __shared__ __align__(16) short As[128 * AP];
    __shared__ __align__(16) short Bs[128 * AP];

    const float mn = mm_[lb * 2];
    const float denom = fmaxf(mm_[lb * 2 + 1] - mn, 1e-4f);
    const float rden = 1.0f / denom;

    floatx4 acc[2][8];
#pragma unroll
    for (int a = 0; a < 2; ++a)
#pragma unroll
        for (int n = 0; n < 8; ++n) acc[a][n] = (floatx4){0.f, 0.f, 0.f, 0.f};

    const short* Ab = pp2 + (size_t)lb * 128 * KPAD;
    const short* Bb = fxb + (size_t)lb * 128 * KPAD;

    for (int it = 0; it < ITC; ++it) {
        const int kk = kc * (ITC * 64) + it * 64;
        if (kk >= KTOT) break;
        for (int e = tid; e < 2048; e += 256) {
            const bool isA = (e < 1024);
            const int e2 = isA ? e : e - 1024;
            const int row = e2 >> 3, i8 = e2 & 7;
            const int k = kk + i8 * 8;
            const short* src = (isA ? Ab : Bb) + (size_t)row * KPAD + k;
            short8 v = {0, 0, 0, 0, 0, 0, 0, 0};
            if (k + 8 <= KTOT) {
                v = *reinterpret_cast<const short8*>(src);
            } else {
#pragma unroll
                for (int j = 0; j < 8; ++j) v[j] = (k + j < KTOT) ? src[j] : (short)0;
            }
            if (isA) {
#pragma unroll
                for (int j = 0; j < 8; ++j) {
                    if (k + j < KTOT) {
                        float f = (b2f(v[j]) - mn) * rden;
                        v[j] = f2bf(1.0f / (1.0f + expf(-10.0f * (f - 0.5f))));
                    } else v[j] = 0;
                }
                *reinterpret_cast<short8*>(&As[row * AP + i8 * 8]) = v;
            } else {
                *reinterpret_cast<short8*>(&Bs[row * AP + i8 * 8]) = v;
            }
        }
        __syncthreads();
#pragma unroll
        for (int ks = 0; ks < 2; ++ks) {
            short8 af0 = *reinterpret_cast<const short8*>(&As[((2 * wave) * 16 + mm) * AP + ks * 32 + q * 8]);
            short8 af1 = *reinterpret_cast<const short8*>(&As[((2 * wave + 1) * 16 + mm) * AP + ks * 32 + q * 8]);
#pragma unroll
            for (int n = 0; n < 8; ++n) {
                short8 bf = *reinterpret_cast<const short8*>(&Bs[(n * 16 + mm) * AP + ks * 32 + q * 8]);
                acc[0][n] = __builtin_amdgcn_mfma_f32_16x16x32_bf16(af0, bf, acc[0][n], 0, 0, 0);
                acc[1][n] = __builtin_amdgcn_mfma_f32_16x16x32_bf16(af1, bf, acc[1][n], 0, 0, 0);
            }
        }
        __syncthreads();
    }

    float* base = px_part + ((size_t)kc * gb + lb) * EL_PX;
#pragma unroll
    for (int a = 0; a < 2; ++a) {
        const int gm0 = (2 * wave + a) * 16 + q * 4;
#pragma unroll
        for (int n = 0; n < 8; ++n) {
            const int gn = n * 16 + mm;
#pragma unroll
            for (int r = 0; r < 4; ++r)
                base[(size_t)(gm0 + r) * 128 + gn] = acc[a][n][r];
        }
    }
}

// ---------------------------------------------------------------------------
// K11b: reduce the NKC partials -> px (applies 1/3690)
// ---------------------------------------------------------------------------
__global__ __launch_bounds__(256) void px_reduce(const float* __restrict__ part,
                                                 float* __restrict__ px,
                                                 int gb) {
    int i = blockIdx.x * 256 + threadIdx.x;
    if (i >= gb * EL_PX) return;
    int lb = i / EL_PX;
    int r = i % EL_PX;
    float s = 0.0f;
#pragma unroll
    for (int kc = 0; kc < NKC; ++kc)
        s += part[((size_t)kc * gb + lb) * EL_PX + r];
    px[i] = s * (1.0f / (float)KTOT);
}

// ---------------------------------------------------------------------------
// K12: FC as split-K f32 GEMM. fc_w read exactly once.
// ---------------------------------------------------------------------------
__global__ __launch_bounds__(256) void fc_wt(const float* __restrict__ w,
                                             float* __restrict__ wT) {
    __shared__ float t[32][33];
    const int bk = blockIdx.x * 32;   // k tile (0..16383)
    const int bo = blockIdx.y * 32;   // o tile (0..255)
    const int tx = threadIdx.x & 31;
    const int ty = threadIdx.x >> 5;  // 0..7
#pragma unroll
    for (int r = 0; r < 4; ++r) {
        int o = bo + ty + r * 8;
        t[ty + r * 8][tx] = w[(size_t)o * EL_PX + bk + tx];
    }
    __syncthreads();
#pragma unroll
    for (int r = 0; r < 4; ++r) {
        int k = bk + ty + r * 8;
        wT[(size_t)k * 256 + bo + tx] = t[tx][ty + r * 8];
    }
}

__global__ __launch_bounds__(256) void fc_part(const float* __restrict__ px,
                                               const float* __restrict__ wT,
                                               float* __restrict__ part) {
    const int kc = blockIdx.x;          // 0..NKF-1
    const int o = threadIdx.x;          // 0..255
    const int k0 = kc * KCF;
    float acc[32];
#pragma unroll
    for (int lb = 0; lb < 32; ++lb) acc[lb] = 0.0f;

    for (int k8 = 0; k8 < KCF; k8 += 8) {
        float wv[8];
#pragma unroll
        for (int j = 0; j < 8; ++j)
            wv[j] = wT[(size_t)(k0 + k8 + j) * 256 + o];
#pragma unroll
        for (int lb = 0; lb < 32; ++lb) {
            const float* pc = px + (size_t)lb * EL_PX + k0 + k8;
            float4 p0 = *reinterpret_cast<const float4*>(pc);
            float4 p1 = *reinterpret_cast<const float4*>(pc + 4);
            acc[lb] += wv[0] * p0.x + wv[1] * p0.y + wv[2] * p0.z + wv[3] * p0.w
                     + wv[4] * p1.x + wv[5] * p1.y + wv[6] * p1.z + wv[7] * p1.w;
        }
    }
    float* pb = part + (size_t)kc * (32 * 256);
#pragma unroll
    for (int lb = 0; lb < 32; ++lb)
        pb[lb * 256 + o] = acc[lb];
}

__global__ __launch_bounds__(256) void fc_out(const float* __restrict__ part,
                                              const float* __restrict__ fcb,
                                              float* __restrict__ out) {
    const int i = blockIdx.x * 256 + threadIdx.x;   // 0..8191
    float s = 0.0f;
    for (int c = 0; c < NKF; ++c)
        s += part[(size_t)c * 8192 + i];
    out[i] = s + fcb[i & 255];
}

// ---------------------------------------------------------------------------
// K12 (fallback for GB<32): FC -> f32 out
// ---------------------------------------------------------------------------
__global__ __launch_bounds__(256) void fc_k(const float* __restrict__ px,
                                            const float* __restrict__ w,
                                            const float* __restrict__ bias,
                                            float* __restrict__ out,
                                            int b0) {
    const int gw = blockIdx.x * 4 + (threadIdx.x >> 6);
    const int lane = threadIdx.x & 63;
    const int lb = gw >> 8;
    const int o = gw & 255;
    const float* xb = px + (size_t)lb * EL_PX;
    const float* wr = w + (size_t)o * EL_PX;
    float s = 0.0f;
    for (int k = lane; k < EL_PX; k += 64) s += xb[k] * wr[k];
#pragma unroll
    for (int off = 32; off > 0; off >>= 1) s += __shfl_down(s, off);
    if (lane == 0) out[(size_t)(b0 + lb) * 256 + o] = s + bias[o];
}

// ---------------------------------------------------------------------------
extern "C" void kernel_launch(void* const* d_in, const int* in_sizes, int n_in,
                              void* d_out, int out_size, void* d_ws, size_t ws_size,
                              hipStream_t stream) {
    const float* x_t   = (const float*)d_in[0];
    const float* image = (const float*)d_in[1];
    const float* c1_w  = (const float*)d_in[2];
    const float* c1_b  = (const float*)d_in[3];
    const float* bn1_g = (const float*)d_in[4];
    const float* bn1_b = (const float*)d_in[5];
    const float* c2_w  = (const float*)d_in[6];
    const float* c2_b  = (const float*)d_in[7];
    const float* bn2_g = (const float*)d_in[8];
    const float* bn2_b = (const float*)d_in[9];
    const float* a1_w  = (const float*)d_in[10];
    const float* a1_b  = (const float*)d_in[11];
    const float* abn1_g= (const float*)d_in[12];
    const float* abn1_b= (const float*)d_in[13];
    const float* a2_w  = (const float*)d_in[14];
    const float* a2_b  = (const float*)d_in[15];
    const float* abn2_g= (const float*)d_in[16];
    const float* abn2_b= (const float*)d_in[17];
    const float* p1_w  = (const float*)d_in[18];
    const float* p1_b  = (const float*)d_in[19];
    const float* pbn1_g= (const float*)d_in[20];
    const float* pbn1_b= (const float*)d_in[21];
    const float* p2_w  = (const float*)d_in[22];
    const float* p2_b  = (const float*)d_in[23];
    const float* pbn2_g= (const float*)d_in[24];
    const float* pbn2_b= (const float*)d_in[25];
    const float* fc_w  = (const float*)d_in[26];
    const float* fc_b  = (const float*)d_in[27];
    float* outp = (float*)d_out;

    // Fixed region: folded bf16 weights + biases
    float* ws = (float*)d_ws;
    short* wTa1 = (short*)ws;
    short* wTa2 = wTa1 + WSH_A1;
    short* wTp1 = wTa2 + WSH_A2;
    short* wTp2 = wTp1 + WSH_A1;
    short* wTc2 = wTp2 + WSH_A2;
    float* bfa1 = ws + WSH_TOT / 2;
    float* bfa2 = bfa1 + 128;
    float* bfp1 = bfa2 + 128;
    float* bfp2 = bfp1 + 128;
    float* bfc2 = bfp2 + 128;
    float* dyn  = bfc2 + 128;
    const size_t fixed_floats = WSH_TOT / 2 + 1024;

    int GB = 32;
    while (GB > 1) {
        size_t need = ((size_t)GB * EL_PER_BATCH + fixed_floats + 256) * sizeof(float);
        if (need <= ws_size) break;
        GB >>= 1;
    }
    const int ngroups = NB / GB;

    float* heat = dyn;                                 // GB*EL_HEAT
    float* m    = heat + (size_t)GB * EL_HEAT;         // 64
    float* regB = m + 64;                              // GB*EL_REGB
    float* regC = regB + (size_t)GB * EL_REGB;         // GB*EL_REGC
    float* regD = regC + (size_t)GB * EL_REGC;         // GB*EL_REGD
    float* regE = regD + (size_t)GB * EL_REGD;         // GB*EL_REGE
    float* pmm  = regE + (size_t)GB * EL_REGE;         // 128
    float* px   = pmm + 128;                           // GB*EL_PX

    // Optional regF for pp2 (enables merged a2+p2): after px.
    const size_t need_merged = ((size_t)GB * (EL_PER_BATCH + EL_REGD) + fixed_floats + 256) * sizeof(float);
    const bool MRG = (GB == 32) && (ws_size >= need_merged);
    float* regF = px + (size_t)GB * EL_PX;

    float* G      = regD;            // [lb][181][330] f32 (dead after rowcombine)
    short* out1b  = (short*)regB;    // bf16 ch-last [H1*W1][32]
    short* out2b  = (short*)regC;    // bf16 ch-last [pixel][64]
    short* fbuf   = (short*)regD;    // bf16 ch-last [pixel][128] (a1 out)
    short* fxbf   = (short*)regE;    // bf16 ch-first [c][KPAD]
    short* pp1    = (short*)regB;    // bf16 ch-last (out1 dead)
    short* pp2    = MRG ? (short*)regF : (short*)regD;  // bf16 ch-first [c][KPAD]
    float* pxpart = regB;            // f32, NKC*GB*EL_PX = 10.49M, spans regB+regC (both dead)
    // FC-phase aliases (valid once einsum_part/px_reduce are done):
    float* fcwT   = regD;            // f32 wT[16384][256] (fbuf/pp2 dead)
    float* fcpart = regB;            // f32 NKF*8192 (pxpart dead after px_reduce)

    wfold_k<<<(9 * 128 * CH2 + 255) / 256, 256, 0, stream>>>(a1_w, abn1_g, a1_b, abn1_b, wTa1, bfa1, 128, CH2);
    wfold_k<<<(9 * 128 * CH3 + 255) / 256, 256, 0, stream>>>(a2_w, abn2_g, a2_b, abn2_b, wTa2, bfa2, 128, CH3);
    wfold_k<<<(9 * 128 * CH2 + 255) / 256, 256, 0, stream>>>(p1_w, pbn1_g, p1_b, pbn1_b, wTp1, bfp1, 128, CH2);
    wfold_k<<<(9 * 128 * CH3 + 255) / 256, 256, 0, stream>>>(p2_w, pbn2_g, p2_b, pbn2_b, wTp2, bfp2, 128, CH3);
    wfold_k<<<(9 * 64 * 32 + 255) / 256, 256, 0, stream>>>(c2_w, bn2_g, c2_b, bn2_b, wTc2, bfc2, 64, 32);

    for (int gidx = 0; gidx < ngroups; ++gidx) {
        const int b0 = gidx * GB;
        mm_init<<<1, 256, 0, stream>>>((unsigned*)m, (unsigned*)pmm);
        heat_scatter_cols<<<dim3(NSTRIP, GB), 256, 0, stream>>>(x_t, G, b0);
        heat_rowcombine<<<dim3(IH / BXR, GB, 2), 256, 0, stream>>>(G, heat, (unsigned*)m);
        conv1_pool<<<(GB * H1 * W1 + 255) / 256, 256, 0, stream>>>(
            heat, image, m, c1_w, c1_b, bn1_g, bn1_b, out1b, b0, GB);
        conv2_mfma<<<dim3(6, 12, GB), 256, 0, stream>>>(out1b, wTc2, bfc2, out2b);
        // merged a1+p1 (shared input, disjoint outputs; per-block body = round-3)
        conv3x3_mfma<CH2, 0, 0, true><<<dim3(3, 24, GB), 256, 0, stream>>>(
            out2b, out2b, wTa1, wTp1, bfa1, bfp1, fbuf, pp1);
        if (MRG) {
            // merged a2+p2: independent inputs (fbuf, pp1), disjoint outputs (fxbf, pp2=regF)
            conv3x3_mfma<CH3, 2, 2, true><<<dim3(3, 24, GB), 256, 0, stream>>>(
                fbuf, pp1, wTa2, wTp2, bfa2, bfp2, fxbf, pp2);
        } else {
            conv3x3_mfma<CH3, 2, 1, false><<<dim3(3, 12, GB), 256, 0, stream>>>(
                fbuf, fbuf, wTa2, wTa2, bfa2, bfa2, fxbf, fxbf);
            conv3x3_mfma<CH3, 2, 0, false><<<dim3(3, 12, GB), 256, 0, stream>>>(
                pp1, pp1, wTp2, wTp2, bfp2, bfp2, pp2, pp2);
        }
        pminmax<<<dim3(16, GB), 256, 0, stream>>>(pp2, (unsigned*)pmm);
        einsum_part<<<dim3(NKC, GB), 256, 0, stream>>>(pp2, fxbf, pmm, pxpart);
        px_reduce<<<(GB * EL_PX + 255) / 256, 256, 0, stream>>>(pxpart, px, GB);
        if (GB == 32) {
            fc_wt<<<dim3(EL_PX / 32, 256 / 32), 256, 0, stream>>>(fc_w, fcwT);
            fc_part<<<NKF, 256, 0, stream>>>(px, fcwT, fcpart);
            fc_out<<<8192 / 256, 256, 0, stream>>>(fcpart, fc_b, outp);
        } else {
            fc_k<<<GB * 64, 256, 0, stream>>>(px, fc_w, fc_b, outp, b0);
        }
    }
}

// Round 13
// 551.767 us; speedup vs baseline: 1.1349x; 1.0384x over previous
//
#include <hip/hip_runtime.h>
#include <hip/hip_bf16.h>

// Problem constants
#define NB 32
#define NT 1024
#define IH 180
#define IW 330
#define KSZ 37
#define XBINS 181
#define H1 90
#define W1 165
#define H2 45
#define W2 82
#define PIX2 (H2*W2)          // 3690
#define KTOT PIX2
#define KPAD 3712
#define CH1 32
#define CH2 64
#define CH3 128
#define NSTRIP 6
#define NKC 20                // einsum K-chunks (192 each over KPAD; 640 blocks = 2.5/CU)
#define ITC 3                 // 64-k steps per chunk

// FC split-K config (round 13: 2 blocks/CU for fc_part; parallel 2-stage reduce)
#define NKF 512               // K-chunks for fc (16384/32)
#define KCF 32
#define FCSL 8                // c-slices in fc_out (each covers NKF/FCSL = 64)

// heat_rowcombine band config
#define BXR 12                // output rows per band (15 bands cover 180)
#define YHW 165               // half of IW
#define GROWS_MAX 54          // max staged G rows

// Per-batch f32-slot counts
#define EL_HEAT (IH*IW)           // 59,400
#define EL_REGB 237600            // out1 bf16 [H1*W1][32] -> pp1 bf16 [PIX2][128] -> px_part f32 -> fc partials
#define EL_REGC (CH2*PIX2/2)      // 118,080 : out2 bf16 ch-last [pixel][64]
#define EL_REGD (CH3*KPAD/2)      // 237,568 : G f32 -> fbuf bf16 -> (pp2) -> wT f32
#define EL_REGE (CH3*KPAD/2)      // 237,568 : fx bf16 [c][KPAD]
#define EL_PX   (CH3*CH3)         // 16,384
#define EL_PER_BATCH (EL_HEAT + EL_REGB + EL_REGC + EL_REGD + EL_REGE + EL_PX) // 906,600
// pxpart (NKC*GB*EL_PX = 10.49M floats) spans regB+regC (11.38M) — both dead by einsum time.
// fcpart (NKF*8192 = 4.19M) + fcpart2 (8*8192) live in regB after px_reduce.
// Optional regF (GB*EL_REGD) holds pp2 so a2+p2 can merge (pp2 no longer aliases fbuf).

// folded-weight sizes (bf16 shorts)
#define WSH_A1 (9*128*64)
#define WSH_A2 (9*128*128)
#define WSH_C2 (9*64*32)
#define WSH_TOT (2*WSH_A1 + 2*WSH_A2 + WSH_C2)

typedef __attribute__((ext_vector_type(8))) short short8;
typedef __attribute__((ext_vector_type(4))) float floatx4;

__device__ __forceinline__ short f2bf(float v) {
    __hip_bfloat16 h = __float2bfloat16(v);
    return *reinterpret_cast<short*>(&h);
}
__device__ __forceinline__ float b2f(short s) {
    __hip_bfloat16 h = *reinterpret_cast<__hip_bfloat16*>(&s);
    return __bfloat162float(h);
}

// ---------------------------------------------------------------------------
__global__ __launch_bounds__(256) void mm_init(unsigned* __restrict__ m_bits,
                                               unsigned* __restrict__ pmm_bits) {
    int i = threadIdx.x;
    if (i < 64) {
        m_bits[i] = 0u;
        pmm_bits[2 * i]     = 0x7F800000u;   // +inf
        pmm_bits[2 * i + 1] = 0u;
    }
}

// ---------------------------------------------------------------------------
// S1: separable scatter — column profiles into G[xp][Y]
// ---------------------------------------------------------------------------
__global__ __launch_bounds__(256) void heat_scatter_cols(const float* __restrict__ x_t,
                                                         float* __restrict__ G,
                                                         int b0) {
    const int strip = blockIdx.x;
    const int lb = blockIdx.y;
    const int b = b0 + lb;
    const int c0 = strip * 64;
    const int cw = min(64, IW - c0);
    __shared__ float g[XBINS * 64];
    __shared__ float k1n[64];
    __shared__ float2 pts[NT];
    const int tid = threadIdx.x;

    if (tid < 64) {
        float v = 0.0f;
        if (tid < KSZ) {
            float ax = (float)tid - 18.0f;
            v = expf(-ax * ax / 18.0f);
        }
        k1n[tid] = v;
    }
    for (int i = tid; i < XBINS * 64; i += 256) g[i] = 0.0f;
    {
        const float2* xb = (const float2*)x_t + (size_t)b * NT;
        for (int i = tid; i < NT; i += 256) pts[i] = xb[i];
    }
    __syncthreads();
    if (tid == 0) {
        float s = 0.0f;
        for (int i = 0; i < KSZ; i++) s += k1n[i];
        float inv = 1.0f / s;
        for (int i = 0; i < KSZ; i++) k1n[i] *= inv;
    }
    __syncthreads();

    const int wave = tid >> 6;
    const int lane = tid & 63;
    const float kc = k1n[lane];

    for (int p = wave; p < NT; p += 4) {
        float x = pts[p].x, y = pts[p].y;
        if (isnan(x) || isnan(y)) continue;
        int xp = IH - (int)((x - 30.0f) * 180.0f);
        xp = min(max(xp, 0), 180);
        int yp = (int)((y - 120.0f) * 165.0f);
        int ys = min(max(yp - 18, 0), IW - 36);
        int ye = min(max(yp + 18, 0), IW);
        int nc = ye - ys;
        int col = ys + lane;
        if (lane < nc && col >= c0 && col < c0 + cw)
            atomicAdd(&g[xp * 64 + col - c0], kc);
    }
    __syncthreads();
    for (int i = tid; i < XBINS * cw; i += 256) {
        int row = i / cw, col = i % cw;
        G[((size_t)lb * XBINS + row) * IW + c0 + col] = g[row * 64 + col];
    }
}

// ---------------------------------------------------------------------------
// S2: row-combine + fused per-batch max (band-tiled, LDS-staged G)
// ---------------------------------------------------------------------------
__global__ __launch_bounds__(256) void heat_rowcombine(const float* __restrict__ G,
                                                       float* __restrict__ heat,
                                                       unsigned* __restrict__ m_bits) {
    const int band = blockIdx.x;        // 0..14
    const int lb = blockIdx.y;
    const int half = blockIdx.z;        // 0..1
    const int X0 = band * BXR;
    const int c0 = half * YHW;
    const int tid = threadIdx.x;

    __shared__ float k1n[64];
    __shared__ float gs[GROWS_MAX * YHW];   // 35,640 B
    __shared__ float red[256];

    if (tid < 64) {
        float v = 0.0f;
        if (tid < KSZ) {
            float ax = (float)tid - 18.0f;
            v = expf(-ax * ax / 18.0f);
        }
        k1n[tid] = v;
    }

    const int rlo = max(0, X0 - 17);
    const int rhi = (X0 + BXR - 1 >= IH - 36) ? 180 : (X0 + BXR - 1 + 18);
    const int nrows = rhi - rlo + 1;        // <= 54
    const float* Gb = G + (size_t)lb * XBINS * IW;
    for (int i = tid; i < nrows * YHW; i += 256) {
        int r = i / YHW, y = i % YHW;
        gs[i] = Gb[(size_t)(rlo + r) * IW + c0 + y];
    }
    __syncthreads();
    if (tid == 0) {
        float s = 0.0f;
        for (int i = 0; i < KSZ; i++) s += k1n[i];
        float inv = 1.0f / s;
        for (int i = 0; i < KSZ; i++) k1n[i] *= inv;
    }
    __syncthreads();

    float lmax = 0.0f;
    for (int p = tid; p < BXR * YHW; p += 256) {
        const int xr = p / YHW;
        const int yy = p % YHW;
        const int X = X0 + xr;
        const int Y = c0 + yy;
        const int lo = max(0, X - 17);
        const int hi = (X >= IH - 36) ? 180 : X + 18;
        float s = 0.0f;
        for (int xp = lo; xp <= hi; ++xp) {
            int xs = min(max(xp - 18, 0), IH - 36);
            s += k1n[X - xs] * gs[(xp - rlo) * YHW + yy];
        }
        heat[(size_t)lb * EL_HEAT + (size_t)X * IW + Y] = s;
        lmax = fmaxf(lmax, s);
    }
    red[tid] = lmax;
    __syncthreads();
    for (int st = 128; st > 0; st >>= 1) {
        if (tid < st) red[tid] = fmaxf(red[tid], red[tid + st]);
        __syncthreads();
    }
    if (tid == 0) atomicMax(&m_bits[lb], __float_as_uint(red[0]));
}

// ---------------------------------------------------------------------------
// K3: conv1(1->32) + BN + relu + pool (fuse folded); out bf16 ch-last [pix][32]
// ---------------------------------------------------------------------------
__global__ __launch_bounds__(256) void conv1_pool(const float* __restrict__ heat,
                                                  const float* __restrict__ image,
                                                  const float* __restrict__ m,
                                                  const float* __restrict__ w,
                                                  const float* __restrict__ cb,
                                                  const float* __restrict__ g,
                                                  const float* __restrict__ bb,
                                                  short* __restrict__ out1,
                                                  int b0, int gb) {
    __shared__ float ws_[CH1 * 9];
    __shared__ float bs_[CH1];
    const int tid = threadIdx.x;
    for (int i = tid; i < CH1 * 9; i += 256) {
        int oc = i / 9;
        ws_[i] = w[i] * g[oc];
    }
    if (tid < CH1) bs_[tid] = cb[tid] * g[tid] + bb[tid];
    __syncthreads();

    int t = blockIdx.x * 256 + tid;
    if (t >= gb * H1 * W1) return;
    int lb = t / (H1 * W1);
    int r = t % (H1 * W1);
    int py = r / W1, px = r % W1;
    const float s = 0.7f / (m[lb] + 1e-10f);
    const float* hb = heat + (size_t)lb * EL_HEAT;
    const float* ib = image + (size_t)(b0 + lb) * EL_HEAT;

    float v[4][4];
    int y0 = 2 * py - 1, x0 = 2 * px - 1;
#pragma unroll
    for (int i = 0; i < 4; i++) {
#pragma unroll
        for (int j = 0; j < 4; j++) {
            int y = y0 + i, x = x0 + j;
            float val = 0.0f;
            if (y >= 0 && y < IH && x >= 0 && x < IW) {
                size_t idx = (size_t)y * IW + x;
                val = s * hb[idx] + 0.3f * ib[idx];
            }
            v[i][j] = val;
        }
    }
    short8 pk[4];
#pragma unroll
    for (int oc = 0; oc < CH1; oc++) {
        float a00 = 0, a01 = 0, a10 = 0, a11 = 0;
        const float* wp = &ws_[oc * 9];
#pragma unroll
        for (int ky = 0; ky < 3; ky++) {
#pragma unroll
            for (int kx = 0; kx < 3; kx++) {
                float wv = wp[ky * 3 + kx];
                a00 += wv * v[ky][kx];
                a01 += wv * v[ky][kx + 1];
                a10 += wv * v[ky + 1][kx];
                a11 += wv * v[ky + 1][kx + 1];
            }
        }
        float bias = bs_[oc];
        a00 = fmaxf(a00 + bias, 0.0f);
        a01 = fmaxf(a01 + bias, 0.0f);
        a10 = fmaxf(a10 + bias, 0.0f);
        a11 = fmaxf(a11 + bias, 0.0f);
        pk[oc >> 3][oc & 7] = f2bf(fmaxf(fmaxf(a00, a01), fmaxf(a10, a11)));
    }
    short8* op = reinterpret_cast<short8*>(&out1[((size_t)lb * H1 * W1 + r) * CH1]);
#pragma unroll
    for (int vv = 0; vv < 4; vv++) op[vv] = pk[vv];
}

// ---------------------------------------------------------------------------
// weight fold/transpose: wT[tap][oc][ic] = bf16(w[oc][ic][tap]*g[oc])
// ---------------------------------------------------------------------------
__global__ __launch_bounds__(256) void wfold_k(const float* __restrict__ w,
                                               const float* __restrict__ g,
                                               const float* __restrict__ cb,
                                               const float* __restrict__ bb,
                                               short* __restrict__ wT,
                                               float* __restrict__ bfold,
                                               int OC, int IC) {
    int i = blockIdx.x * 256 + threadIdx.x;
    int n = 9 * OC * IC;
    if (i >= n) return;
    int tap = i / (OC * IC);
    int r = i % (OC * IC);
    int oc = r / IC;
    int ic = r % IC;
    wT[i] = f2bf(w[((size_t)oc * IC + ic) * 9 + tap] * g[oc]);
    if (tap == 0 && ic == 0) bfold[oc] = cb[oc] * g[oc] + bb[oc];
}

// ---------------------------------------------------------------------------
// K4: conv2(32->64) + BN + relu + 2x2 pool via bf16 MFMA.
// ---------------------------------------------------------------------------
__global__ __launch_bounds__(256) void conv2_mfma(const short* __restrict__ in,
                                                  const short* __restrict__ wT,
                                                  const float* __restrict__ bfold,
                                                  short* __restrict__ out) {
    const int xt = blockIdx.x;   // 0..5 : 32 pre-pool cols
    const int yt = blockIdx.y;   // 0..11: 8 pre-pool rows
    const int lb = blockIdx.z;
    const int x0 = xt * 32, y0 = yt * 8;
    const int tid = threadIdx.x;
    const int wave = tid >> 6, lane = tid & 63;
    const int mm = lane & 15, q = lane >> 4;
    constexpr int AP = 40;
    constexpr int CP = 72;                      // C-stage stride (16B-aligned rows)
    __shared__ __align__(16) short smem[10 * 34 * AP];   // 27,200 B (>= 64*CP=9,216)

    floatx4 acc[2][2][4];
#pragma unroll
    for (int a = 0; a < 2; ++a)
#pragma unroll
        for (int bq = 0; bq < 2; ++bq)
#pragma unroll
            for (int j = 0; j < 4; ++j) acc[a][bq][j] = (floatx4){0.f, 0.f, 0.f, 0.f};

    const short* inb = in + (size_t)lb * (H1 * W1) * CH1;
    for (int e = tid; e < 10 * 34 * 4; e += 256) {
        int dy = e / (34 * 4);
        int r = e % (34 * 4);
        int tx = r / 4;
        int i8 = r % 4;
        int yin = y0 + dy - 1, xin = x0 + tx - 1;
        short8 hv = {0, 0, 0, 0, 0, 0, 0, 0};
        if (yin >= 0 && yin < H1 && xin >= 0 && xin < W1)
            hv = *reinterpret_cast<const short8*>(&inb[((size_t)(yin * W1 + xin)) * CH1 + i8 * 8]);
        *reinterpret_cast<short8*>(&smem[(dy * 34 + tx) * AP + i8 * 8]) = hv;
    }
    __syncthreads();

#pragma unroll
    for (int tap = 0; tap < 9; ++tap) {
        const int dy = tap / 3, dx = tap % 3;
        short8 bf[4];
#pragma unroll
        for (int j = 0; j < 4; ++j)
            bf[j] = *reinterpret_cast<const short8*>(&wT[((size_t)tap * 64 + j * 16 + mm) * 32 + q * 8]);
#pragma unroll
        for (int row = 0; row < 2; ++row) {
#pragma unroll
            for (int xh = 0; xh < 2; ++xh) {
                short8 af = *reinterpret_cast<const short8*>(
                    &smem[((2 * wave + row + dy) * 34 + xh * 16 + dx + mm) * AP + q * 8]);
#pragma unroll
                for (int j = 0; j < 4; ++j)
                    acc[row][xh][j] = __builtin_amdgcn_mfma_f32_16x16x32_bf16(af, bf[j], acc[row][xh][j], 0, 0, 0);
            }
        }
    }
    __syncthreads();

    // stage pooled C into LDS: [local pooled pixel 0..63][CP]
    short* cst = smem;
#pragma unroll
    for (int xh = 0; xh < 2; ++xh) {
#pragma unroll
        for (int j = 0; j < 4; ++j) {
            const float bias = bfold[j * 16 + mm];
#pragma unroll
            for (int rp = 0; rp < 2; ++rp) {
                int pxl = xh * 8 + q * 2 + rp;            // 0..15
                float v = fmaxf(fmaxf(acc[0][xh][j][2 * rp], acc[0][xh][j][2 * rp + 1]),
                                fmaxf(acc[1][xh][j][2 * rp], acc[1][xh][j][2 * rp + 1]));
                v = fmaxf(v + bias, 0.0f);
                cst[(wave * 16 + pxl) * CP + j * 16 + mm] = f2bf(v);
            }
        }
    }
    __syncthreads();

    // coalesced copy-out: 64 px x 8 short8
    short* ob = out + (size_t)lb * PIX2 * CH2;
    for (int e = tid; e < 512; e += 256) {
        int pl = e >> 3, c8 = e & 7;
        int py = yt * 4 + (pl >> 4);
        int pxg = xt * 16 + (pl & 15);
        if (py < H2 && pxg < W2)
            *reinterpret_cast<short8*>(&ob[((size_t)py * W2 + pxg) * CH2 + c8 * 8]) =
                *reinterpret_cast<const short8*>(&cst[pl * CP + c8 * 8]);
    }
}

// ---------------------------------------------------------------------------
// K5-K8: 3x3 conv via bf16 MFMA; bf16 ch-last input; 32x4 tile.
// (exact round-3 per-block structure — KC=32; frozen)
// OM: 0 = bf16 ch-last out, 2 = bf16 ch-first [oc][KPAD].
// DUAL: grid.y = 24; sel = blockIdx.y/12 picks {iA,wA,bA,oA} vs {iB,wB,bB,oB}.
// SIGMODE: 0 = relu both; 1 = sigmoid; 2 = sel0 sigmoid / sel1 relu (a2+p2).
// ---------------------------------------------------------------------------
template <int IC, int OM, int SIGMODE, bool DUAL>
__global__ __launch_bounds__(256) void conv3x3_mfma(const short* __restrict__ iA,
                                                    const short* __restrict__ iB,
                                                    const short* __restrict__ wA,
                                                    const short* __restrict__ wB,
                                                    const float* __restrict__ bA,
                                                    const float* __restrict__ bB,
                                                    short* __restrict__ oA,
                                                    short* __restrict__ oB) {
    const int xt = blockIdx.x;                          // 0..2 (32 cols)
    const int yt = DUAL ? (blockIdx.y % 12) : blockIdx.y;   // 0..11 (4 rows)
    const int sel = DUAL ? (blockIdx.y / 12) : 0;
    const int lb = blockIdx.z;
    const int x0 = xt * 32, y0 = yt * 4;
    const int tid = threadIdx.x;
    const int wave = tid >> 6, lane = tid & 63;
    const int mm = lane & 15, q = lane >> 4;

    const short* in = (DUAL && sel) ? iB : iA;
    const short* wT = (DUAL && sel) ? wB : wA;
    const float* bfold = (DUAL && sel) ? bB : bA;
    short* outp = (DUAL && sel) ? oB : oA;
    const bool sig = (SIGMODE == 1) || (SIGMODE == 2 && sel == 0);

    constexpr int KC = 32;
    constexpr int NCH = IC / KC;
    constexpr int AP = 40;
    constexpr int CP0 = 136;   // [pixel][128] stage stride (16B-aligned, 2-way banks)
    constexpr int CP2 = 132;   // [oc][pixel] stage stride (4B-aligned, distinct banks)
    // max(tileA 8160, OM0 128*136=17408, OM2 128*132=16896) shorts
    __shared__ __align__(16) short smem[17408];

    floatx4 acc[16];
#pragma unroll
    for (int i = 0; i < 16; ++i) acc[i] = (floatx4){0.f, 0.f, 0.f, 0.f};

    const short* inb = in + (size_t)lb * PIX2 * IC;

    for (int c = 0; c < NCH; ++c) {
        const int ic0 = c * KC;
        for (int e = tid; e < 6 * 34 * (KC / 8); e += 256) {
            int dy = e / (34 * (KC / 8));
            int r  = e % (34 * (KC / 8));
            int tx = r / (KC / 8);
            int i8 = r % (KC / 8);
            int yin = y0 + dy - 1, xin = x0 + tx - 1;
            short8 hv = {0, 0, 0, 0, 0, 0, 0, 0};
            if (yin >= 0 && yin < H2 && xin >= 0 && xin < W2)
                hv = *reinterpret_cast<const short8*>(
                    &inb[((size_t)(yin * W2 + xin)) * IC + ic0 + i8 * 8]);
            *reinterpret_cast<short8*>(&smem[(dy * 34 + tx) * AP + i8 * 8]) = hv;
        }
        __syncthreads();

        const int oc0 = wave * 32 + mm;
#pragma unroll
        for (int tap = 0; tap < 9; ++tap) {
            const int dy = tap / 3, dx = tap % 3;
            short8 b0 = *reinterpret_cast<const short8*>(
                &wT[((size_t)tap * 128 + oc0) * IC + ic0 + q * 8]);
            short8 b1 = *reinterpret_cast<const short8*>(
                &wT[((size_t)tap * 128 + oc0 + 16) * IC + ic0 + q * 8]);
#pragma unroll
            for (int t = 0; t < 8; ++t) {
                const int tr = t >> 1, tc = t & 1;
                short8 af = *reinterpret_cast<const short8*>(
                    &smem[((tr + dy) * 34 + tc * 16 + dx + mm) * AP + q * 8]);
                acc[t * 2]     = __builtin_amdgcn_mfma_f32_16x16x32_bf16(af, b0, acc[t * 2], 0, 0, 0);
                acc[t * 2 + 1] = __builtin_amdgcn_mfma_f32_16x16x32_bf16(af, b1, acc[t * 2 + 1], 0, 0, 0);
            }
        }
        __syncthreads();
    }

    // stage C into LDS
    const int oc0 = wave * 32 + mm;
    const float bias0 = bfold[oc0];
    const float bias1 = bfold[oc0 + 16];
    short* cst = smem;
#pragma unroll
    for (int t = 0; t < 8; ++t) {
        const int tr = t >> 1, tc = t & 1;
#pragma unroll
        for (int r = 0; r < 4; ++r) {
            int pl = tr * 32 + tc * 16 + q * 4 + r;       // 0..127
            float z0 = acc[t * 2][r] + bias0;
            float z1 = acc[t * 2 + 1][r] + bias1;
            if (sig) {
                z0 = 1.0f / (1.0f + expf(-z0));
                z1 = 1.0f / (1.0f + expf(-z1));
            } else {
                z0 = fmaxf(z0, 0.0f);
                z1 = fmaxf(z1, 0.0f);
            }
            if (OM == 0) {
                cst[pl * CP0 + oc0] = f2bf(z0);
                cst[pl * CP0 + oc0 + 16] = f2bf(z1);
            } else {
                cst[oc0 * CP2 + pl] = f2bf(z0);
                cst[(oc0 + 16) * CP2 + pl] = f2bf(z1);
            }
        }
    }
    __syncthreads();

    if (OM == 0) {
        short* ob = outp + (size_t)lb * PIX2 * 128;
        for (int e = tid; e < 2048; e += 256) {
            int pl = e >> 4, c8 = e & 15;
            int yy = y0 + (pl >> 5), xx = x0 + (pl & 31);
            if (yy < H2 && xx < W2)
                *reinterpret_cast<short8*>(&ob[((size_t)yy * W2 + xx) * 128 + c8 * 8]) =
                    *reinterpret_cast<const short8*>(&cst[pl * CP0 + c8 * 8]);
        }
    } else {
        short* ob = outp + (size_t)lb * 128 * KPAD;
        for (int e = tid; e < 8192; e += 256) {
            int oc = e >> 6;                   // 0..127
            int r2 = e & 63;
            int yy4 = r2 >> 4;                 // 0..3
            int x2 = (r2 & 15) * 2;            // 0..30
            int yy = y0 + yy4, xx = x0 + x2;
            if (yy < H2 && xx < W2) {
                int pl = yy4 * 32 + x2;
                if (xx + 1 < W2) {
                    *reinterpret_cast<int*>(&ob[(size_t)oc * KPAD + yy * W2 + xx]) =
                        *reinterpret_cast<const int*>(&cst[oc * CP2 + pl]);
                } else {
                    ob[(size_t)oc * KPAD + yy * W2 + xx] = cst[oc * CP2 + pl];
                }
            }
        }
    }
}

// ---------------------------------------------------------------------------
// K9: per-batch min/max of pp2 (bf16 ch-first [c][KPAD], valid hw < PIX2).
// ---------------------------------------------------------------------------
__global__ __launch_bounds__(256) void pminmax(const short* __restrict__ p,
                                               unsigned* __restrict__ pmm_bits) {
    const int cg = blockIdx.x;             // 0..15 (8 channels each)
    const int lb = blockIdx.y;
    const short* pb = p + (size_t)lb * 128 * KPAD + (size_t)cg * 8 * KPAD;
    float mn = INFINITY, mx = 0.0f;
#pragma unroll
    for (int c = 0; c < 8; ++c) {
        const short* pc = pb + (size_t)c * KPAD;
        for (int i8 = threadIdx.x; i8 < PIX2 / 8; i8 += 256) {   // 461 vectors
            short8 v = *reinterpret_cast<const short8*>(&pc[i8 * 8]);
#pragma unroll
            for (int j = 0; j < 8; ++j) {
                float f = b2f(v[j]);
                mn = fminf(mn, f);
                mx = fmaxf(mx, f);
            }
        }
        if (threadIdx.x < PIX2 - (PIX2 / 8) * 8) {               // tail: 2 elems
            float f = b2f(pc[(PIX2 / 8) * 8 + threadIdx.x]);
            mn = fminf(mn, f);
            mx = fmaxf(mx, f);
        }
    }
    __shared__ float rmn[256], rmx[256];
    rmn[threadIdx.x] = mn; rmx[threadIdx.x] = mx;
    __syncthreads();
    for (int s = 128; s > 0; s >>= 1) {
        if (threadIdx.x < s) {
            rmn[threadIdx.x] = fminf(rmn[threadIdx.x], rmn[threadIdx.x + s]);
            rmx[threadIdx.x] = fmaxf(rmx[threadIdx.x], rmx[threadIdx.x + s]);
        }
        __syncthreads();
    }
    if (threadIdx.x == 0) {
        atomicMin(&pmm_bits[lb * 2],     __float_as_uint(rmn[0]));
        atomicMax(&pmm_bits[lb * 2 + 1], __float_as_uint(rmx[0]));
    }
}

// ---------------------------------------------------------------------------
// K11a: K-split einsum via bf16 MFMA, pmap fused into A-staging.
// ---------------------------------------------------------------------------
__global__ __launch_bounds__(256) void einsum_part(const short* __restrict__ pp2,
                                                   const short* __restrict__ fxb,
                                                   const float* __restrict__ mm_,
                                                   float* __restrict__ px_part) {
    const int kc = blockIdx.x;   // 0..NKC-1
    const int lb = blockIdx.y;
    const int gb = gridDim.y;
    const int tid = threadIdx.x;
    const int wave = tid >> 6, lane = tid & 63;
    const int mm = lane & 15, q = lane >> 4;
    constexpr int AP = 72;
    __shared__ __align__(16) short As[128 * AP];
    __shared__ __align__(16) short Bs[128 * AP];

    const float mn = mm_[lb * 2];
    const float denom = fmaxf(mm_[lb * 2 + 1] - mn, 1e-4f);
    const float rden = 1.0f / denom;

    floatx4 acc[2][8];
#pragma unroll
    for (int a = 0; a < 2; ++a)
#pragma unroll
        for (int n = 0; n < 8; ++n) acc[a][n] = (floatx4){0.f, 0.f, 0.f, 0.f};

    const short* Ab = pp2 + (size_t)lb * 128 * KPAD;
    const short* Bb = fxb + (size_t)lb * 128 * KPAD;

    for (int it = 0; it < ITC; ++it) {
        const int kk = kc * (ITC * 64) + it * 64;
        if (kk >= KTOT) break;
        for (int e = tid; e < 2048; e += 256) {
            const bool isA = (e < 1024);
            const int e2 = isA ? e : e - 1024;
            const int row = e2 >> 3, i8 = e2 & 7;
            const int k = kk + i8 * 8;
            const short* src = (isA ? Ab : Bb) + (size_t)row * KPAD + k;
            short8 v = {0, 0, 0, 0, 0, 0, 0, 0};
            if (k + 8 <= KTOT) {
                v = *reinterpret_cast<const short8*>(src);
            } else {
#pragma unroll
                for (int j = 0; j < 8; ++j) v[j] = (k + j < KTOT) ? src[j] : (short)0;
            }
            if (isA) {
#pragma unroll
                for (int j = 0; j < 8; ++j) {
                    if (k + j < KTOT) {
                        float f = (b2f(v[j]) - mn) * rden;
                        v[j] = f2bf(1.0f / (1.0f + expf(-10.0f * (f - 0.5f))));
                    } else v[j] = 0;
                }
                *reinterpret_cast<short8*>(&As[row * AP + i8 * 8]) = v;
            } else {
                *reinterpret_cast<short8*>(&Bs[row * AP + i8 * 8]) = v;
            }
        }
        __syncthreads();
#pragma unroll
        for (int ks = 0; ks < 2; ++ks) {
            short8 af0 = *reinterpret_cast<const short8*>(&As[((2 * wave) * 16 + mm) * AP + ks * 32 + q * 8]);
            short8 af1 = *reinterpret_cast<const short8*>(&As[((2 * wave + 1) * 16 + mm) * AP + ks * 32 + q * 8]);
#pragma unroll
            for (int n = 0; n < 8; ++n) {
                short8 bf = *reinterpret_cast<const short8*>(&Bs[(n * 16 + mm) * AP + ks * 32 + q * 8]);
                acc[0][n] = __builtin_amdgcn_mfma_f32_16x16x32_bf16(af0, bf, acc[0][n], 0, 0, 0);
                acc[1][n] = __builtin_amdgcn_mfma_f32_16x16x32_bf16(af1, bf, acc[1][n], 0, 0, 0);
            }
        }
        __syncthreads();
    }

    float* base = px_part + ((size_t)kc * gb + lb) * EL_PX;
#pragma unroll
    for (int a = 0; a < 2; ++a) {
        const int gm0 = (2 * wave + a) * 16 + q * 4;
#pragma unroll
        for (int n = 0; n < 8; ++n) {
            const int gn = n * 16 + mm;
#pragma unroll
            for (int r = 0; r < 4; ++r)
                base[(size_t)(gm0 + r) * 128 + gn] = acc[a][n][r];
        }
    }
}

// ---------------------------------------------------------------------------
// K11b: reduce the NKC partials -> px (applies 1/3690)
// ---------------------------------------------------------------------------
__global__ __launch_bounds__(256) void px_reduce(const float* __restrict__ part,
                                                 float* __restrict__ px,
                                                 int gb) {
    int i = blockIdx.x * 256 + threadIdx.x;
    if (i >= gb * EL_PX) return;
    int lb = i / EL_PX;
    int r = i % EL_PX;
    float s = 0.0f;
#pragma unroll
    for (int kc = 0; kc < NKC; ++kc)
        s += part[((size_t)kc * gb + lb) * EL_PX + r];
    px[i] = s * (1.0f / (float)KTOT);
}

// ---------------------------------------------------------------------------
// K12: FC as split-K f32 GEMM. fc_w read exactly once.
// ---------------------------------------------------------------------------
__global__ __launch_bounds__(256) void fc_wt(const float* __restrict__ w,
                                             float* __restrict__ wT) {
    __shared__ float t[32][33];
    const int bk = blockIdx.x * 32;   // k tile (0..16383)
    const int bo = blockIdx.y * 32;   // o tile (0..255)
    const int tx = threadIdx.x & 31;
    const int ty = threadIdx.x >> 5;  // 0..7
#pragma unroll
    for (int r = 0; r < 4; ++r) {
        int o = bo + ty + r * 8;
        t[ty + r * 8][tx] = w[(size_t)o * EL_PX + bk + tx];
    }
    __syncthreads();
#pragma unroll
    for (int r = 0; r < 4; ++r) {
        int k = bk + ty + r * 8;
        wT[(size_t)k * 256 + bo + tx] = t[tx][ty + r * 8];
    }
}

// fc_part: NKF=512 K-chunks of KCF=32 -> 2 blocks/CU (was 1). wT read once.
__global__ __launch_bounds__(256) void fc_part(const float* __restrict__ px,
                                               const float* __restrict__ wT,
                                               float* __restrict__ part) {
    const int kc = blockIdx.x;          // 0..NKF-1
    const int o = threadIdx.x;          // 0..255
    const int k0 = kc * KCF;
    float acc[32];
#pragma unroll
    for (int lb = 0; lb < 32; ++lb) acc[lb] = 0.0f;

    for (int k8 = 0; k8 < KCF; k8 += 8) {
        float wv[8];
#pragma unroll
        for (int j = 0; j < 8; ++j)
            wv[j] = wT[(size_t)(k0 + k8 + j) * 256 + o];
#pragma unroll
        for (int lb = 0; lb < 32; ++lb) {
            const float* pc = px + (size_t)lb * EL_PX + k0 + k8;
            float4 p0 = *reinterpret_cast<const float4*>(pc);
            float4 p1 = *reinterpret_cast<const float4*>(pc + 4);
            acc[lb] += wv[0] * p0.x + wv[1] * p0.y + wv[2] * p0.z + wv[3] * p0.w
                     + wv[4] * p1.x + wv[5] * p1.y + wv[6] * p1.z + wv[7] * p1.w;
        }
    }
    float* pb = part + (size_t)kc * (32 * 256);
#pragma unroll
    for (int lb = 0; lb < 32; ++lb)
        pb[lb * 256 + o] = acc[lb];
}

// fc_out stage 1: reduce NKF partials -> FCSL per-slice sums.
// grid (128 output-groups of 64, FCSL c-slices) = 1024 blocks = 4/CU.
// Wave-coalesced 256B reads; LDS cross-wave reduce; deterministic.
__global__ __launch_bounds__(256) void fc_out(const float* __restrict__ part,
                                              float* __restrict__ part2) {
    const int og = blockIdx.x;          // 0..127
    const int cs = blockIdx.y;          // 0..FCSL-1
    const int il = threadIdx.x & 63;    // output within group
    const int cw = threadIdx.x >> 6;    // 0..3 wave's c-offset
    const int i = og * 64 + il;
    const int cbase = cs * (NKF / FCSL);
    float s = 0.0f;
    for (int c = cbase + cw; c < cbase + NKF / FCSL; c += 4)
        s += part[(size_t)c * 8192 + i];
    __shared__ float red[4][64];
    red[cw][il] = s;
    __syncthreads();
    if (threadIdx.x < 64) {
        float v = red[0][il] + red[1][il] + red[2][il] + red[3][il];
        part2[(size_t)cs * 8192 + i] = v;
    }
}

// fc_out stage 2: sum FCSL slices + bias -> out[32][256]
__global__ __launch_bounds__(256) void fc_fin(const float* __restrict__ part2,
                                              const float* __restrict__ fcb,
                                              float* __restrict__ out) {
    const int i = blockIdx.x * 256 + threadIdx.x;   // 0..8191
    float s = 0.0f;
#pragma unroll
    for (int y = 0; y < FCSL; ++y)
        s += part2[(size_t)y * 8192 + i];
    out[i] = s + fcb[i & 255];
}

// ---------------------------------------------------------------------------
// K12 (fallback for GB<32): FC -> f32 out
// ---------------------------------------------------------------------------
__global__ __launch_bounds__(256) void fc_k(const float* __restrict__ px,
                                            const float* __restrict__ w,
                                            const float* __restrict__ bias,
                                            float* __restrict__ out,
                                            int b0) {
    const int gw = blockIdx.x * 4 + (threadIdx.x >> 6);
    const int lane = threadIdx.x & 63;
    const int lb = gw >> 8;
    const int o = gw & 255;
    const float* xb = px + (size_t)lb * EL_PX;
    const float* wr = w + (size_t)o * EL_PX;
    float s = 0.0f;
    for (int k = lane; k < EL_PX; k += 64) s += xb[k] * wr[k];
#pragma unroll
    for (int off = 32; off > 0; off >>= 1) s += __shfl_down(s, off);
    if (lane == 0) out[(size_t)(b0 + lb) * 256 + o] = s + bias[o];
}

// ---------------------------------------------------------------------------
extern "C" void kernel_launch(void* const* d_in, const int* in_sizes, int n_in,
                              void* d_out, int out_size, void* d_ws, size_t ws_size,
                              hipStream_t stream) {
    const float* x_t   = (const float*)d_in[0];
    const float* image = (const float*)d_in[1];
    const float* c1_w  = (const float*)d_in[2];
    const float* c1_b  = (const float*)d_in[3];
    const float* bn1_g = (const float*)d_in[4];
    const float* bn1_b = (const float*)d_in[5];
    const float* c2_w  = (const float*)d_in[6];
    const float* c2_b  = (const float*)d_in[7];
    const float* bn2_g = (const float*)d_in[8];
    const float* bn2_b = (const float*)d_in[9];
    const float* a1_w  = (const float*)d_in[10];
    const float* a1_b  = (const float*)d_in[11];
    const float* abn1_g= (const float*)d_in[12];
    const float* abn1_b= (const float*)d_in[13];
    const float* a2_w  = (const float*)d_in[14];
    const float* a2_b  = (const float*)d_in[15];
    const float* abn2_g= (const float*)d_in[16];
    const float* abn2_b= (const float*)d_in[17];
    const float* p1_w  = (const float*)d_in[18];
    const float* p1_b  = (const float*)d_in[19];
    const float* pbn1_g= (const float*)d_in[20];
    const float* pbn1_b= (const float*)d_in[21];
    const float* p2_w  = (const float*)d_in[22];
    const float* p2_b  = (const float*)d_in[23];
    const float* pbn2_g= (const float*)d_in[24];
    const float* pbn2_b= (const float*)d_in[25];
    const float* fc_w  = (const float*)d_in[26];
    const float* fc_b  = (const float*)d_in[27];
    float* outp = (float*)d_out;

    // Fixed region: folded bf16 weights + biases
    float* ws = (float*)d_ws;
    short* wTa1 = (short*)ws;
    short* wTa2 = wTa1 + WSH_A1;
    short* wTp1 = wTa2 + WSH_A2;
    short* wTp2 = wTp1 + WSH_A1;
    short* wTc2 = wTp2 + WSH_A2;
    float* bfa1 = ws + WSH_TOT / 2;
    float* bfa2 = bfa1 + 128;
    float* bfp1 = bfa2 + 128;
    float* bfp2 = bfp1 + 128;
    float* bfc2 = bfp2 + 128;
    float* dyn  = bfc2 + 128;
    const size_t fixed_floats = WSH_TOT / 2 + 1024;

    int GB = 32;
    while (GB > 1) {
        size_t need = ((size_t)GB * EL_PER_BATCH + fixed_floats + 256) * sizeof(float);
        if (need <= ws_size) break;
        GB >>= 1;
    }
    const int ngroups = NB / GB;

    float* heat = dyn;                                 // GB*EL_HEAT
    float* m    = heat + (size_t)GB * EL_HEAT;         // 64
    float* regB = m + 64;                              // GB*EL_REGB
    float* regC = regB + (size_t)GB * EL_REGB;         // GB*EL_REGC
    float* regD = regC + (size_t)GB * EL_REGC;         // GB*EL_REGD
    float* regE = regD + (size_t)GB * EL_REGD;         // GB*EL_REGE
    float* pmm  = regE + (size_t)GB * EL_REGE;         // 128
    float* px   = pmm + 128;                           // GB*EL_PX

    // Optional regF for pp2 (enables merged a2+p2): after px.
    const size_t need_merged = ((size_t)GB * (EL_PER_BATCH + EL_REGD) + fixed_floats + 256) * sizeof(float);
    const bool MRG = (GB == 32) && (ws_size >= need_merged);
    float* regF = px + (size_t)GB * EL_PX;

    float* G      = regD;            // [lb][181][330] f32 (dead after rowcombine)
    short* out1b  = (short*)regB;    // bf16 ch-last [H1*W1][32]
    short* out2b  = (short*)regC;    // bf16 ch-last [pixel][64]
    short* fbuf   = (short*)regD;    // bf16 ch-last [pixel][128] (a1 out)
    short* fxbf   = (short*)regE;    // bf16 ch-first [c][KPAD]
    short* pp1    = (short*)regB;    // bf16 ch-last (out1 dead)
    short* pp2    = MRG ? (short*)regF : (short*)regD;  // bf16 ch-first [c][KPAD]
    float* pxpart = regB;            // f32, NKC*GB*EL_PX = 10.49M, spans regB+regC (both dead)
    // FC-phase aliases (valid once einsum_part/px_reduce are done):
    float* fcwT   = regD;            // f32 wT[16384][256] (fbuf/pp2 dead)
    float* fcpart = regB;            // f32 NKF*8192 = 4.19M (pxpart dead after px_reduce)
    float* fcpart2= regB + (size_t)NKF * 8192;          // f32 FCSL*8192 (still in regB/regC)

    wfold_k<<<(9 * 128 * CH2 + 255) / 256, 256, 0, stream>>>(a1_w, abn1_g, a1_b, abn1_b, wTa1, bfa1, 128, CH2);
    wfold_k<<<(9 * 128 * CH3 + 255) / 256, 256, 0, stream>>>(a2_w, abn2_g, a2_b, abn2_b, wTa2, bfa2, 128, CH3);
    wfold_k<<<(9 * 128 * CH2 + 255) / 256, 256, 0, stream>>>(p1_w, pbn1_g, p1_b, pbn1_b, wTp1, bfp1, 128, CH2);
    wfold_k<<<(9 * 128 * CH3 + 255) / 256, 256, 0, stream>>>(p2_w, pbn2_g, p2_b, pbn2_b, wTp2, bfp2, 128, CH3);
    wfold_k<<<(9 * 64 * 32 + 255) / 256, 256, 0, stream>>>(c2_w, bn2_g, c2_b, bn2_b, wTc2, bfc2, 64, 32);

    for (int gidx = 0; gidx < ngroups; ++gidx) {
        const int b0 = gidx * GB;
        mm_init<<<1, 256, 0, stream>>>((unsigned*)m, (unsigned*)pmm);
        heat_scatter_cols<<<dim3(NSTRIP, GB), 256, 0, stream>>>(x_t, G, b0);
        heat_rowcombine<<<dim3(IH / BXR, GB, 2), 256, 0, stream>>>(G, heat, (unsigned*)m);
        conv1_pool<<<(GB * H1 * W1 + 255) / 256, 256, 0, stream>>>(
            heat, image, m, c1_w, c1_b, bn1_g, bn1_b, out1b, b0, GB);
        conv2_mfma<<<dim3(6, 12, GB), 256, 0, stream>>>(out1b, wTc2, bfc2, out2b);
        // merged a1+p1 (shared input, disjoint outputs; per-block body = round-3)
        conv3x3_mfma<CH2, 0, 0, true><<<dim3(3, 24, GB), 256, 0, stream>>>(
            out2b, out2b, wTa1, wTp1, bfa1, bfp1, fbuf, pp1);
        if (MRG) {
            // merged a2+p2: independent inputs (fbuf, pp1), disjoint outputs (fxbf, pp2=regF)
            conv3x3_mfma<CH3, 2, 2, true><<<dim3(3, 24, GB), 256, 0, stream>>>(
                fbuf, pp1, wTa2, wTp2, bfa2, bfp2, fxbf, pp2);
        } else {
            conv3x3_mfma<CH3, 2, 1, false><<<dim3(3, 12, GB), 256, 0, stream>>>(
                fbuf, fbuf, wTa2, wTa2, bfa2, bfa2, fxbf, fxbf);
            conv3x3_mfma<CH3, 2, 0, false><<<dim3(3, 12, GB), 256, 0, stream>>>(
                pp1, pp1, wTp2, wTp2, bfp2, bfp2, pp2, pp2);
        }
        pminmax<<<dim3(16, GB), 256, 0, stream>>>(pp2, (unsigned*)pmm);
        einsum_part<<<dim3(NKC, GB), 256, 0, stream>>>(pp2, fxbf, pmm, pxpart);
        px_reduce<<<(GB * EL_PX + 255) / 256, 256, 0, stream>>>(pxpart, px, GB);
        if (GB == 32) {
            fc_wt<<<dim3(EL_PX / 32, 256 / 32), 256, 0, stream>>>(fc_w, fcwT);
            fc_part<<<NKF, 256, 0, stream>>>(px, fcwT, fcpart);
            fc_out<<<dim3(128, FCSL), 256, 0, stream>>>(fcpart, fcpart2);
            fc_fin<<<8192 / 256, 256, 0, stream>>>(fcpart2, fc_b, outp);
        } else {
            fc_k<<<GB * 64, 256, 0, stream>>>(px, fc_w, fc_b, outp, b0);
        }
    }
}